// Round 7
// baseline (437.729 us; speedup 1.0000x reference)
//
#include <hip/hip_runtime.h>
#include <math.h>

#define BB 4
#define S 1024
#define D 512
#define H 8
#define DKH 64

#define ATT_LD 1032   // att row stride (shorts): 516 dwords == 4 mod 32 (2-way = free)
#define LOG2E 1.4426950408889634f

typedef __attribute__((ext_vector_type(8))) short bf16x8;
typedef __attribute__((ext_vector_type(4))) float f32x4;

#if __has_builtin(__builtin_amdgcn_exp2f)
#define EXP2(x) __builtin_amdgcn_exp2f(x)
#else
#define EXP2(x) exp2f(x)
#endif
#if __has_builtin(__builtin_amdgcn_sqrtf)
#define SQRTF(x) __builtin_amdgcn_sqrtf(x)
#else
#define SQRTF(x) sqrtf(x)
#endif
#if __has_builtin(__builtin_amdgcn_rcpf)
#define RCPF(x) __builtin_amdgcn_rcpf(x)
#else
#define RCPF(x) (1.0f / (x))
#endif

__device__ __forceinline__ unsigned short f2bf(float f){
  unsigned int u = __float_as_uint(f);
  u += 0x7FFFu + ((u >> 16) & 1u);
  return (unsigned short)(u >> 16);
}
__device__ __forceinline__ unsigned short f2bf_rhu(float f){
  return (unsigned short)((__float_as_uint(f) + 0x8000u) >> 16);
}
__device__ __forceinline__ unsigned int pk_rhu(float lo, float hi){
  unsigned int a = __float_as_uint(lo) + 0x8000u;
  unsigned int b = __float_as_uint(hi) + 0x8000u;
#if __has_builtin(__builtin_amdgcn_perm)
  return __builtin_amdgcn_perm(b, a, 0x07060302u);
#else
  return (a >> 16) | (b & 0xffff0000u);
#endif
}
__device__ __forceinline__ float bf2f(unsigned int v){
  return __uint_as_float(v << 16);
}
__device__ __forceinline__ f32x4 MFMA(bf16x8 a, bf16x8 b, f32x4 c){
  return __builtin_amdgcn_mfma_f32_16x16x32_bf16(a, b, c, 0, 0, 0);
}
__device__ __forceinline__ void gl_lds16(const void* g, void* l){
  __builtin_amdgcn_global_load_lds(
      (const __attribute__((address_space(1))) void*)g,
      (__attribute__((address_space(3))) void*)l, 16, 0, 0);
}

// ---- DPP cross-lane (pure VALU pipe, no ds_bpermute latency) ----
template<int CTRL>
__device__ __forceinline__ float dppadd(float v){
  int s = __builtin_amdgcn_update_dpp(0, __float_as_int(v), CTRL, 0xf, 0xf, true);
  return v + __int_as_float(s);
}
__device__ __forceinline__ float rdl(float v, int l){
  return __int_as_float(__builtin_amdgcn_readlane(__float_as_int(v), l));
}
// inclusive 64-lane prefix (order-exact) + total, via 16-lane row scans + row offsets
__device__ __forceinline__ void wave_scan64(float v, int lane, float& incl, float& total){
  float r = dppadd<0x111>(v);   // row_shr:1
  r = dppadd<0x112>(r);         // row_shr:2
  r = dppadd<0x114>(r);         // row_shr:4
  r = dppadd<0x118>(r);         // row_shr:8
  float t0 = rdl(r, 15), t1 = rdl(r, 31), t2 = rdl(r, 47), t3 = rdl(r, 63);
  const int row = lane >> 4;
  float off = (row > 0 ? t0 : 0.f) + (row > 1 ? t1 : 0.f) + (row > 2 ? t2 : 0.f);
  incl = r + off;
  total = (t0 + t1) + (t2 + t3);
}
__device__ __forceinline__ float wave_sum64(float v){
  float r = dppadd<0x111>(v);
  r = dppadd<0x112>(r);
  r = dppadd<0x114>(r);
  r = dppadd<0x118>(r);
  return (rdl(r, 15) + rdl(r, 31)) + (rdl(r, 47) + rdl(r, 63));
}

__device__ __forceinline__ float blk_sum(float* r, int t, float v){
  r[t] = v; __syncthreads();
  for (int s = 128; s > 0; s >>= 1){
    if (t < s) r[t] += r[t + s];
    __syncthreads();
  }
  float res = r[0]; __syncthreads();
  return res;
}

// ================= batched projection GEMM (M=4096,N=512,K=512) =================
struct GemmJobs {
  const unsigned short* A[4];
  const unsigned short* W[4];
  const float* bias[4];
  void* C[4];
};
template<int OUTBF>
__global__ __launch_bounds__(256) void mfma_gemm_b(GemmJobs jb)
{
  __shared__ __align__(16) short As[128][32];
  __shared__ __align__(16) short Ws[128][32];
  const int t = threadIdx.x;
  const int z = blockIdx.z;
  const int n0 = blockIdx.x * 128, m0 = blockIdx.y * 128;
  const unsigned short* A = jb.A[z];
  const unsigned short* W = jb.W[z];
  const float* bias = jb.bias[z];
  const int w = t >> 6, lane = t & 63;
  const int wm = (w >> 1) << 6, wn = (w & 1) << 6;
  const int lm = lane & 15, q = lane >> 4;
  const int r = t >> 2, cc = (t & 3) << 3;
  char* ldsA = ((char*)&As[0][0]) + w * 1024;
  char* ldsW = ((char*)&Ws[0][0]) + w * 1024;
  f32x4 acc[4][4];
  #pragma unroll
  for (int a_ = 0; a_ < 4; a_++)
    #pragma unroll
    for (int b_ = 0; b_ < 4; b_++)
      acc[a_][b_] = (f32x4){0.f, 0.f, 0.f, 0.f};
  for (int k0 = 0; k0 < D; k0 += 32){
    gl_lds16(&A[(size_t)(m0 + r)      * D + k0 + cc], ldsA);
    gl_lds16(&A[(size_t)(m0 + r + 64) * D + k0 + cc], ldsA + 4096);
    gl_lds16(&W[(size_t)(n0 + r)      * D + k0 + cc], ldsW);
    gl_lds16(&W[(size_t)(n0 + r + 64) * D + k0 + cc], ldsW + 4096);
    __syncthreads();
    bf16x8 af[4], bf[4];
    #pragma unroll
    for (int mt = 0; mt < 4; mt++) af[mt] = *(const bf16x8*)&As[wm + mt*16 + lm][q*8];
    #pragma unroll
    for (int nt = 0; nt < 4; nt++) bf[nt] = *(const bf16x8*)&Ws[wn + nt*16 + lm][q*8];
    #pragma unroll
    for (int mt = 0; mt < 4; mt++)
      #pragma unroll
      for (int nt = 0; nt < 4; nt++)
        acc[mt][nt] = MFMA(af[mt], bf[nt], acc[mt][nt]);
    __syncthreads();
  }
  #pragma unroll
  for (int nt = 0; nt < 4; nt++){
    const int n = n0 + wn + nt*16 + lm;
    const float bs = bias[n];
    #pragma unroll
    for (int mt = 0; mt < 4; mt++){
      const int mb = m0 + wm + mt*16 + (q << 2);
      f32x4 c = acc[mt][nt];
      #pragma unroll
      for (int rr = 0; rr < 4; rr++){
        float vv = c[rr] + bs;
        if (OUTBF)
          ((unsigned short*)jb.C[z])[(size_t)(mb + rr) * D + n] = f2bf(vv);
        else
          ((float*)jb.C[z])[(size_t)(mb + rr) * D + n] = vv;
      }
    }
  }
}

// ================= V transpose: VT[bh][64][S] from V[b][S][D] =================
// XCD-pinned 1D grid: xcd = bh & 7 (same invariant as fused_attn) so the VT
// tile is written into the L2 of the XCD that will read it.
#define KS_LD 66
struct VTArgs { const unsigned short* v[2]; unsigned short* vt[2]; int nz; };
__global__ __launch_bounds__(256) void vt_kernel(VTArgs a)
{
  __shared__ unsigned short tile[64 * KS_LD];
  const int lin = blockIdx.x;
  const int xcd = lin & 7, slot = lin >> 3;
  const int j0 = (slot & 15) * 64;
  const int set = slot >> 4;
  const int z   = (a.nz == 2) ? (set & 1)  : 0;
  const int grp = (a.nz == 2) ? (set >> 1) : set;
  const int bh = xcd + 8 * grp, b = bh >> 3, h = bh & 7;
  const int t = threadIdx.x;
  const unsigned short* vp = a.v[z];
  unsigned short* vtp = a.vt[z] + (size_t)bh * 64 * S;
  #pragma unroll
  for (int p = 0; p < 2; p++){
    int lin2 = t + p * 256, row = lin2 >> 3, c8 = (lin2 & 7) << 3;
    *(uint4*)&tile[row * KS_LD + c8] =
      *(const uint4*)&vp[((size_t)b * S + j0 + row) * D + h * DKH + c8];
  }
  __syncthreads();
  #pragma unroll
  for (int p = 0; p < 2; p++){
    int lin2 = t + p * 256, d = lin2 >> 3, c8 = (lin2 & 7) << 3;
    unsigned short tmp[8];
    #pragma unroll
    for (int jx = 0; jx < 8; jx++) tmp[jx] = tile[(c8 + jx) * KS_LD + d];
    *(uint4*)&vtp[(size_t)d * S + j0 + c8] = *(const uint4*)tmp;
  }
}

// ================= fused attention: scores -> decay -> AV =================
// 16-row i-blocks; att (unnormalized pp) in LDS; row scale applied in phase 3.
// XCD-pinned 1D grid (grid = 8*64*4*nz blocks, 256 threads).
// Phase 2 BATCHES all 4 rows of a wave through each step (loads, cumsums,
// scans, decay, reductions) so 4 independent dependency chains are in flight
// -- the per-row serial chain (scan ~150cy + trans chains) was the r0-r6
// invariant stall source that neither occupancy nor issue-count touched.
struct FAArgs {
  const unsigned short* qk[2];   // q==k source (bf16, [b][S][D])
  const unsigned short* vt[2];   // VT (bf16, [bh][64][S])
  unsigned short* ctx[2];        // out (bf16, [b][S][D])
  const float* g[2];
  const float* c3;               // fp32 [b][h][S] (C3 mode)
  int diag, zero_pad, nz;
};
template<int C3>
__global__ __launch_bounds__(256, 2) void fused_attn(FAArgs a)
{
  __shared__ __align__(16) unsigned short att[16 * ATT_LD];   // 33,024 B
  __shared__ float ls2s[16];                                   // per-row inv2
  const int t = threadIdx.x;
  const int lin = blockIdx.x;
  const int xcd = lin & 7;
  const int slot = lin >> 3;
  const int i0 = (slot & 63) * 16;
  const int set = slot >> 6;
  const int z   = (a.nz == 2) ? (set & 1)  : 0;
  const int grp = (a.nz == 2) ? (set >> 1) : set;
  const int bh = xcd + 8 * grp, b = bh >> 3, h = bh & 7;
  const int w = t >> 6, lane = t & 63, lm = lane & 15, q = lane >> 4;
  const unsigned short* qkp = a.qk[z];
  const unsigned short* vtp = a.vt[z] + (size_t)bh * 64 * S;
  unsigned short* ctxp = a.ctx[z];
  float gm2;
  { float gv = a.g[z][h];
    gm2 = -((gv > 20.f) ? gv : log1pf(expf(gv))) * LOG2E; }   // log2-space gamma

  // ---------- phase 1: scores tile [16 x 1024] -> att (bf16), K prefetched ----------
  if (!C3){
    const size_t rowbase = (size_t)b * S;
    bf16x8 af0 = *(const bf16x8*)&qkp[(rowbase + i0 + lm) * D + h * DKH + q*8];
    bf16x8 af1 = *(const bf16x8*)&qkp[(rowbase + i0 + lm) * D + h * DKH + 32 + q*8];
    size_t kb = (rowbase + w*16 + lm) * D + h * DKH;
    bf16x8 bv0 = *(const bf16x8*)&qkp[kb + q*8];
    bf16x8 bv1 = *(const bf16x8*)&qkp[kb + 32 + q*8];
    for (int jc = 0; jc < S; jc += 64){
      bf16x8 nb0, nb1;
      if (jc + 64 < S){
        size_t kb2 = (rowbase + jc + 64 + w*16 + lm) * D + h * DKH;
        nb0 = *(const bf16x8*)&qkp[kb2 + q*8];
        nb1 = *(const bf16x8*)&qkp[kb2 + 32 + q*8];
      }
      f32x4 acc = (f32x4){0.f, 0.f, 0.f, 0.f};
      acc = MFMA(af0, bv0, acc);
      acc = MFMA(af1, bv1, acc);
      #pragma unroll
      for (int rr = 0; rr < 4; rr++)
        att[(q*4 + rr) * ATT_LD + jc + w*16 + lm] = f2bf_rhu(acc[rr] * 0.125f);
      bv0 = nb0; bv1 = nb1;
    }
  }
  __syncthreads();

  // ---------- phase 2: decay + double softmax, 4 rows batched per wave ----------
  const int jA0 = lane * 8, jB0 = 512 + lane * 8;

  // C3: scores are row-invariant per (b,h) — hoist unpack + raw exp across rows
  float cHA[8], cHB[8], erHA[8], erHB[8];
  if (C3){
    const float* c3p = a.c3 + ((size_t)b * H + h) * S;
    float4 x0 = *(const float4*)&c3p[lane*8];
    float4 x1 = *(const float4*)&c3p[lane*8 + 4];
    float4 y0 = *(const float4*)&c3p[512 + lane*8];
    float4 y1 = *(const float4*)&c3p[512 + lane*8 + 4];
    cHA[0]=x0.x*LOG2E; cHA[1]=x0.y*LOG2E; cHA[2]=x0.z*LOG2E; cHA[3]=x0.w*LOG2E;
    cHA[4]=x1.x*LOG2E; cHA[5]=x1.y*LOG2E; cHA[6]=x1.z*LOG2E; cHA[7]=x1.w*LOG2E;
    cHB[0]=y0.x*LOG2E; cHB[1]=y0.y*LOG2E; cHB[2]=y0.z*LOG2E; cHB[3]=y0.w*LOG2E;
    cHB[4]=y1.x*LOG2E; cHB[5]=y1.y*LOG2E; cHB[6]=y1.z*LOG2E; cHB[7]=y1.w*LOG2E;
    #pragma unroll
    for (int k = 0; k < 8; k++){ erHA[k] = EXP2(cHA[k]); erHB[k] = EXP2(cHB[k]); }
  }

  {
    const int rbase = w * 4;
    const int jmax0 = i0 + rbase + a.diag;
    const bool skipB = (jmax0 + 3 < 512);    // wave-uniform (rows rbase..rbase+3)

    // step 1: all LDS reads + unpack (8 ds_read_b128 in flight)
    float cA[4][8], cB[4][8];
    if (!C3){
      #pragma unroll
      for (int r = 0; r < 4; r++){
        const unsigned short* rowp = &att[(rbase + r) * ATT_LD];
        uint4 uAv = *(const uint4*)&rowp[jA0];
        uint4 uBv = *(const uint4*)&rowp[jB0];
        unsigned int ua[4] = {uAv.x, uAv.y, uAv.z, uAv.w};
        unsigned int ub[4] = {uBv.x, uBv.y, uBv.z, uBv.w};
        #pragma unroll
        for (int mel = 0; mel < 4; mel++){
          cA[r][mel*2]   = bf2f(ua[mel] & 0xffffu) * LOG2E;
          cA[r][mel*2+1] = bf2f(ua[mel] >> 16) * LOG2E;
          cB[r][mel*2]   = bf2f(ub[mel] & 0xffffu) * LOG2E;
          cB[r][mel*2+1] = bf2f(ub[mel] >> 16) * LOG2E;
        }
      }
    }

    // step 2: 4 independent cumsums (A half)
    float plA[4][8], plB[4][8];
    float runA[4], sA[4], TA[4];
    #pragma unroll
    for (int r = 0; r < 4; r++){
      const int jmax = jmax0 + r;
      float run = 0.f;
      #pragma unroll
      for (int k = 0; k < 8; k++){
        float e;
        if (C3) e = (jA0 + k <= jmax) ? erHA[k] : 0.f;
        else    e = (jA0 + k <= jmax) ? EXP2(cA[r][k]) : 0.f;
        run += e; plA[r][k] = run;
      }
      runA[r] = run;
    }
    // step 3: 4 scans back-to-back — chains overlap
    #pragma unroll
    for (int r = 0; r < 4; r++) wave_scan64(runA[r], lane, sA[r], TA[r]);

    float runB[4], sB[4], TB[4];
    if (!skipB){
      #pragma unroll
      for (int r = 0; r < 4; r++){
        const int jmax = jmax0 + r;
        float run = 0.f;
        #pragma unroll
        for (int k = 0; k < 8; k++){
          float e;
          if (C3) e = (jB0 + k <= jmax) ? erHB[k] : 0.f;
          else    e = (jB0 + k <= jmax) ? EXP2(cB[r][k]) : 0.f;
          run += e; plB[r][k] = run;
        }
        runB[r] = run;
      }
      #pragma unroll
      for (int r = 0; r < 4; r++) wave_scan64(runB[r], lane, sB[r], TB[r]);
    }

    // step 4: 4 independent decay streams (trans latencies interleave)
    float ls2[4];
    #pragma unroll
    for (int r = 0; r < 4; r++){
      const float T = skipB ? TA[r] : (TA[r] + TB[r]);
      const float inv1 = RCPF(T);
      const float cbaseA = (T - (sA[r] - runA[r])) * inv1;
      const float fiA = (float)(i0 + rbase + r - jA0);
      float s2 = 0.f;
      #pragma unroll
      for (int k = 0; k < 8; k++){
        float remn = fmaf(-plA[r][k], inv1, cbaseA);
        float pos  = fabsf(fiA - (float)k);
        float dist = SQRTF(fmaxf(remn * pos, 0.f));
        float eff  = fmaxf(EXP2(gm2 * dist), 1e-5f);
        float cv   = C3 ? cHA[k] : cA[r][k];
        float pp   = EXP2(cv * eff);
        s2 += pp; plA[r][k] = pp;
      }
      if (!skipB){
        const float cbaseB = (T - (TA[r] + sB[r] - runB[r])) * inv1;
        const float fiB = (float)(i0 + rbase + r - jB0);
        #pragma unroll
        for (int k = 0; k < 8; k++){
          float remn = fmaf(-plB[r][k], inv1, cbaseB);
          float pos  = fabsf(fiB - (float)k);
          float dist = SQRTF(fmaxf(remn * pos, 0.f));
          float eff  = fmaxf(EXP2(gm2 * dist), 1e-5f);
          float cv   = C3 ? cHB[k] : cB[r][k];
          float pp   = EXP2(cv * eff);
          s2 += pp; plB[r][k] = pp;
        }
      } else {
        #pragma unroll
        for (int k = 0; k < 8; k++){
          float e2 = C3 ? erHB[k] : EXP2(cB[r][k]);
          plB[r][k] = e2; s2 += e2;
        }
      }
      ls2[r] = s2;
    }

    // step 5: 4 reductions back-to-back
    #pragma unroll
    for (int r = 0; r < 4; r++) ls2[r] = wave_sum64(ls2[r]);

    // C3 zero_pad row 0: computed with T=0 (NaNs) — override outputs
    #pragma unroll
    for (int r = 0; r < 4; r++){
      if (C3 && a.zero_pad && (i0 + rbase + r) == 0){
        #pragma unroll
        for (int k = 0; k < 8; k++){ plA[r][k] = 0.f; plB[r][k] = 0.f; }
        ls2[r] = 1.f;
      }
    }

    // step 6: stores
    #pragma unroll
    for (int r = 0; r < 4; r++){
      unsigned short* rowp = &att[(rbase + r) * ATT_LD];
      if (lane == 0) ls2s[rbase + r] = RCPF(ls2[r]);
      uint4 oA, oB;
      oA.x = pk_rhu(plA[r][0], plA[r][1]);
      oA.y = pk_rhu(plA[r][2], plA[r][3]);
      oA.z = pk_rhu(plA[r][4], plA[r][5]);
      oA.w = pk_rhu(plA[r][6], plA[r][7]);
      oB.x = pk_rhu(plB[r][0], plB[r][1]);
      oB.y = pk_rhu(plB[r][2], plB[r][3]);
      oB.z = pk_rhu(plB[r][4], plB[r][5]);
      oB.w = pk_rhu(plB[r][6], plB[r][7]);
      *(uint4*)&rowp[jA0] = oA;
      *(uint4*)&rowp[jB0] = oB;
    }
  }
  __syncthreads();

  // ---------- phase 3: ctx = att @ V (VT prefetched from global), scale by inv2 ----------
  f32x4 acc = (f32x4){0.f,0.f,0.f,0.f};
  const unsigned short* vrow = &vtp[(size_t)(w*16 + lm) * S];
  bf16x8 bv0 = *(const bf16x8*)&vrow[q*8];
  bf16x8 bv1 = *(const bf16x8*)&vrow[32 + q*8];
  for (int kc = 0; kc < S; kc += 64){
    bf16x8 nb0, nb1;
    if (kc + 64 < S){
      nb0 = *(const bf16x8*)&vrow[kc + 64 + q*8];
      nb1 = *(const bf16x8*)&vrow[kc + 96 + q*8];
    }
    bf16x8 a0 = *(const bf16x8*)&att[lm * ATT_LD + kc + q*8];
    bf16x8 a1 = *(const bf16x8*)&att[lm * ATT_LD + kc + 32 + q*8];
    acc = MFMA(a0, bv0, acc);
    acc = MFMA(a1, bv1, acc);
    bv0 = nb0; bv1 = nb1;
  }
  #pragma unroll
  for (int rr = 0; rr < 4; rr++){
    const int rl = q*4 + rr;
    const float sc = ls2s[rl];
    const int row = i0 + rl;
    ctxp[((size_t)b * S + row) * D + h * DKH + w*16 + lm] = f2bf(acc[rr] * sc);
  }
}

// ================= residual + LayerNorm -> bf16 (batched) =================
struct LNJobs {
  const float* resid[2];
  const float* y[2];
  const float* ls[2];
  const float* lb[2];
  unsigned short* out[2];
  int bcast[2];
};
__global__ __launch_bounds__(256) void ln_residual_b(LNJobs j)
{
  const int z = blockIdx.y;
  const int r = blockIdx.x, t = threadIdx.x;
  __shared__ float red[256];
  const size_t base = (size_t)r * D;
  const float* resid = j.resid[z];
  const float* y = j.y[z];
  const int bcast = j.bcast[z];
  float r0 = bcast ? resid[t]       : resid[base + t];
  float r1 = bcast ? resid[t + 256] : resid[base + t + 256];
  float x0 = r0 + y[base + t];
  float x1 = r1 + y[base + t + 256];
  float mean = blk_sum(red, t, x0 + x1) * (1.0f / 512.0f);
  float d0 = x0 - mean, d1 = x1 - mean;
  float var = blk_sum(red, t, d0*d0 + d1*d1) * (1.0f / 512.0f);
  float inv = rsqrtf(var + 1e-5f);
  j.out[z][base + t]       = f2bf(d0 * inv * j.ls[z][t]       + j.lb[z][t]);
  j.out[z][base + t + 256] = f2bf(d1 * inv * j.ls[z][t + 256] + j.lb[z][t + 256]);
}

// ================= fp32 -> bf16 conversions =================
struct CvtJobs {
  const float* s[12];
  unsigned short* d[12];
  int n[12];
};
__global__ __launch_bounds__(256) void cvt_all(CvtJobs jb){
  const int z = blockIdx.y;
  const int n = jb.n[z];
  const float* s = jb.s[z];
  unsigned short* d = jb.d[z];
  for (int idx = blockIdx.x * 256 + threadIdx.x; idx < n; idx += gridDim.x * 256)
    d[idx] = f2bf(s[idx]);
}

// ================= know-derived small kernels (merged) =================
__global__ __launch_bounds__(256) void know_kernel(
    const float* __restrict__ know, const float* __restrict__ Wq3,
    const float* __restrict__ bq3, float* __restrict__ q3,
    const float* __restrict__ Wlk, const float* __restrict__ blk_,
    float* __restrict__ keyt)
{
  if (blockIdx.x < 128){
    const int wv = (blockIdx.x * 256 + threadIdx.x) >> 6;
    const int lane = threadIdx.x & 63;
    const float* wr = Wq3 + (size_t)wv * 512 + lane * 8;
    const float* kr = know + lane * 8;
    float4 w0 = *(const float4*)&wr[0], w1 = *(const float4*)&wr[4];
    float4 k0 = *(const float4*)&kr[0], k1 = *(const float4*)&kr[4];
    float p = w0.x*k0.x + w0.y*k0.y + w0.z*k0.z + w0.w*k0.w
            + w1.x*k1.x + w1.y*k1.y + w1.z*k1.z + w1.w*k1.w;
    p = wave_sum64(p);
    if (lane == 0) q3[wv] = p + bq3[wv];
  } else {
    int idx = (blockIdx.x - 128) * 256 + threadIdx.x;
    int h = idx >> 9, n = idx & 511;
    float acc = 0.f;
    for (int i = 0; i < 64; i++) acc += know[h * 64 + i] * Wlk[(size_t)n * 64 + i];
    keyt[idx] = 1.f / (1.f + __expf(-(acc + blk_[n])));
  }
}

__global__ __launch_bounds__(256) void scores3_kernel(
    const float* __restrict__ q3, const unsigned short* __restrict__ k3,
    float* __restrict__ c3)
{
  int idx = blockIdx.x * 256 + threadIdx.x;   // (b*H+h)*S + j
  int j  = idx & (S - 1);
  int bh = idx >> 10;
  int h  = bh & 7, b = bh >> 3;
  const unsigned short* kp = k3 + ((size_t)b * S + j) * D + h * DKH;
  const float* qp = q3 + h * DKH;
  float acc = 0.f;
  #pragma unroll
  for (int d8 = 0; d8 < 64; d8 += 8){
    uint4 u = *(const uint4*)&kp[d8];
    unsigned int uu[4] = {u.x, u.y, u.z, u.w};
    #pragma unroll
    for (int mel = 0; mel < 4; mel++){
      acc += qp[d8 + 2*mel]     * bf2f(uu[mel] & 0xffffu);
      acc += qp[d8 + 2*mel + 1] * bf2f(uu[mel] >> 16);
    }
  }
  c3[idx] = acc * 0.125f;
}

__global__ __launch_bounds__(256) void alphas_kernel(
    const float* __restrict__ keyt, const float* __restrict__ q_emb,
    float* __restrict__ alpha)
{
  const int row = blockIdx.x * 4 + (threadIdx.x >> 6);
  const int l = threadIdx.x & 63;
  const int h = l >> 3, sub = l & 7;
  const float* qr = q_emb + (size_t)row * D;
  const float* kt = keyt + h * D;
  float p = 0.f;
  for (int d = sub; d < D; d += 8) p += kt[d] * qr[d];
  p += __shfl_xor(p, 1, 64);
  p += __shfl_xor(p, 2, 64);
  p += __shfl_xor(p, 4, 64);
  float m = p;
  m = fmaxf(m, __shfl_xor(m, 8, 64));
  m = fmaxf(m, __shfl_xor(m, 16, 64));
  m = fmaxf(m, __shfl_xor(m, 32, 64));
  float e = __expf(p - m);
  float ssum = e;
  ssum += __shfl_xor(ssum, 8, 64);
  ssum += __shfl_xor(ssum, 16, 64);
  ssum += __shfl_xor(ssum, 32, 64);
  if (sub == 0) alpha[(size_t)row * H + h] = e / ssum;
}

// ================= fused val GEMM + sigmoid + alpha-combine =================
__global__ __launch_bounds__(256) void val_fused(
    const unsigned short* __restrict__ Ah,
    const unsigned short* __restrict__ Wv,
    const float* __restrict__ blv,
    const float* __restrict__ alpha,
    float* __restrict__ out)
{
  __shared__ __align__(16) short As[128][32];
  __shared__ __align__(16) short Ws[128][32];
  __shared__ float als[128];
  const int t = threadIdx.x;
  const int n0 = blockIdx.x * 128, m0 = blockIdx.y * 128;
  if (t < 128) als[t] = alpha[m0 + t];
  const int w = t >> 6, lane = t & 63;
  const int wm = (w >> 1) << 6, wn = (w & 1) << 6;
  const int lm = lane & 15, q = lane >> 4;
  const int r = t >> 2, cc = (t & 3) << 3;
  f32x4 acc[4][4];
  #pragma unroll
  for (int a_ = 0; a_ < 4; a_++)
    #pragma unroll
    for (int b_ = 0; b_ < 4; b_++)
      acc[a_][b_] = (f32x4){0.f, 0.f, 0.f, 0.f};
  for (int k0 = 0; k0 < 64; k0 += 32){
    *(uint4*)&As[r][cc]      = *(const uint4*)&Ah[(size_t)(m0 + r) * 64 + k0 + cc];
    *(uint4*)&As[r + 64][cc] = *(const uint4*)&Ah[(size_t)(m0 + r + 64) * 64 + k0 + cc];
    *(uint4*)&Ws[r][cc]      = *(const uint4*)&Wv[(size_t)(n0 + r) * 64 + k0 + cc];
    *(uint4*)&Ws[r + 64][cc] = *(const uint4*)&Wv[(size_t)(n0 + r + 64) * 64 + k0 + cc];
    __syncthreads();
    bf16x8 af[4], bf[4];
    #pragma unroll
    for (int mt = 0; mt < 4; mt++) af[mt] = *(const bf16x8*)&As[wm + mt*16 + lm][q*8];
    #pragma unroll
    for (int nt = 0; nt < 4; nt++) bf[nt] = *(const bf16x8*)&Ws[wn + nt*16 + lm][q*8];
    #pragma unroll
    for (int mt = 0; mt < 4; mt++)
      #pragma unroll
      for (int nt = 0; nt < 4; nt++)
        acc[mt][nt] = MFMA(af[mt], bf[nt], acc[mt][nt]);
    __syncthreads();
  }
  #pragma unroll
  for (int nt = 0; nt < 4; nt++){
    const int n = n0 + wn + nt*16 + lm;
    const float bs = blv[n];
    #pragma unroll
    for (int mt = 0; mt < 4; mt++){
      const int mb = m0 + wm + mt*16;
      f32x4 c = acc[mt][nt];
      float part = 0.f;
      #pragma unroll
      for (int rr = 0; rr < 4; rr++){
        const int ml = (mb - m0) + (q << 2) + rr;
        float sg = 1.f / (1.f + __expf(-(c[rr] + bs)));
        part += als[ml] * sg;
      }
      part += __shfl_xor(part, 16, 64);
      if ((q & 1) == 0){
        const int srow = (mb >> 3) + (q >> 1);
        out[(size_t)srow * D + n] = part;
      }
    }
  }
}

// ================= orchestration =================
extern "C" void kernel_launch(void* const* d_in, const int* in_sizes, int n_in,
                              void* d_out, int out_size, void* d_ws, size_t ws_size,
                              hipStream_t stream) {
  const float* q_emb  = (const float*)d_in[0];
  const float* qa_emb = (const float*)d_in[1];
  const float* Wq1 = (const float*)d_in[2],  *bq1 = (const float*)d_in[3];
  const float* Wv1 = (const float*)d_in[4],  *bv1 = (const float*)d_in[5];
  const float* Wo1 = (const float*)d_in[6],  *bo1 = (const float*)d_in[7];
  const float* g1  = (const float*)d_in[8],  *ls1 = (const float*)d_in[9],  *lb1 = (const float*)d_in[10];
  const float* Wq2 = (const float*)d_in[11], *bq2 = (const float*)d_in[12];
  const float* Wv2 = (const float*)d_in[13], *bv2 = (const float*)d_in[14];
  const float* Wo2 = (const float*)d_in[15], *bo2 = (const float*)d_in[16];
  const float* g2  = (const float*)d_in[17], *ls2 = (const float*)d_in[18], *lb2 = (const float*)d_in[19];
  const float* Wq3 = (const float*)d_in[20], *bq3 = (const float*)d_in[21];
  const float* Wk3 = (const float*)d_in[22], *bk3 = (const float*)d_in[23];
  const float* Wv3 = (const float*)d_in[24], *bv3 = (const float*)d_in[25];
  const float* Wo3 = (const float*)d_in[26], *bo3 = (const float*)d_in[27];
  const float* g3  = (const float*)d_in[28], *ls3 = (const float*)d_in[29], *lb3 = (const float*)d_in[30];
  const float* know = (const float*)d_in[31];
  const float* Wlk  = (const float*)d_in[32], *b_lk = (const float*)d_in[33];
  const float* Wlv  = (const float*)d_in[34], *b_lv = (const float*)d_in[35];
  float* outp = (float*)d_out;

  const size_t NSD = (size_t)BB * S * D;   // 2,097,152
  unsigned short* p = (unsigned short*)d_ws;
  unsigned short* qk1b = p; p += NSD;
  unsigned short* v1b  = p; p += NSD;
  unsigned short* qk2b = p; p += NSD;
  unsigned short* v2b  = p; p += NSD;
  unsigned short* k3b  = p; p += NSD;
  unsigned short* v3b  = p; p += NSD;
  unsigned short* ctx1b= p; p += NSD;
  unsigned short* ctx2b= p; p += NSD;
  unsigned short* ctx3b= p; p += NSD;
  unsigned short* xqb  = p; p += NSD;
  unsigned short* xab  = p; p += NSD;
  unsigned short* hqb  = p; p += NSD;
  unsigned short* hab  = p; p += NSD;
  unsigned short* hfb  = p; p += NSD;
  unsigned short* vt1  = p; p += NSD;   // [32][64][1024]
  unsigned short* vt2  = p; p += NSD;
  unsigned short* vt3  = p; p += NSD;
  unsigned short* wb   = p; p += (size_t)9 * D * D;
  unsigned short* wlvb = p; p += (size_t)D * DKH;
  float* yv0   = (float*)p;
  float* yv1   = yv0 + NSD;
  float* q3    = yv1 + NSD;
  float* keyt  = q3 + 512;
  float* c3    = keyt + 4096;
  float* alpha = c3 + (size_t)BB * H * S;

  unsigned short* Wq1b = wb + 0*(size_t)D*D;
  unsigned short* Wv1b = wb + 1*(size_t)D*D;
  unsigned short* Wo1b = wb + 2*(size_t)D*D;
  unsigned short* Wq2b = wb + 3*(size_t)D*D;
  unsigned short* Wv2b = wb + 4*(size_t)D*D;
  unsigned short* Wo2b = wb + 5*(size_t)D*D;
  unsigned short* Wk3b = wb + 6*(size_t)D*D;
  unsigned short* Wv3b = wb + 7*(size_t)D*D;
  unsigned short* Wo3b = wb + 8*(size_t)D*D;

  // ---- conversions ----
  CvtJobs jb;
  jb.s[0] = q_emb;  jb.d[0] = xqb;  jb.n[0] = (int)NSD;
  jb.s[1] = qa_emb; jb.d[1] = xab;  jb.n[1] = (int)NSD;
  jb.s[2] = Wq1; jb.d[2] = Wq1b; jb.n[2] = D*D;
  jb.s[3] = Wv1; jb.d[3] = Wv1b; jb.n[3] = D*D;
  jb.s[4] = Wo1; jb.d[4] = Wo1b; jb.n[4] = D*D;
  jb.s[5] = Wq2; jb.d[5] = Wq2b; jb.n[5] = D*D;
  jb.s[6] = Wv2; jb.d[6] = Wv2b; jb.n[6] = D*D;
  jb.s[7] = Wo2; jb.d[7] = Wo2b; jb.n[7] = D*D;
  jb.s[8] = Wk3; jb.d[8] = Wk3b; jb.n[8] = D*D;
  jb.s[9] = Wv3; jb.d[9] = Wv3b; jb.n[9] = D*D;
  jb.s[10] = Wo3; jb.d[10] = Wo3b; jb.n[10] = D*D;
  jb.s[11] = Wlv; jb.d[11] = wlvb; jb.n[11] = D*DKH;
  cvt_all<<<dim3(256, 12), 256, 0, stream>>>(jb);

  // ---- blocks 1&2: projections (z=4) ----
  {
    GemmJobs g;
    g.A[0]=xqb; g.W[0]=Wq1b; g.bias[0]=bq1; g.C[0]=qk1b;
    g.A[1]=xqb; g.W[1]=Wv1b; g.bias[1]=bv1; g.C[1]=v1b;
    g.A[2]=xab; g.W[2]=Wq2b; g.bias[2]=bq2; g.C[2]=qk2b;
    g.A[3]=xab; g.W[3]=Wv2b; g.bias[3]=bv2; g.C[3]=v2b;
    mfma_gemm_b<1><<<dim3(4, 32, 4), 256, 0, stream>>>(g);
  }
  { VTArgs a; a.v[0]=v1b; a.v[1]=v2b; a.vt[0]=vt1; a.vt[1]=vt2; a.nz=2;
    vt_kernel<<<dim3(1024), 256, 0, stream>>>(a); }
  { FAArgs a;
    a.qk[0]=qk1b; a.qk[1]=qk2b; a.vt[0]=vt1; a.vt[1]=vt2;
    a.ctx[0]=ctx1b; a.ctx[1]=ctx2b; a.g[0]=g1; a.g[1]=g2;
    a.c3=nullptr; a.diag=0; a.zero_pad=0; a.nz=2;
    fused_attn<0><<<dim3(4096), 256, 0, stream>>>(a); }
  {
    GemmJobs g;
    g.A[0]=ctx1b; g.W[0]=Wo1b; g.bias[0]=bo1; g.C[0]=yv0;
    g.A[1]=ctx2b; g.W[1]=Wo2b; g.bias[1]=bo2; g.C[1]=yv1;
    g.A[2]=ctx1b; g.W[2]=Wo1b; g.bias[2]=bo1; g.C[2]=yv0;
    g.A[3]=ctx1b; g.W[3]=Wo1b; g.bias[3]=bo1; g.C[3]=yv0;
    mfma_gemm_b<0><<<dim3(4, 32, 2), 256, 0, stream>>>(g);
  }
  {
    LNJobs lj;
    lj.resid[0]=q_emb;  lj.y[0]=yv0; lj.ls[0]=ls1; lj.lb[0]=lb1; lj.out[0]=hqb; lj.bcast[0]=0;
    lj.resid[1]=qa_emb; lj.y[1]=yv1; lj.ls[1]=ls2; lj.lb[1]=lb2; lj.out[1]=hab; lj.bcast[1]=0;
    ln_residual_b<<<dim3(BB*S, 2), 256, 0, stream>>>(lj);
  }

  // ---- block 3 ----
  know_kernel<<<144, 256, 0, stream>>>(know, Wq3, bq3, q3, Wlk, b_lk, keyt);
  {
    GemmJobs g;
    g.A[0]=hqb; g.W[0]=Wk3b; g.bias[0]=bk3; g.C[0]=k3b;
    g.A[1]=hab; g.W[1]=Wv3b; g.bias[1]=bv3; g.C[1]=v3b;
    g.A[2]=hqb; g.W[2]=Wk3b; g.bias[2]=bk3; g.C[2]=k3b;
    g.A[3]=hqb; g.W[3]=Wk3b; g.bias[3]=bk3; g.C[3]=k3b;
    mfma_gemm_b<1><<<dim3(4, 32, 2), 256, 0, stream>>>(g);
  }
  { VTArgs a; a.v[0]=v3b; a.v[1]=v3b; a.vt[0]=vt3; a.vt[1]=vt3; a.nz=1;
    vt_kernel<<<dim3(512), 256, 0, stream>>>(a); }
  scores3_kernel<<<128, 256, 0, stream>>>(q3, k3b, c3);
  { FAArgs a;
    a.qk[0]=k3b; a.qk[1]=k3b; a.vt[0]=vt3; a.vt[1]=vt3;
    a.ctx[0]=ctx3b; a.ctx[1]=ctx3b; a.g[0]=g3; a.g[1]=g3;
    a.c3=c3; a.diag=-1; a.zero_pad=1; a.nz=1;
    fused_attn<1><<<dim3(2048), 256, 0, stream>>>(a); }
  {
    GemmJobs g;
    g.A[0]=ctx3b; g.W[0]=Wo3b; g.bias[0]=bo3; g.C[0]=yv0;
    g.A[1]=ctx3b; g.W[1]=Wo3b; g.bias[1]=bo3; g.C[1]=yv0;
    g.A[2]=ctx3b; g.W[2]=Wo3b; g.bias[2]=bo3; g.C[2]=yv0;
    g.A[3]=ctx3b; g.W[3]=Wo3b; g.bias[3]=bo3; g.C[3]=yv0;
    mfma_gemm_b<0><<<dim3(4, 32, 1), 256, 0, stream>>>(g);
  }
  {
    LNJobs lj;
    lj.resid[0]=know; lj.y[0]=yv0; lj.ls[0]=ls3; lj.lb[0]=lb3; lj.out[0]=hfb; lj.bcast[0]=1;
    lj.resid[1]=know; lj.y[1]=yv0; lj.ls[1]=ls3; lj.lb[1]=lb3; lj.out[1]=hfb; lj.bcast[1]=1;
    ln_residual_b<<<dim3(BB*S, 1), 256, 0, stream>>>(lj);
  }

  // ---- final combine ----
  alphas_kernel<<<1024, 256, 0, stream>>>(keyt, q_emb, alpha);
  val_fused<<<dim3(4, 256), 256, 0, stream>>>(hfb, wlvb, b_lv, alpha, outp);
}

// Round 8
// 435.845 us; speedup vs baseline: 1.0043x; 1.0043x over previous
//
#include <hip/hip_runtime.h>
#include <math.h>

#define BB 4
#define S 1024
#define D 512
#define H 8
#define DKH 64

#define ATT_LD 1032   // att row stride (shorts): 516 dwords == 4 mod 32 (2-way = free)
#define LOG2E 1.4426950408889634f
#define PIDX(j) ((j) + ((j) >> 3))   // bank-staggered prefix-table index

typedef __attribute__((ext_vector_type(8))) short bf16x8;
typedef __attribute__((ext_vector_type(4))) float f32x4;

#if __has_builtin(__builtin_amdgcn_exp2f)
#define EXP2(x) __builtin_amdgcn_exp2f(x)
#else
#define EXP2(x) exp2f(x)
#endif
#if __has_builtin(__builtin_amdgcn_sqrtf)
#define SQRTF(x) __builtin_amdgcn_sqrtf(x)
#else
#define SQRTF(x) sqrtf(x)
#endif
#if __has_builtin(__builtin_amdgcn_rcpf)
#define RCPF(x) __builtin_amdgcn_rcpf(x)
#else
#define RCPF(x) (1.0f / (x))
#endif

__device__ __forceinline__ unsigned short f2bf(float f){
  unsigned int u = __float_as_uint(f);
  u += 0x7FFFu + ((u >> 16) & 1u);
  return (unsigned short)(u >> 16);
}
__device__ __forceinline__ unsigned short f2bf_rhu(float f){
  return (unsigned short)((__float_as_uint(f) + 0x8000u) >> 16);
}
__device__ __forceinline__ unsigned int pk_rhu(float lo, float hi){
  unsigned int a = __float_as_uint(lo) + 0x8000u;
  unsigned int b = __float_as_uint(hi) + 0x8000u;
#if __has_builtin(__builtin_amdgcn_perm)
  return __builtin_amdgcn_perm(b, a, 0x07060302u);
#else
  return (a >> 16) | (b & 0xffff0000u);
#endif
}
__device__ __forceinline__ float bf2f(unsigned int v){
  return __uint_as_float(v << 16);
}
__device__ __forceinline__ f32x4 MFMA(bf16x8 a, bf16x8 b, f32x4 c){
  return __builtin_amdgcn_mfma_f32_16x16x32_bf16(a, b, c, 0, 0, 0);
}
__device__ __forceinline__ void gl_lds16(const void* g, void* l){
  __builtin_amdgcn_global_load_lds(
      (const __attribute__((address_space(1))) void*)g,
      (__attribute__((address_space(3))) void*)l, 16, 0, 0);
}

// ---- DPP cross-lane (pure VALU pipe, no ds_bpermute latency) ----
template<int CTRL>
__device__ __forceinline__ float dppadd(float v){
  int s = __builtin_amdgcn_update_dpp(0, __float_as_int(v), CTRL, 0xf, 0xf, true);
  return v + __int_as_float(s);
}
__device__ __forceinline__ float rdl(float v, int l){
  return __int_as_float(__builtin_amdgcn_readlane(__float_as_int(v), l));
}
// inclusive 64-lane prefix (order-exact) + total, via 16-lane row scans + row offsets
__device__ __forceinline__ void wave_scan64(float v, int lane, float& incl, float& total){
  float r = dppadd<0x111>(v);   // row_shr:1
  r = dppadd<0x112>(r);         // row_shr:2
  r = dppadd<0x114>(r);         // row_shr:4
  r = dppadd<0x118>(r);         // row_shr:8
  float t0 = rdl(r, 15), t1 = rdl(r, 31), t2 = rdl(r, 47), t3 = rdl(r, 63);
  const int row = lane >> 4;
  float off = (row > 0 ? t0 : 0.f) + (row > 1 ? t1 : 0.f) + (row > 2 ? t2 : 0.f);
  incl = r + off;
  total = (t0 + t1) + (t2 + t3);
}
__device__ __forceinline__ float wave_sum64(float v){
  float r = dppadd<0x111>(v);
  r = dppadd<0x112>(r);
  r = dppadd<0x114>(r);
  r = dppadd<0x118>(r);
  return (rdl(r, 15) + rdl(r, 31)) + (rdl(r, 47) + rdl(r, 63));
}

__device__ __forceinline__ float blk_sum(float* r, int t, float v){
  r[t] = v; __syncthreads();
  for (int s = 128; s > 0; s >>= 1){
    if (t < s) r[t] += r[t + s];
    __syncthreads();
  }
  float res = r[0]; __syncthreads();
  return res;
}

// ================= batched projection GEMM (M=4096,N=512,K=512) =================
struct GemmJobs {
  const unsigned short* A[4];
  const unsigned short* W[4];
  const float* bias[4];
  void* C[4];
};
template<int OUTBF>
__global__ __launch_bounds__(256) void mfma_gemm_b(GemmJobs jb)
{
  __shared__ __align__(16) short As[128][32];
  __shared__ __align__(16) short Ws[128][32];
  const int t = threadIdx.x;
  const int z = blockIdx.z;
  const int n0 = blockIdx.x * 128, m0 = blockIdx.y * 128;
  const unsigned short* A = jb.A[z];
  const unsigned short* W = jb.W[z];
  const float* bias = jb.bias[z];
  const int w = t >> 6, lane = t & 63;
  const int wm = (w >> 1) << 6, wn = (w & 1) << 6;
  const int lm = lane & 15, q = lane >> 4;
  const int r = t >> 2, cc = (t & 3) << 3;
  char* ldsA = ((char*)&As[0][0]) + w * 1024;
  char* ldsW = ((char*)&Ws[0][0]) + w * 1024;
  f32x4 acc[4][4];
  #pragma unroll
  for (int a_ = 0; a_ < 4; a_++)
    #pragma unroll
    for (int b_ = 0; b_ < 4; b_++)
      acc[a_][b_] = (f32x4){0.f, 0.f, 0.f, 0.f};
  for (int k0 = 0; k0 < D; k0 += 32){
    gl_lds16(&A[(size_t)(m0 + r)      * D + k0 + cc], ldsA);
    gl_lds16(&A[(size_t)(m0 + r + 64) * D + k0 + cc], ldsA + 4096);
    gl_lds16(&W[(size_t)(n0 + r)      * D + k0 + cc], ldsW);
    gl_lds16(&W[(size_t)(n0 + r + 64) * D + k0 + cc], ldsW + 4096);
    __syncthreads();
    bf16x8 af[4], bf[4];
    #pragma unroll
    for (int mt = 0; mt < 4; mt++) af[mt] = *(const bf16x8*)&As[wm + mt*16 + lm][q*8];
    #pragma unroll
    for (int nt = 0; nt < 4; nt++) bf[nt] = *(const bf16x8*)&Ws[wn + nt*16 + lm][q*8];
    #pragma unroll
    for (int mt = 0; mt < 4; mt++)
      #pragma unroll
      for (int nt = 0; nt < 4; nt++)
        acc[mt][nt] = MFMA(af[mt], bf[nt], acc[mt][nt]);
    __syncthreads();
  }
  #pragma unroll
  for (int nt = 0; nt < 4; nt++){
    const int n = n0 + wn + nt*16 + lm;
    const float bs = bias[n];
    #pragma unroll
    for (int mt = 0; mt < 4; mt++){
      const int mb = m0 + wm + mt*16 + (q << 2);
      f32x4 c = acc[mt][nt];
      #pragma unroll
      for (int rr = 0; rr < 4; rr++){
        float vv = c[rr] + bs;
        if (OUTBF)
          ((unsigned short*)jb.C[z])[(size_t)(mb + rr) * D + n] = f2bf(vv);
        else
          ((float*)jb.C[z])[(size_t)(mb + rr) * D + n] = vv;
      }
    }
  }
}

// ================= V transpose: VT[bh][64][S] from V[b][S][D] =================
// XCD-pinned 1D grid: xcd = bh & 7 (same invariant as fused_attn) so the VT
// tile is written into the L2 of the XCD that will read it.
#define KS_LD 66
struct VTArgs { const unsigned short* v[2]; unsigned short* vt[2]; int nz; };
__global__ __launch_bounds__(256) void vt_kernel(VTArgs a)
{
  __shared__ unsigned short tile[64 * KS_LD];
  const int lin = blockIdx.x;
  const int xcd = lin & 7, slot = lin >> 3;
  const int j0 = (slot & 15) * 64;
  const int set = slot >> 4;
  const int z   = (a.nz == 2) ? (set & 1)  : 0;
  const int grp = (a.nz == 2) ? (set >> 1) : set;
  const int bh = xcd + 8 * grp, b = bh >> 3, h = bh & 7;
  const int t = threadIdx.x;
  const unsigned short* vp = a.v[z];
  unsigned short* vtp = a.vt[z] + (size_t)bh * 64 * S;
  #pragma unroll
  for (int p = 0; p < 2; p++){
    int lin2 = t + p * 256, row = lin2 >> 3, c8 = (lin2 & 7) << 3;
    *(uint4*)&tile[row * KS_LD + c8] =
      *(const uint4*)&vp[((size_t)b * S + j0 + row) * D + h * DKH + c8];
  }
  __syncthreads();
  #pragma unroll
  for (int p = 0; p < 2; p++){
    int lin2 = t + p * 256, d = lin2 >> 3, c8 = (lin2 & 7) << 3;
    unsigned short tmp[8];
    #pragma unroll
    for (int jx = 0; jx < 8; jx++) tmp[jx] = tile[(c8 + jx) * KS_LD + d];
    *(uint4*)&vtp[(size_t)d * S + j0 + c8] = *(const uint4*)tmp;
  }
}

// ================= fused attention: scores -> decay -> AV =================
// 16-row i-blocks; att (unnormalized pp) in LDS; row scale applied in phase 3.
// XCD-pinned 1D grid (grid = 8*64*4*nz blocks, 256 threads).
// C3 mode: per-(b,h) masked prefix is row-independent -> build a shared prefix
// table Ptab ONCE per block (one wave, one scan); each row's cumsum/scans
// (~600cy) become LDS lookups P[min(j,jmax)]. Bank-staggered via PIDX.
// Phases 1/3: 4-deep global prefetch (2 iterations ahead).
struct FAArgs {
  const unsigned short* qk[2];   // q==k source (bf16, [b][S][D])
  const unsigned short* vt[2];   // VT (bf16, [bh][64][S])
  unsigned short* ctx[2];        // out (bf16, [b][S][D])
  const float* g[2];
  const float* c3;               // fp32 [b][h][S] (C3 mode)
  int diag, zero_pad, nz;
};
template<int C3>
__global__ __launch_bounds__(256, 4) void fused_attn(FAArgs a)
{
  __shared__ __align__(16) unsigned short att[16 * ATT_LD];   // 33,024 B
  __shared__ float ls2s[16];                                   // per-row inv2
  __shared__ float Ptab[1152];                                 // C3 prefix (staggered)
  const int t = threadIdx.x;
  const int lin = blockIdx.x;
  const int xcd = lin & 7;
  const int slot = lin >> 3;
  const int i0 = (slot & 63) * 16;
  const int set = slot >> 6;
  const int z   = (a.nz == 2) ? (set & 1)  : 0;
  const int grp = (a.nz == 2) ? (set >> 1) : set;
  const int bh = xcd + 8 * grp, b = bh >> 3, h = bh & 7;
  const int w = t >> 6, lane = t & 63, lm = lane & 15, q = lane >> 4;
  const unsigned short* qkp = a.qk[z];
  const unsigned short* vtp = a.vt[z] + (size_t)bh * 64 * S;
  unsigned short* ctxp = a.ctx[z];
  float gm2;
  { float gv = a.g[z][h];
    gm2 = -((gv > 20.f) ? gv : log1pf(expf(gv))) * LOG2E; }   // log2-space gamma

  // ---------- phase 1: scores tile [16 x 1024] -> att (bf16), 4-deep prefetch ----------
  if (!C3){
    const size_t rowbase = (size_t)b * S;
    bf16x8 af0 = *(const bf16x8*)&qkp[(rowbase + i0 + lm) * D + h * DKH + q*8];
    bf16x8 af1 = *(const bf16x8*)&qkp[(rowbase + i0 + lm) * D + h * DKH + 32 + q*8];
    size_t k0a = (rowbase + 0  + w*16 + lm) * D + h * DKH;
    size_t k1a = (rowbase + 64 + w*16 + lm) * D + h * DKH;
    bf16x8 c0a = *(const bf16x8*)&qkp[k0a + q*8];
    bf16x8 c0b = *(const bf16x8*)&qkp[k0a + 32 + q*8];
    bf16x8 c1a = *(const bf16x8*)&qkp[k1a + q*8];
    bf16x8 c1b = *(const bf16x8*)&qkp[k1a + 32 + q*8];
    for (int jc = 0; jc < S; jc += 64){
      bf16x8 na, nb;
      if (jc + 128 < S){
        size_t kb2 = (rowbase + jc + 128 + w*16 + lm) * D + h * DKH;
        na = *(const bf16x8*)&qkp[kb2 + q*8];
        nb = *(const bf16x8*)&qkp[kb2 + 32 + q*8];
      }
      f32x4 acc = (f32x4){0.f, 0.f, 0.f, 0.f};
      acc = MFMA(af0, c0a, acc);
      acc = MFMA(af1, c0b, acc);
      #pragma unroll
      for (int rr = 0; rr < 4; rr++)
        att[(q*4 + rr) * ATT_LD + jc + w*16 + lm] = f2bf_rhu(acc[rr] * 0.125f);
      c0a = c1a; c0b = c1b; c1a = na; c1b = nb;
    }
  }

  // ---------- C3: build shared prefix table (wave 0), hoist c in row layout ----------
  float cHA[8], cHB[8];
  if (C3){
    const float* c3p = a.c3 + ((size_t)b * H + h) * S;
    if (w == 0){
      float e[16]; float run = 0.f;
      float4 f0 = *(const float4*)&c3p[lane*16];
      float4 f1 = *(const float4*)&c3p[lane*16 + 4];
      float4 f2 = *(const float4*)&c3p[lane*16 + 8];
      float4 f3 = *(const float4*)&c3p[lane*16 + 12];
      e[0]=f0.x; e[1]=f0.y; e[2]=f0.z; e[3]=f0.w;
      e[4]=f1.x; e[5]=f1.y; e[6]=f1.z; e[7]=f1.w;
      e[8]=f2.x; e[9]=f2.y; e[10]=f2.z; e[11]=f2.w;
      e[12]=f3.x; e[13]=f3.y; e[14]=f3.z; e[15]=f3.w;
      float loc[16];
      #pragma unroll
      for (int k = 0; k < 16; k++){ run += EXP2(e[k] * LOG2E); loc[k] = run; }
      float incl, tot;
      wave_scan64(run, lane, incl, tot);
      const float off = incl - run;   // exclusive prefix of lane totals
      #pragma unroll
      for (int k = 0; k < 16; k++) Ptab[PIDX(lane*16 + k)] = loc[k] + off;
    }
    float4 x0 = *(const float4*)&c3p[lane*8];
    float4 x1 = *(const float4*)&c3p[lane*8 + 4];
    float4 y0 = *(const float4*)&c3p[512 + lane*8];
    float4 y1 = *(const float4*)&c3p[512 + lane*8 + 4];
    cHA[0]=x0.x*LOG2E; cHA[1]=x0.y*LOG2E; cHA[2]=x0.z*LOG2E; cHA[3]=x0.w*LOG2E;
    cHA[4]=x1.x*LOG2E; cHA[5]=x1.y*LOG2E; cHA[6]=x1.z*LOG2E; cHA[7]=x1.w*LOG2E;
    cHB[0]=y0.x*LOG2E; cHB[1]=y0.y*LOG2E; cHB[2]=y0.z*LOG2E; cHB[3]=y0.w*LOG2E;
    cHB[4]=y1.x*LOG2E; cHB[5]=y1.y*LOG2E; cHB[6]=y1.z*LOG2E; cHB[7]=y1.w*LOG2E;
  }
  __syncthreads();

  // ---------- phase 2: decay + double softmax, wave-per-row (4 rows/wave) ----------
  const int jA0 = lane * 8, jB0 = 512 + lane * 8;

  for (int rloc = 0; rloc < 4; rloc++){
    const int rl = w*4 + rloc;
    const int i = i0 + rl;
    unsigned short* rowp = &att[rl * ATT_LD];
    if (C3 && a.zero_pad && i == 0){
      uint4 zz = make_uint4(0u,0u,0u,0u);
      *(uint4*)&rowp[jA0] = zz;
      *(uint4*)&rowp[jB0] = zz;
      if (lane == 0) ls2s[0] = 1.f;
      continue;
    }
    const int jmax = i + a.diag;
    float pl[16];
    float ls2 = 0.f;

    if (C3){
      // prefix-table path: no cumsum, no scans
      const float T = Ptab[PIDX(jmax)];
      const float inv1 = RCPF(T);
      const float fiA = (float)(i - jA0);
      const float fiB = (float)(i - jB0);
      #pragma unroll
      for (int k = 0; k < 8; k++){
        const int j = jA0 + k;
        const int jc2 = (j < jmax) ? j : jmax;
        float Pj = Ptab[PIDX(jc2)];
        float remn = (T - Pj) * inv1;
        float pos  = fabsf(fiA - (float)k);
        float dist = SQRTF(fmaxf(remn * pos, 0.f));
        float eff  = fmaxf(EXP2(gm2 * dist), 1e-5f);
        float pp   = EXP2(cHA[k] * eff);
        ls2 += pp; pl[k] = pp;
      }
      #pragma unroll
      for (int k = 0; k < 8; k++){
        const int j = jB0 + k;
        const int jc2 = (j < jmax) ? j : jmax;
        float Pj = Ptab[PIDX(jc2)];
        float remn = (T - Pj) * inv1;
        float pos  = fabsf(fiB - (float)k);
        float dist = SQRTF(fmaxf(remn * pos, 0.f));
        float eff  = fmaxf(EXP2(gm2 * dist), 1e-5f);
        float pp   = EXP2(cHB[k] * eff);
        ls2 += pp; pl[8+k] = pp;
      }
    } else {
      const bool skipB = (jmax < 512);     // wave-uniform
      float cA[8], cB[8];
      uint4 uAv = *(const uint4*)&rowp[jA0];
      uint4 uBv = *(const uint4*)&rowp[jB0];
      unsigned int ua[4] = {uAv.x, uAv.y, uAv.z, uAv.w};
      unsigned int ub[4] = {uBv.x, uBv.y, uBv.z, uBv.w};
      #pragma unroll
      for (int mel = 0; mel < 4; mel++){
        cA[mel*2]     = bf2f(ua[mel] & 0xffffu) * LOG2E;
        cA[mel*2 + 1] = bf2f(ua[mel] >> 16) * LOG2E;
        cB[mel*2]     = bf2f(ub[mel] & 0xffffu) * LOG2E;
        cB[mel*2 + 1] = bf2f(ub[mel] >> 16) * LOG2E;
      }
      float runA = 0.f;
      #pragma unroll
      for (int k = 0; k < 8; k++){
        float e = (jA0 + k <= jmax) ? EXP2(cA[k]) : 0.f;
        runA += e; pl[k] = runA;
      }
      float sA, TA;
      wave_scan64(runA, lane, sA, TA);
      float T = TA, sB = 0.f, runB = 0.f, TB = 0.f;
      if (!skipB){
        #pragma unroll
        for (int k = 0; k < 8; k++){
          float e = (jB0 + k <= jmax) ? EXP2(cB[k]) : 0.f;
          runB += e; pl[8+k] = runB;
        }
        wave_scan64(runB, lane, sB, TB);
        T = TA + TB;
      }
      const float inv1 = RCPF(T);
      const float cbaseA = (T - (sA - runA)) * inv1;
      const float fiA = (float)(i - jA0);
      #pragma unroll
      for (int k = 0; k < 8; k++){
        float remn = fmaf(-pl[k], inv1, cbaseA);
        float pos  = fabsf(fiA - (float)k);
        float dist = SQRTF(fmaxf(remn * pos, 0.f));
        float eff  = fmaxf(EXP2(gm2 * dist), 1e-5f);
        float pp   = EXP2(cA[k] * eff);
        ls2 += pp; pl[k] = pp;
      }
      if (!skipB){
        const float cbaseB = (T - (TA + sB - runB)) * inv1;
        const float fiB = (float)(i - jB0);
        #pragma unroll
        for (int k = 0; k < 8; k++){
          float remn = fmaf(-pl[8+k], inv1, cbaseB);
          float pos  = fabsf(fiB - (float)k);
          float dist = SQRTF(fmaxf(remn * pos, 0.f));
          float eff  = fmaxf(EXP2(gm2 * dist), 1e-5f);
          float pp   = EXP2(cB[k] * eff);
          ls2 += pp; pl[8+k] = pp;
        }
      } else {
        #pragma unroll
        for (int k = 0; k < 8; k++){
          float e2 = EXP2(cB[k]);
          pl[8+k] = e2; ls2 += e2;
        }
      }
    }

    ls2 = wave_sum64(ls2);
    if (lane == 0) ls2s[rl] = RCPF(ls2);
    uint4 oA, oB;
    oA.x = pk_rhu(pl[0], pl[1]);
    oA.y = pk_rhu(pl[2], pl[3]);
    oA.z = pk_rhu(pl[4], pl[5]);
    oA.w = pk_rhu(pl[6], pl[7]);
    oB.x = pk_rhu(pl[8], pl[9]);
    oB.y = pk_rhu(pl[10], pl[11]);
    oB.z = pk_rhu(pl[12], pl[13]);
    oB.w = pk_rhu(pl[14], pl[15]);
    *(uint4*)&rowp[jA0] = oA;
    *(uint4*)&rowp[jB0] = oB;
  }
  __syncthreads();

  // ---------- phase 3: ctx = att @ V, 4-deep VT prefetch, scale by inv2 ----------
  f32x4 acc = (f32x4){0.f,0.f,0.f,0.f};
  const unsigned short* vrow = &vtp[(size_t)(w*16 + lm) * S];
  bf16x8 p0a = *(const bf16x8*)&vrow[q*8];
  bf16x8 p0b = *(const bf16x8*)&vrow[32 + q*8];
  bf16x8 p1a = *(const bf16x8*)&vrow[64 + q*8];
  bf16x8 p1b = *(const bf16x8*)&vrow[96 + q*8];
  for (int kc = 0; kc < S; kc += 64){
    bf16x8 na, nb;
    if (kc + 128 < S){
      na = *(const bf16x8*)&vrow[kc + 128 + q*8];
      nb = *(const bf16x8*)&vrow[kc + 160 + q*8];
    }
    bf16x8 a0 = *(const bf16x8*)&att[lm * ATT_LD + kc + q*8];
    bf16x8 a1 = *(const bf16x8*)&att[lm * ATT_LD + kc + 32 + q*8];
    acc = MFMA(a0, p0a, acc);
    acc = MFMA(a1, p0b, acc);
    p0a = p1a; p0b = p1b; p1a = na; p1b = nb;
  }
  #pragma unroll
  for (int rr = 0; rr < 4; rr++){
    const int rl = q*4 + rr;
    const float sc = ls2s[rl];
    const int row = i0 + rl;
    ctxp[((size_t)b * S + row) * D + h * DKH + w*16 + lm] = f2bf(acc[rr] * sc);
  }
}

// ================= residual + LayerNorm -> bf16 (batched) =================
struct LNJobs {
  const float* resid[2];
  const float* y[2];
  const float* ls[2];
  const float* lb[2];
  unsigned short* out[2];
  int bcast[2];
};
__global__ __launch_bounds__(256) void ln_residual_b(LNJobs j)
{
  const int z = blockIdx.y;
  const int r = blockIdx.x, t = threadIdx.x;
  __shared__ float red[256];
  const size_t base = (size_t)r * D;
  const float* resid = j.resid[z];
  const float* y = j.y[z];
  const int bcast = j.bcast[z];
  float r0 = bcast ? resid[t]       : resid[base + t];
  float r1 = bcast ? resid[t + 256] : resid[base + t + 256];
  float x0 = r0 + y[base + t];
  float x1 = r1 + y[base + t + 256];
  float mean = blk_sum(red, t, x0 + x1) * (1.0f / 512.0f);
  float d0 = x0 - mean, d1 = x1 - mean;
  float var = blk_sum(red, t, d0*d0 + d1*d1) * (1.0f / 512.0f);
  float inv = rsqrtf(var + 1e-5f);
  j.out[z][base + t]       = f2bf(d0 * inv * j.ls[z][t]       + j.lb[z][t]);
  j.out[z][base + t + 256] = f2bf(d1 * inv * j.ls[z][t + 256] + j.lb[z][t + 256]);
}

// ================= fp32 -> bf16 conversions =================
struct CvtJobs {
  const float* s[12];
  unsigned short* d[12];
  int n[12];
};
__global__ __launch_bounds__(256) void cvt_all(CvtJobs jb){
  const int z = blockIdx.y;
  const int n = jb.n[z];
  const float* s = jb.s[z];
  unsigned short* d = jb.d[z];
  for (int idx = blockIdx.x * 256 + threadIdx.x; idx < n; idx += gridDim.x * 256)
    d[idx] = f2bf(s[idx]);
}

// ================= know-derived small kernels (merged) =================
__global__ __launch_bounds__(256) void know_kernel(
    const float* __restrict__ know, const float* __restrict__ Wq3,
    const float* __restrict__ bq3, float* __restrict__ q3,
    const float* __restrict__ Wlk, const float* __restrict__ blk_,
    float* __restrict__ keyt)
{
  if (blockIdx.x < 128){
    const int wv = (blockIdx.x * 256 + threadIdx.x) >> 6;
    const int lane = threadIdx.x & 63;
    const float* wr = Wq3 + (size_t)wv * 512 + lane * 8;
    const float* kr = know + lane * 8;
    float4 w0 = *(const float4*)&wr[0], w1 = *(const float4*)&wr[4];
    float4 k0 = *(const float4*)&kr[0], k1 = *(const float4*)&kr[4];
    float p = w0.x*k0.x + w0.y*k0.y + w0.z*k0.z + w0.w*k0.w
            + w1.x*k1.x + w1.y*k1.y + w1.z*k1.z + w1.w*k1.w;
    p = wave_sum64(p);
    if (lane == 0) q3[wv] = p + bq3[wv];
  } else {
    int idx = (blockIdx.x - 128) * 256 + threadIdx.x;
    int h = idx >> 9, n = idx & 511;
    float acc = 0.f;
    for (int i = 0; i < 64; i++) acc += know[h * 64 + i] * Wlk[(size_t)n * 64 + i];
    keyt[idx] = 1.f / (1.f + __expf(-(acc + blk_[n])));
  }
}

__global__ __launch_bounds__(256) void scores3_kernel(
    const float* __restrict__ q3, const unsigned short* __restrict__ k3,
    float* __restrict__ c3)
{
  int idx = blockIdx.x * 256 + threadIdx.x;   // (b*H+h)*S + j
  int j  = idx & (S - 1);
  int bh = idx >> 10;
  int h  = bh & 7, b = bh >> 3;
  const unsigned short* kp = k3 + ((size_t)b * S + j) * D + h * DKH;
  const float* qp = q3 + h * DKH;
  float acc = 0.f;
  #pragma unroll
  for (int d8 = 0; d8 < 64; d8 += 8){
    uint4 u = *(const uint4*)&kp[d8];
    unsigned int uu[4] = {u.x, u.y, u.z, u.w};
    #pragma unroll
    for (int mel = 0; mel < 4; mel++){
      acc += qp[d8 + 2*mel]     * bf2f(uu[mel] & 0xffffu);
      acc += qp[d8 + 2*mel + 1] * bf2f(uu[mel] >> 16);
    }
  }
  c3[idx] = acc * 0.125f;
}

__global__ __launch_bounds__(256) void alphas_kernel(
    const float* __restrict__ keyt, const float* __restrict__ q_emb,
    float* __restrict__ alpha)
{
  const int row = blockIdx.x * 4 + (threadIdx.x >> 6);
  const int l = threadIdx.x & 63;
  const int h = l >> 3, sub = l & 7;
  const float* qr = q_emb + (size_t)row * D;
  const float* kt = keyt + h * D;
  float p = 0.f;
  for (int d = sub; d < D; d += 8) p += kt[d] * qr[d];
  p += __shfl_xor(p, 1, 64);
  p += __shfl_xor(p, 2, 64);
  p += __shfl_xor(p, 4, 64);
  float m = p;
  m = fmaxf(m, __shfl_xor(m, 8, 64));
  m = fmaxf(m, __shfl_xor(m, 16, 64));
  m = fmaxf(m, __shfl_xor(m, 32, 64));
  float e = __expf(p - m);
  float ssum = e;
  ssum += __shfl_xor(ssum, 8, 64);
  ssum += __shfl_xor(ssum, 16, 64);
  ssum += __shfl_xor(ssum, 32, 64);
  if (sub == 0) alpha[(size_t)row * H + h] = e / ssum;
}

// ================= fused val GEMM + sigmoid + alpha-combine =================
__global__ __launch_bounds__(256) void val_fused(
    const unsigned short* __restrict__ Ah,
    const unsigned short* __restrict__ Wv,
    const float* __restrict__ blv,
    const float* __restrict__ alpha,
    float* __restrict__ out)
{
  __shared__ __align__(16) short As[128][32];
  __shared__ __align__(16) short Ws[128][32];
  __shared__ float als[128];
  const int t = threadIdx.x;
  const int n0 = blockIdx.x * 128, m0 = blockIdx.y * 128;
  if (t < 128) als[t] = alpha[m0 + t];
  const int w = t >> 6, lane = t & 63;
  const int wm = (w >> 1) << 6, wn = (w & 1) << 6;
  const int lm = lane & 15, q = lane >> 4;
  const int r = t >> 2, cc = (t & 3) << 3;
  f32x4 acc[4][4];
  #pragma unroll
  for (int a_ = 0; a_ < 4; a_++)
    #pragma unroll
    for (int b_ = 0; b_ < 4; b_++)
      acc[a_][b_] = (f32x4){0.f, 0.f, 0.f, 0.f};
  for (int k0 = 0; k0 < 64; k0 += 32){
    *(uint4*)&As[r][cc]      = *(const uint4*)&Ah[(size_t)(m0 + r) * 64 + k0 + cc];
    *(uint4*)&As[r + 64][cc] = *(const uint4*)&Ah[(size_t)(m0 + r + 64) * 64 + k0 + cc];
    *(uint4*)&Ws[r][cc]      = *(const uint4*)&Wv[(size_t)(n0 + r) * 64 + k0 + cc];
    *(uint4*)&Ws[r + 64][cc] = *(const uint4*)&Wv[(size_t)(n0 + r + 64) * 64 + k0 + cc];
    __syncthreads();
    bf16x8 af[4], bf[4];
    #pragma unroll
    for (int mt = 0; mt < 4; mt++) af[mt] = *(const bf16x8*)&As[wm + mt*16 + lm][q*8];
    #pragma unroll
    for (int nt = 0; nt < 4; nt++) bf[nt] = *(const bf16x8*)&Ws[wn + nt*16 + lm][q*8];
    #pragma unroll
    for (int mt = 0; mt < 4; mt++)
      #pragma unroll
      for (int nt = 0; nt < 4; nt++)
        acc[mt][nt] = MFMA(af[mt], bf[nt], acc[mt][nt]);
    __syncthreads();
  }
  #pragma unroll
  for (int nt = 0; nt < 4; nt++){
    const int n = n0 + wn + nt*16 + lm;
    const float bs = blv[n];
    #pragma unroll
    for (int mt = 0; mt < 4; mt++){
      const int mb = m0 + wm + mt*16;
      f32x4 c = acc[mt][nt];
      float part = 0.f;
      #pragma unroll
      for (int rr = 0; rr < 4; rr++){
        const int ml = (mb - m0) + (q << 2) + rr;
        float sg = 1.f / (1.f + __expf(-(c[rr] + bs)));
        part += als[ml] * sg;
      }
      part += __shfl_xor(part, 16, 64);
      if ((q & 1) == 0){
        const int srow = (mb >> 3) + (q >> 1);
        out[(size_t)srow * D + n] = part;
      }
    }
  }
}

// ================= orchestration =================
extern "C" void kernel_launch(void* const* d_in, const int* in_sizes, int n_in,
                              void* d_out, int out_size, void* d_ws, size_t ws_size,
                              hipStream_t stream) {
  const float* q_emb  = (const float*)d_in[0];
  const float* qa_emb = (const float*)d_in[1];
  const float* Wq1 = (const float*)d_in[2],  *bq1 = (const float*)d_in[3];
  const float* Wv1 = (const float*)d_in[4],  *bv1 = (const float*)d_in[5];
  const float* Wo1 = (const float*)d_in[6],  *bo1 = (const float*)d_in[7];
  const float* g1  = (const float*)d_in[8],  *ls1 = (const float*)d_in[9],  *lb1 = (const float*)d_in[10];
  const float* Wq2 = (const float*)d_in[11], *bq2 = (const float*)d_in[12];
  const float* Wv2 = (const float*)d_in[13], *bv2 = (const float*)d_in[14];
  const float* Wo2 = (const float*)d_in[15], *bo2 = (const float*)d_in[16];
  const float* g2  = (const float*)d_in[17], *ls2 = (const float*)d_in[18], *lb2 = (const float*)d_in[19];
  const float* Wq3 = (const float*)d_in[20], *bq3 = (const float*)d_in[21];
  const float* Wk3 = (const float*)d_in[22], *bk3 = (const float*)d_in[23];
  const float* Wv3 = (const float*)d_in[24], *bv3 = (const float*)d_in[25];
  const float* Wo3 = (const float*)d_in[26], *bo3 = (const float*)d_in[27];
  const float* g3  = (const float*)d_in[28], *ls3 = (const float*)d_in[29], *lb3 = (const float*)d_in[30];
  const float* know = (const float*)d_in[31];
  const float* Wlk  = (const float*)d_in[32], *b_lk = (const float*)d_in[33];
  const float* Wlv  = (const float*)d_in[34], *b_lv = (const float*)d_in[35];
  float* outp = (float*)d_out;

  const size_t NSD = (size_t)BB * S * D;   // 2,097,152
  unsigned short* p = (unsigned short*)d_ws;
  unsigned short* qk1b = p; p += NSD;
  unsigned short* v1b  = p; p += NSD;
  unsigned short* qk2b = p; p += NSD;
  unsigned short* v2b  = p; p += NSD;
  unsigned short* k3b  = p; p += NSD;
  unsigned short* v3b  = p; p += NSD;
  unsigned short* ctx1b= p; p += NSD;
  unsigned short* ctx2b= p; p += NSD;
  unsigned short* ctx3b= p; p += NSD;
  unsigned short* xqb  = p; p += NSD;
  unsigned short* xab  = p; p += NSD;
  unsigned short* hqb  = p; p += NSD;
  unsigned short* hab  = p; p += NSD;
  unsigned short* hfb  = p; p += NSD;
  unsigned short* vt1  = p; p += NSD;   // [32][64][1024]
  unsigned short* vt2  = p; p += NSD;
  unsigned short* vt3  = p; p += NSD;
  unsigned short* wb   = p; p += (size_t)9 * D * D;
  unsigned short* wlvb = p; p += (size_t)D * DKH;
  float* yv0   = (float*)p;
  float* yv1   = yv0 + NSD;
  float* q3    = yv1 + NSD;
  float* keyt  = q3 + 512;
  float* c3    = keyt + 4096;
  float* alpha = c3 + (size_t)BB * H * S;

  unsigned short* Wq1b = wb + 0*(size_t)D*D;
  unsigned short* Wv1b = wb + 1*(size_t)D*D;
  unsigned short* Wo1b = wb + 2*(size_t)D*D;
  unsigned short* Wq2b = wb + 3*(size_t)D*D;
  unsigned short* Wv2b = wb + 4*(size_t)D*D;
  unsigned short* Wo2b = wb + 5*(size_t)D*D;
  unsigned short* Wk3b = wb + 6*(size_t)D*D;
  unsigned short* Wv3b = wb + 7*(size_t)D*D;
  unsigned short* Wo3b = wb + 8*(size_t)D*D;

  // ---- conversions ----
  CvtJobs jb;
  jb.s[0] = q_emb;  jb.d[0] = xqb;  jb.n[0] = (int)NSD;
  jb.s[1] = qa_emb; jb.d[1] = xab;  jb.n[1] = (int)NSD;
  jb.s[2] = Wq1; jb.d[2] = Wq1b; jb.n[2] = D*D;
  jb.s[3] = Wv1; jb.d[3] = Wv1b; jb.n[3] = D*D;
  jb.s[4] = Wo1; jb.d[4] = Wo1b; jb.n[4] = D*D;
  jb.s[5] = Wq2; jb.d[5] = Wq2b; jb.n[5] = D*D;
  jb.s[6] = Wv2; jb.d[6] = Wv2b; jb.n[6] = D*D;
  jb.s[7] = Wo2; jb.d[7] = Wo2b; jb.n[7] = D*D;
  jb.s[8] = Wk3; jb.d[8] = Wk3b; jb.n[8] = D*D;
  jb.s[9] = Wv3; jb.d[9] = Wv3b; jb.n[9] = D*D;
  jb.s[10] = Wo3; jb.d[10] = Wo3b; jb.n[10] = D*D;
  jb.s[11] = Wlv; jb.d[11] = wlvb; jb.n[11] = D*DKH;
  cvt_all<<<dim3(256, 12), 256, 0, stream>>>(jb);

  // ---- blocks 1&2: projections (z=4) ----
  {
    GemmJobs g;
    g.A[0]=xqb; g.W[0]=Wq1b; g.bias[0]=bq1; g.C[0]=qk1b;
    g.A[1]=xqb; g.W[1]=Wv1b; g.bias[1]=bv1; g.C[1]=v1b;
    g.A[2]=xab; g.W[2]=Wq2b; g.bias[2]=bq2; g.C[2]=qk2b;
    g.A[3]=xab; g.W[3]=Wv2b; g.bias[3]=bv2; g.C[3]=v2b;
    mfma_gemm_b<1><<<dim3(4, 32, 4), 256, 0, stream>>>(g);
  }
  { VTArgs a; a.v[0]=v1b; a.v[1]=v2b; a.vt[0]=vt1; a.vt[1]=vt2; a.nz=2;
    vt_kernel<<<dim3(1024), 256, 0, stream>>>(a); }
  { FAArgs a;
    a.qk[0]=qk1b; a.qk[1]=qk2b; a.vt[0]=vt1; a.vt[1]=vt2;
    a.ctx[0]=ctx1b; a.ctx[1]=ctx2b; a.g[0]=g1; a.g[1]=g2;
    a.c3=nullptr; a.diag=0; a.zero_pad=0; a.nz=2;
    fused_attn<0><<<dim3(4096), 256, 0, stream>>>(a); }
  {
    GemmJobs g;
    g.A[0]=ctx1b; g.W[0]=Wo1b; g.bias[0]=bo1; g.C[0]=yv0;
    g.A[1]=ctx2b; g.W[1]=Wo2b; g.bias[1]=bo2; g.C[1]=yv1;
    g.A[2]=ctx1b; g.W[2]=Wo1b; g.bias[2]=bo1; g.C[2]=yv0;
    g.A[3]=ctx1b; g.W[3]=Wo1b; g.bias[3]=bo1; g.C[3]=yv0;
    mfma_gemm_b<0><<<dim3(4, 32, 2), 256, 0, stream>>>(g);
  }
  {
    LNJobs lj;
    lj.resid[0]=q_emb;  lj.y[0]=yv0; lj.ls[0]=ls1; lj.lb[0]=lb1; lj.out[0]=hqb; lj.bcast[0]=0;
    lj.resid[1]=qa_emb; lj.y[1]=yv1; lj.ls[1]=ls2; lj.lb[1]=lb2; lj.out[1]=hab; lj.bcast[1]=0;
    ln_residual_b<<<dim3(BB*S, 2), 256, 0, stream>>>(lj);
  }

  // ---- block 3 ----
  know_kernel<<<144, 256, 0, stream>>>(know, Wq3, bq3, q3, Wlk, b_lk, keyt);
  {
    GemmJobs g;
    g.A[0]=hqb; g.W[0]=Wk3b; g.bias[0]=bk3; g.C[0]=k3b;
    g.A[1]=hab; g.W[1]=Wv3b; g.bias[1]=bv3; g.C[1]=v3b;
    g.A[2]=hqb; g.W[2]=Wk3b; g.bias[2]=bk3; g.C[2]=k3b;
    g.A[3]=hqb; g.W[3]=Wk3b; g.bias[3]=bk3; g.C[3]=k3b;
    mfma_gemm_b<1><<<dim3(4, 32, 2), 256, 0, stream>>>(g);
  }
  { VTArgs a; a.v[0]=v3b; a.v[1]=v3b; a.vt[0]=vt3; a.vt[1]=vt3; a.nz=1;
    vt_kernel<<<dim3(512), 256, 0, stream>>>(a); }
  scores3_kernel<<<128, 256, 0, stream>>>(q3, k3b, c3);
  { FAArgs a;
    a.qk[0]=k3b; a.qk[1]=k3b; a.vt[0]=vt3; a.vt[1]=vt3;
    a.ctx[0]=ctx3b; a.ctx[1]=ctx3b; a.g[0]=g3; a.g[1]=g3;
    a.c3=c3; a.diag=-1; a.zero_pad=1; a.nz=1;
    fused_attn<1><<<dim3(2048), 256, 0, stream>>>(a); }
  {
    GemmJobs g;
    g.A[0]=ctx3b; g.W[0]=Wo3b; g.bias[0]=bo3; g.C[0]=yv0;
    g.A[1]=ctx3b; g.W[1]=Wo3b; g.bias[1]=bo3; g.C[1]=yv0;
    g.A[2]=ctx3b; g.W[2]=Wo3b; g.bias[2]=bo3; g.C[2]=yv0;
    g.A[3]=ctx3b; g.W[3]=Wo3b; g.bias[3]=bo3; g.C[3]=yv0;
    mfma_gemm_b<0><<<dim3(4, 32, 1), 256, 0, stream>>>(g);
  }
  {
    LNJobs lj;
    lj.resid[0]=know; lj.y[0]=yv0; lj.ls[0]=ls3; lj.lb[0]=lb3; lj.out[0]=hfb; lj.bcast[0]=1;
    lj.resid[1]=know; lj.y[1]=yv0; lj.ls[1]=ls3; lj.lb[1]=lb3; lj.out[1]=hfb; lj.bcast[1]=1;
    ln_residual_b<<<dim3(BB*S, 1), 256, 0, stream>>>(lj);
  }

  // ---- final combine ----
  alphas_kernel<<<1024, 256, 0, stream>>>(keyt, q_emb, alpha);
  val_fused<<<dim3(4, 256), 256, 0, stream>>>(hfb, wlvb, b_lv, alpha, outp);
}

// Round 9
// 423.467 us; speedup vs baseline: 1.0337x; 1.0292x over previous
//
#include <hip/hip_runtime.h>
#include <math.h>

#define BB 4
#define S 1024
#define D 512
#define H 8
#define DKH 64

#define ATT_LD 1032   // att row stride (shorts): 516 dwords == 4 mod 32 (2-way = free)
#define LOG2E 1.4426950408889634f

typedef __attribute__((ext_vector_type(8))) short bf16x8;
typedef __attribute__((ext_vector_type(4))) float f32x4;

#if __has_builtin(__builtin_amdgcn_exp2f)
#define EXP2(x) __builtin_amdgcn_exp2f(x)
#else
#define EXP2(x) exp2f(x)
#endif
#if __has_builtin(__builtin_amdgcn_sqrtf)
#define SQRTF(x) __builtin_amdgcn_sqrtf(x)
#else
#define SQRTF(x) sqrtf(x)
#endif
#if __has_builtin(__builtin_amdgcn_rcpf)
#define RCPF(x) __builtin_amdgcn_rcpf(x)
#else
#define RCPF(x) (1.0f / (x))
#endif

__device__ __forceinline__ unsigned short f2bf(float f){
  unsigned int u = __float_as_uint(f);
  u += 0x7FFFu + ((u >> 16) & 1u);
  return (unsigned short)(u >> 16);
}
__device__ __forceinline__ unsigned short f2bf_rhu(float f){
  return (unsigned short)((__float_as_uint(f) + 0x8000u) >> 16);
}
__device__ __forceinline__ unsigned int pk_rhu(float lo, float hi){
  unsigned int a = __float_as_uint(lo) + 0x8000u;
  unsigned int b = __float_as_uint(hi) + 0x8000u;
#if __has_builtin(__builtin_amdgcn_perm)
  return __builtin_amdgcn_perm(b, a, 0x07060302u);
#else
  return (a >> 16) | (b & 0xffff0000u);
#endif
}
__device__ __forceinline__ float bf2f(unsigned int v){
  return __uint_as_float(v << 16);
}
__device__ __forceinline__ f32x4 MFMA(bf16x8 a, bf16x8 b, f32x4 c){
  return __builtin_amdgcn_mfma_f32_16x16x32_bf16(a, b, c, 0, 0, 0);
}
__device__ __forceinline__ void gl_lds16(const void* g, void* l){
  __builtin_amdgcn_global_load_lds(
      (const __attribute__((address_space(1))) void*)g,
      (__attribute__((address_space(3))) void*)l, 16, 0, 0);
}

// ---- DPP cross-lane (pure VALU pipe, no ds_bpermute latency) ----
template<int CTRL>
__device__ __forceinline__ float dppadd(float v){
  int s = __builtin_amdgcn_update_dpp(0, __float_as_int(v), CTRL, 0xf, 0xf, true);
  return v + __int_as_float(s);
}
__device__ __forceinline__ float rdl(float v, int l){
  return __int_as_float(__builtin_amdgcn_readlane(__float_as_int(v), l));
}
// inclusive 64-lane prefix (order-exact) + total, via 16-lane row scans + row offsets
__device__ __forceinline__ void wave_scan64(float v, int lane, float& incl, float& total){
  float r = dppadd<0x111>(v);   // row_shr:1
  r = dppadd<0x112>(r);         // row_shr:2
  r = dppadd<0x114>(r);         // row_shr:4
  r = dppadd<0x118>(r);         // row_shr:8
  float t0 = rdl(r, 15), t1 = rdl(r, 31), t2 = rdl(r, 47), t3 = rdl(r, 63);
  const int row = lane >> 4;
  float off = (row > 0 ? t0 : 0.f) + (row > 1 ? t1 : 0.f) + (row > 2 ? t2 : 0.f);
  incl = r + off;
  total = (t0 + t1) + (t2 + t3);
}
__device__ __forceinline__ float wave_sum64(float v){
  float r = dppadd<0x111>(v);
  r = dppadd<0x112>(r);
  r = dppadd<0x114>(r);
  r = dppadd<0x118>(r);
  return (rdl(r, 15) + rdl(r, 31)) + (rdl(r, 47) + rdl(r, 63));
}

// ================= batched projection GEMM (M=4096,N=512,K=512) =================
struct GemmJobs {
  const unsigned short* A[4];
  const unsigned short* W[4];
  const float* bias[4];
  void* C[4];
};
template<int OUTBF>
__global__ __launch_bounds__(256) void mfma_gemm_b(GemmJobs jb)
{
  __shared__ __align__(16) short As[128][32];
  __shared__ __align__(16) short Ws[128][32];
  const int t = threadIdx.x;
  const int z = blockIdx.z;
  const int n0 = blockIdx.x * 128, m0 = blockIdx.y * 128;
  const unsigned short* A = jb.A[z];
  const unsigned short* W = jb.W[z];
  const float* bias = jb.bias[z];
  const int w = t >> 6, lane = t & 63;
  const int wm = (w >> 1) << 6, wn = (w & 1) << 6;
  const int lm = lane & 15, q = lane >> 4;
  const int r = t >> 2, cc = (t & 3) << 3;
  char* ldsA = ((char*)&As[0][0]) + w * 1024;
  char* ldsW = ((char*)&Ws[0][0]) + w * 1024;
  f32x4 acc[4][4];
  #pragma unroll
  for (int a_ = 0; a_ < 4; a_++)
    #pragma unroll
    for (int b_ = 0; b_ < 4; b_++)
      acc[a_][b_] = (f32x4){0.f, 0.f, 0.f, 0.f};
  for (int k0 = 0; k0 < D; k0 += 32){
    gl_lds16(&A[(size_t)(m0 + r)      * D + k0 + cc], ldsA);
    gl_lds16(&A[(size_t)(m0 + r + 64) * D + k0 + cc], ldsA + 4096);
    gl_lds16(&W[(size_t)(n0 + r)      * D + k0 + cc], ldsW);
    gl_lds16(&W[(size_t)(n0 + r + 64) * D + k0 + cc], ldsW + 4096);
    __syncthreads();
    bf16x8 af[4], bf[4];
    #pragma unroll
    for (int mt = 0; mt < 4; mt++) af[mt] = *(const bf16x8*)&As[wm + mt*16 + lm][q*8];
    #pragma unroll
    for (int nt = 0; nt < 4; nt++) bf[nt] = *(const bf16x8*)&Ws[wn + nt*16 + lm][q*8];
    #pragma unroll
    for (int mt = 0; mt < 4; mt++)
      #pragma unroll
      for (int nt = 0; nt < 4; nt++)
        acc[mt][nt] = MFMA(af[mt], bf[nt], acc[mt][nt]);
    __syncthreads();
  }
  #pragma unroll
  for (int nt = 0; nt < 4; nt++){
    const int n = n0 + wn + nt*16 + lm;
    const float bs = bias[n];
    #pragma unroll
    for (int mt = 0; mt < 4; mt++){
      const int mb = m0 + wm + mt*16 + (q << 2);
      f32x4 c = acc[mt][nt];
      #pragma unroll
      for (int rr = 0; rr < 4; rr++){
        float vv = c[rr] + bs;
        if (OUTBF)
          ((unsigned short*)jb.C[z])[(size_t)(mb + rr) * D + n] = f2bf(vv);
        else
          ((float*)jb.C[z])[(size_t)(mb + rr) * D + n] = vv;
      }
    }
  }
}

// ================= V transpose (+ merged alphas role for nz=2) =================
// XCD-pinned for vt part; blocks >= vtblocks run the alphas combine (keyt ready
// because know_kernel is launched first).
#define KS_LD 66
struct VTArgs {
  const unsigned short* v[2]; unsigned short* vt[2]; int nz;
  int vtblocks;                 // blocks below this do VT; above do alphas
  const float* keyt; const float* q_emb; float* alpha;
};
__global__ __launch_bounds__(256) void vt_kernel(VTArgs a)
{
  __shared__ unsigned short tile[64 * KS_LD];
  if ((int)blockIdx.x >= a.vtblocks){
    // ---- alphas role: softmax over heads of keyt . q_emb ----
    const int row = (blockIdx.x - a.vtblocks) * 4 + (threadIdx.x >> 6);
    const int l = threadIdx.x & 63;
    const int h = l >> 3, sub = l & 7;
    const float* qr = a.q_emb + (size_t)row * D;
    const float* kt = a.keyt + h * D;
    float p = 0.f;
    for (int d = sub; d < D; d += 8) p += kt[d] * qr[d];
    p += __shfl_xor(p, 1, 64);
    p += __shfl_xor(p, 2, 64);
    p += __shfl_xor(p, 4, 64);
    float m = p;
    m = fmaxf(m, __shfl_xor(m, 8, 64));
    m = fmaxf(m, __shfl_xor(m, 16, 64));
    m = fmaxf(m, __shfl_xor(m, 32, 64));
    float e = __expf(p - m);
    float ssum = e;
    ssum += __shfl_xor(ssum, 8, 64);
    ssum += __shfl_xor(ssum, 16, 64);
    ssum += __shfl_xor(ssum, 32, 64);
    if (sub == 0) a.alpha[(size_t)row * H + h] = e / ssum;
    return;
  }
  const int lin = blockIdx.x;
  const int xcd = lin & 7, slot = lin >> 3;
  const int j0 = (slot & 15) * 64;
  const int set = slot >> 4;
  const int z   = (a.nz == 2) ? (set & 1)  : 0;
  const int grp = (a.nz == 2) ? (set >> 1) : set;
  const int bh = xcd + 8 * grp, b = bh >> 3, h = bh & 7;
  const int t = threadIdx.x;
  const unsigned short* vp = a.v[z];
  unsigned short* vtp = a.vt[z] + (size_t)bh * 64 * S;
  #pragma unroll
  for (int p = 0; p < 2; p++){
    int lin2 = t + p * 256, row = lin2 >> 3, c8 = (lin2 & 7) << 3;
    *(uint4*)&tile[row * KS_LD + c8] =
      *(const uint4*)&vp[((size_t)b * S + j0 + row) * D + h * DKH + c8];
  }
  __syncthreads();
  #pragma unroll
  for (int p = 0; p < 2; p++){
    int lin2 = t + p * 256, d = lin2 >> 3, c8 = (lin2 & 7) << 3;
    unsigned short tmp[8];
    #pragma unroll
    for (int jx = 0; jx < 8; jx++) tmp[jx] = tile[(c8 + jx) * KS_LD + d];
    *(uint4*)&vtp[(size_t)d * S + j0 + c8] = *(const uint4*)tmp;
  }
}

// ================= fused attention: scores -> decay -> AV =================
// (r5 structure exactly: straight-line phase 2, 32-float live set, XCD-pinned,
// 2-deep prefetch — the best-measured configuration, 427.5us total.)
struct FAArgs {
  const unsigned short* qk[2];   // q==k source (bf16, [b][S][D])
  const unsigned short* vt[2];   // VT (bf16, [bh][64][S])
  unsigned short* ctx[2];        // out (bf16, [b][S][D])
  const float* g[2];
  const float* c3;               // fp32 [b][h][S] (C3 mode)
  int diag, zero_pad, nz;
};
template<int C3>
__global__ __launch_bounds__(256, 4) void fused_attn(FAArgs a)
{
  __shared__ __align__(16) unsigned short att[16 * ATT_LD];   // 33,024 B
  __shared__ float ls2s[16];                                   // per-row inv2
  const int t = threadIdx.x;
  const int lin = blockIdx.x;
  const int xcd = lin & 7;
  const int slot = lin >> 3;
  const int i0 = (slot & 63) * 16;
  const int set = slot >> 6;
  const int z   = (a.nz == 2) ? (set & 1)  : 0;
  const int grp = (a.nz == 2) ? (set >> 1) : set;
  const int bh = xcd + 8 * grp, b = bh >> 3, h = bh & 7;
  const int w = t >> 6, lane = t & 63, lm = lane & 15, q = lane >> 4;
  const unsigned short* qkp = a.qk[z];
  const unsigned short* vtp = a.vt[z] + (size_t)bh * 64 * S;
  unsigned short* ctxp = a.ctx[z];
  float gm2;
  { float gv = a.g[z][h];
    gm2 = -((gv > 20.f) ? gv : log1pf(expf(gv))) * LOG2E; }   // log2-space gamma

  // ---------- phase 1: scores tile [16 x 1024] -> att (bf16), K prefetched ----------
  if (!C3){
    const size_t rowbase = (size_t)b * S;
    bf16x8 af0 = *(const bf16x8*)&qkp[(rowbase + i0 + lm) * D + h * DKH + q*8];
    bf16x8 af1 = *(const bf16x8*)&qkp[(rowbase + i0 + lm) * D + h * DKH + 32 + q*8];
    size_t kb = (rowbase + w*16 + lm) * D + h * DKH;
    bf16x8 bv0 = *(const bf16x8*)&qkp[kb + q*8];
    bf16x8 bv1 = *(const bf16x8*)&qkp[kb + 32 + q*8];
    for (int jc = 0; jc < S; jc += 64){
      bf16x8 nb0, nb1;
      if (jc + 64 < S){
        size_t kb2 = (rowbase + jc + 64 + w*16 + lm) * D + h * DKH;
        nb0 = *(const bf16x8*)&qkp[kb2 + q*8];
        nb1 = *(const bf16x8*)&qkp[kb2 + 32 + q*8];
      }
      f32x4 acc = (f32x4){0.f, 0.f, 0.f, 0.f};
      acc = MFMA(af0, bv0, acc);
      acc = MFMA(af1, bv1, acc);
      #pragma unroll
      for (int rr = 0; rr < 4; rr++)
        att[(q*4 + rr) * ATT_LD + jc + w*16 + lm] = f2bf_rhu(acc[rr] * 0.125f);
      bv0 = nb0; bv1 = nb1;
    }
  }
  __syncthreads();

  // ---------- phase 2: decay + double softmax, wave-per-row (4 rows/wave) ----------
  const int jA0 = lane * 8, jB0 = 512 + lane * 8;

  // C3: scores are row-invariant per (b,h) — hoist unpack + raw exp across rows
  float cHA[8], cHB[8], erHA[8], erHB[8];
  if (C3){
    const float* c3p = a.c3 + ((size_t)b * H + h) * S;
    float4 x0 = *(const float4*)&c3p[lane*8];
    float4 x1 = *(const float4*)&c3p[lane*8 + 4];
    float4 y0 = *(const float4*)&c3p[512 + lane*8];
    float4 y1 = *(const float4*)&c3p[512 + lane*8 + 4];
    cHA[0]=x0.x*LOG2E; cHA[1]=x0.y*LOG2E; cHA[2]=x0.z*LOG2E; cHA[3]=x0.w*LOG2E;
    cHA[4]=x1.x*LOG2E; cHA[5]=x1.y*LOG2E; cHA[6]=x1.z*LOG2E; cHA[7]=x1.w*LOG2E;
    cHB[0]=y0.x*LOG2E; cHB[1]=y0.y*LOG2E; cHB[2]=y0.z*LOG2E; cHB[3]=y0.w*LOG2E;
    cHB[4]=y1.x*LOG2E; cHB[5]=y1.y*LOG2E; cHB[6]=y1.z*LOG2E; cHB[7]=y1.w*LOG2E;
    #pragma unroll
    for (int k = 0; k < 8; k++){ erHA[k] = EXP2(cHA[k]); erHB[k] = EXP2(cHB[k]); }
  }

  for (int rloc = 0; rloc < 4; rloc++){
    const int rl = w*4 + rloc;
    const int i = i0 + rl;
    unsigned short* rowp = &att[rl * ATT_LD];
    if (C3 && a.zero_pad && i == 0){
      uint4 zz = make_uint4(0u,0u,0u,0u);
      *(uint4*)&rowp[jA0] = zz;
      *(uint4*)&rowp[jB0] = zz;
      if (lane == 0) ls2s[0] = 1.f;
      continue;
    }

    const int jmax = i + a.diag;
    const bool skipB = (jmax < 512);     // wave-uniform

    float cA[8], cB[8], plA[8], plB[8];
    if (!C3){
      uint4 uA = *(const uint4*)&rowp[jA0];
      uint4 uB = *(const uint4*)&rowp[jB0];
      unsigned int ua[4] = {uA.x, uA.y, uA.z, uA.w};
      unsigned int ub[4] = {uB.x, uB.y, uB.z, uB.w};
      #pragma unroll
      for (int mel = 0; mel < 4; mel++){
        cA[mel*2]     = bf2f(ua[mel] & 0xffffu) * LOG2E;
        cA[mel*2 + 1] = bf2f(ua[mel] >> 16) * LOG2E;
        cB[mel*2]     = bf2f(ub[mel] & 0xffffu) * LOG2E;
        cB[mel*2 + 1] = bf2f(ub[mel] >> 16) * LOG2E;
      }
    }

    // cumsum A (er computed inline; 8 exp2)
    float runA = 0.f;
    #pragma unroll
    for (int k = 0; k < 8; k++){
      float e;
      if (C3) e = (jA0 + k <= jmax) ? erHA[k] : 0.f;
      else    e = (jA0 + k <= jmax) ? EXP2(cA[k]) : 0.f;
      runA += e; plA[k] = runA;
    }
    float sA, TA;
    wave_scan64(runA, lane, sA, TA);
    float T = TA, sB = 0.f, runB = 0.f;
    if (!skipB){
      #pragma unroll
      for (int k = 0; k < 8; k++){
        float e;
        if (C3) e = (jB0 + k <= jmax) ? erHB[k] : 0.f;
        else    e = (jB0 + k <= jmax) ? EXP2(cB[k]) : 0.f;
        runB += e; plB[k] = runB;
      }
      float TB;
      wave_scan64(runB, lane, sB, TB);
      T = TA + TB;
    }

    const float inv1 = RCPF(T);
    const float cbaseA = (T - (sA - runA)) * inv1;
    const float fiA = (float)(i - jA0);
    float ls2 = 0.f;
    #pragma unroll
    for (int k = 0; k < 8; k++){
      float remn = fmaf(-plA[k], inv1, cbaseA);
      float pos  = fabsf(fiA - (float)k);
      float dist = SQRTF(fmaxf(remn * pos, 0.f));
      float eff  = fmaxf(EXP2(gm2 * dist), 1e-5f);
      float cv   = C3 ? cHA[k] : cA[k];
      float pp   = EXP2(cv * eff);
      ls2 += pp; plA[k] = pp;
    }
    if (!skipB){
      const float cbaseB = (T - (TA + sB - runB)) * inv1;
      const float fiB = (float)(i - jB0);
      #pragma unroll
      for (int k = 0; k < 8; k++){
        float remn = fmaf(-plB[k], inv1, cbaseB);
        float pos  = fabsf(fiB - (float)k);
        float dist = SQRTF(fmaxf(remn * pos, 0.f));
        float eff  = fmaxf(EXP2(gm2 * dist), 1e-5f);
        float cv   = C3 ? cHB[k] : cB[k];
        float pp   = EXP2(cv * eff);
        ls2 += pp; plB[k] = pp;
      }
    } else {
      #pragma unroll
      for (int k = 0; k < 8; k++){
        float e2 = C3 ? erHB[k] : EXP2(cB[k]);
        plB[k] = e2; ls2 += e2;
      }
    }
    ls2 = wave_sum64(ls2);
    if (lane == 0) ls2s[rl] = RCPF(ls2);

    uint4 oA, oB;
    oA.x = pk_rhu(plA[0], plA[1]);
    oA.y = pk_rhu(plA[2], plA[3]);
    oA.z = pk_rhu(plA[4], plA[5]);
    oA.w = pk_rhu(plA[6], plA[7]);
    oB.x = pk_rhu(plB[0], plB[1]);
    oB.y = pk_rhu(plB[2], plB[3]);
    oB.z = pk_rhu(plB[4], plB[5]);
    oB.w = pk_rhu(plB[6], plB[7]);
    *(uint4*)&rowp[jA0] = oA;
    *(uint4*)&rowp[jB0] = oB;
  }
  __syncthreads();

  // ---------- phase 3: ctx = att @ V (VT prefetched from global), scale by inv2 ----------
  f32x4 acc = (f32x4){0.f,0.f,0.f,0.f};
  const unsigned short* vrow = &vtp[(size_t)(w*16 + lm) * S];
  bf16x8 bv0 = *(const bf16x8*)&vrow[q*8];
  bf16x8 bv1 = *(const bf16x8*)&vrow[32 + q*8];
  for (int kc = 0; kc < S; kc += 64){
    bf16x8 nb0, nb1;
    if (kc + 64 < S){
      nb0 = *(const bf16x8*)&vrow[kc + 64 + q*8];
      nb1 = *(const bf16x8*)&vrow[kc + 96 + q*8];
    }
    bf16x8 a0 = *(const bf16x8*)&att[lm * ATT_LD + kc + q*8];
    bf16x8 a1 = *(const bf16x8*)&att[lm * ATT_LD + kc + 32 + q*8];
    acc = MFMA(a0, bv0, acc);
    acc = MFMA(a1, bv1, acc);
    bv0 = nb0; bv1 = nb1;
  }
  #pragma unroll
  for (int rr = 0; rr < 4; rr++){
    const int rl = q*4 + rr;
    const float sc = ls2s[rl];
    const int row = i0 + rl;
    ctxp[((size_t)b * S + row) * D + h * DKH + w*16 + lm] = f2bf(acc[rr] * sc);
  }
}

// ================= residual + LayerNorm -> bf16 (batched, DPP reductions) =================
// blk_sum's 16 barrier rounds replaced by wave_sum64 + 4-elem LDS combine:
// 2 __syncthreads per block instead of ~16 (reduction order change ~1e-6,
// far below the inherent 0.004 bf16 error).
struct LNJobs {
  const float* resid[2];
  const float* y[2];
  const float* ls[2];
  const float* lb[2];
  unsigned short* out[2];
  int bcast[2];
};
__global__ __launch_bounds__(256) void ln_residual_b(LNJobs j)
{
  const int z = blockIdx.y;
  const int r = blockIdx.x, t = threadIdx.x;
  const int w = t >> 6, lane = t & 63;
  __shared__ float p1[4], p2[4];
  const size_t base = (size_t)r * D;
  const float* resid = j.resid[z];
  const float* y = j.y[z];
  const int bcast = j.bcast[z];
  float r0 = bcast ? resid[t]       : resid[base + t];
  float r1 = bcast ? resid[t + 256] : resid[base + t + 256];
  float x0 = r0 + y[base + t];
  float x1 = r1 + y[base + t + 256];
  float s = wave_sum64(x0 + x1);
  if (lane == 0) p1[w] = s;
  __syncthreads();
  float mean = ((p1[0] + p1[1]) + (p1[2] + p1[3])) * (1.0f / 512.0f);
  float d0 = x0 - mean, d1 = x1 - mean;
  float v = wave_sum64(d0*d0 + d1*d1);
  if (lane == 0) p2[w] = v;
  __syncthreads();
  float var = ((p2[0] + p2[1]) + (p2[2] + p2[3])) * (1.0f / 512.0f);
  float inv = rsqrtf(var + 1e-5f);
  j.out[z][base + t]       = f2bf(d0 * inv * j.ls[z][t]       + j.lb[z][t]);
  j.out[z][base + t + 256] = f2bf(d1 * inv * j.ls[z][t + 256] + j.lb[z][t + 256]);
}

// ================= fp32 -> bf16 conversions =================
struct CvtJobs {
  const float* s[12];
  unsigned short* d[12];
  int n[12];
};
__global__ __launch_bounds__(256) void cvt_all(CvtJobs jb){
  const int z = blockIdx.y;
  const int n = jb.n[z];
  const float* s = jb.s[z];
  unsigned short* d = jb.d[z];
  for (int idx = blockIdx.x * 256 + threadIdx.x; idx < n; idx += gridDim.x * 256)
    d[idx] = f2bf(s[idx]);
}

// ================= know-derived small kernels (merged) =================
__global__ __launch_bounds__(256) void know_kernel(
    const float* __restrict__ know, const float* __restrict__ Wq3,
    const float* __restrict__ bq3, float* __restrict__ q3,
    const float* __restrict__ Wlk, const float* __restrict__ blk_,
    float* __restrict__ keyt)
{
  if (blockIdx.x < 128){
    const int wv = (blockIdx.x * 256 + threadIdx.x) >> 6;
    const int lane = threadIdx.x & 63;
    const float* wr = Wq3 + (size_t)wv * 512 + lane * 8;
    const float* kr = know + lane * 8;
    float4 w0 = *(const float4*)&wr[0], w1 = *(const float4*)&wr[4];
    float4 k0 = *(const float4*)&kr[0], k1 = *(const float4*)&kr[4];
    float p = w0.x*k0.x + w0.y*k0.y + w0.z*k0.z + w0.w*k0.w
            + w1.x*k1.x + w1.y*k1.y + w1.z*k1.z + w1.w*k1.w;
    p = wave_sum64(p);
    if (lane == 0) q3[wv] = p + bq3[wv];
  } else {
    int idx = (blockIdx.x - 128) * 256 + threadIdx.x;
    int h = idx >> 9, n = idx & 511;
    float acc = 0.f;
    for (int i = 0; i < 64; i++) acc += know[h * 64 + i] * Wlk[(size_t)n * 64 + i];
    keyt[idx] = 1.f / (1.f + __expf(-(acc + blk_[n])));
  }
}

// scores3: 4 lanes per output (16 MACs each + 2 shfl_xor) -> 4x the waves of
// the 1-thread-per-output version (latency hiding at 2048 vs 512 waves).
__global__ __launch_bounds__(256) void scores3_kernel(
    const float* __restrict__ q3, const unsigned short* __restrict__ k3,
    float* __restrict__ c3)
{
  int gid = blockIdx.x * 64 + (threadIdx.x >> 2);   // (b*H+h)*S + j
  int sub = threadIdx.x & 3;
  int j  = gid & (S - 1);
  int bh = gid >> 10;
  int h  = bh & 7, b = bh >> 3;
  const unsigned short* kp = k3 + ((size_t)b * S + j) * D + h * DKH + sub * 16;
  const float* qp = q3 + h * DKH + sub * 16;
  float acc = 0.f;
  #pragma unroll
  for (int d8 = 0; d8 < 16; d8 += 8){
    uint4 u = *(const uint4*)&kp[d8];
    unsigned int uu[4] = {u.x, u.y, u.z, u.w};
    #pragma unroll
    for (int mel = 0; mel < 4; mel++){
      acc += qp[d8 + 2*mel]     * bf2f(uu[mel] & 0xffffu);
      acc += qp[d8 + 2*mel + 1] * bf2f(uu[mel] >> 16);
    }
  }
  acc += __shfl_xor(acc, 1, 64);
  acc += __shfl_xor(acc, 2, 64);
  if (sub == 0) c3[gid] = acc * 0.125f;
}

// ================= fused val GEMM + sigmoid + alpha-combine =================
__global__ __launch_bounds__(256) void val_fused(
    const unsigned short* __restrict__ Ah,
    const unsigned short* __restrict__ Wv,
    const float* __restrict__ blv,
    const float* __restrict__ alpha,
    float* __restrict__ out)
{
  __shared__ __align__(16) short As[128][32];
  __shared__ __align__(16) short Ws[128][32];
  __shared__ float als[128];
  const int t = threadIdx.x;
  const int n0 = blockIdx.x * 128, m0 = blockIdx.y * 128;
  if (t < 128) als[t] = alpha[m0 + t];
  const int w = t >> 6, lane = t & 63;
  const int wm = (w >> 1) << 6, wn = (w & 1) << 6;
  const int lm = lane & 15, q = lane >> 4;
  const int r = t >> 2, cc = (t & 3) << 3;
  f32x4 acc[4][4];
  #pragma unroll
  for (int a_ = 0; a_ < 4; a_++)
    #pragma unroll
    for (int b_ = 0; b_ < 4; b_++)
      acc[a_][b_] = (f32x4){0.f, 0.f, 0.f, 0.f};
  for (int k0 = 0; k0 < 64; k0 += 32){
    *(uint4*)&As[r][cc]      = *(const uint4*)&Ah[(size_t)(m0 + r) * 64 + k0 + cc];
    *(uint4*)&As[r + 64][cc] = *(const uint4*)&Ah[(size_t)(m0 + r + 64) * 64 + k0 + cc];
    *(uint4*)&Ws[r][cc]      = *(const uint4*)&Wv[(size_t)(n0 + r) * 64 + k0 + cc];
    *(uint4*)&Ws[r + 64][cc] = *(const uint4*)&Wv[(size_t)(n0 + r + 64) * 64 + k0 + cc];
    __syncthreads();
    bf16x8 af[4], bf[4];
    #pragma unroll
    for (int mt = 0; mt < 4; mt++) af[mt] = *(const bf16x8*)&As[wm + mt*16 + lm][q*8];
    #pragma unroll
    for (int nt = 0; nt < 4; nt++) bf[nt] = *(const bf16x8*)&Ws[wn + nt*16 + lm][q*8];
    #pragma unroll
    for (int mt = 0; mt < 4; mt++)
      #pragma unroll
      for (int nt = 0; nt < 4; nt++)
        acc[mt][nt] = MFMA(af[mt], bf[nt], acc[mt][nt]);
    __syncthreads();
  }
  #pragma unroll
  for (int nt = 0; nt < 4; nt++){
    const int n = n0 + wn + nt*16 + lm;
    const float bs = blv[n];
    #pragma unroll
    for (int mt = 0; mt < 4; mt++){
      const int mb = m0 + wm + mt*16;
      f32x4 c = acc[mt][nt];
      float part = 0.f;
      #pragma unroll
      for (int rr = 0; rr < 4; rr++){
        const int ml = (mb - m0) + (q << 2) + rr;
        float sg = 1.f / (1.f + __expf(-(c[rr] + bs)));
        part += als[ml] * sg;
      }
      part += __shfl_xor(part, 16, 64);
      if ((q & 1) == 0){
        const int srow = (mb >> 3) + (q >> 1);
        out[(size_t)srow * D + n] = part;
      }
    }
  }
}

// ================= orchestration =================
extern "C" void kernel_launch(void* const* d_in, const int* in_sizes, int n_in,
                              void* d_out, int out_size, void* d_ws, size_t ws_size,
                              hipStream_t stream) {
  const float* q_emb  = (const float*)d_in[0];
  const float* qa_emb = (const float*)d_in[1];
  const float* Wq1 = (const float*)d_in[2],  *bq1 = (const float*)d_in[3];
  const float* Wv1 = (const float*)d_in[4],  *bv1 = (const float*)d_in[5];
  const float* Wo1 = (const float*)d_in[6],  *bo1 = (const float*)d_in[7];
  const float* g1  = (const float*)d_in[8],  *ls1 = (const float*)d_in[9],  *lb1 = (const float*)d_in[10];
  const float* Wq2 = (const float*)d_in[11], *bq2 = (const float*)d_in[12];
  const float* Wv2 = (const float*)d_in[13], *bv2 = (const float*)d_in[14];
  const float* Wo2 = (const float*)d_in[15], *bo2 = (const float*)d_in[16];
  const float* g2  = (const float*)d_in[17], *ls2 = (const float*)d_in[18], *lb2 = (const float*)d_in[19];
  const float* Wq3 = (const float*)d_in[20], *bq3 = (const float*)d_in[21];
  const float* Wk3 = (const float*)d_in[22], *bk3 = (const float*)d_in[23];
  const float* Wv3 = (const float*)d_in[24], *bv3 = (const float*)d_in[25];
  const float* Wo3 = (const float*)d_in[26], *bo3 = (const float*)d_in[27];
  const float* g3  = (const float*)d_in[28], *ls3 = (const float*)d_in[29], *lb3 = (const float*)d_in[30];
  const float* know = (const float*)d_in[31];
  const float* Wlk  = (const float*)d_in[32], *b_lk = (const float*)d_in[33];
  const float* Wlv  = (const float*)d_in[34], *b_lv = (const float*)d_in[35];
  float* outp = (float*)d_out;

  const size_t NSD = (size_t)BB * S * D;   // 2,097,152
  unsigned short* p = (unsigned short*)d_ws;
  unsigned short* qk1b = p; p += NSD;
  unsigned short* v1b  = p; p += NSD;
  unsigned short* qk2b = p; p += NSD;
  unsigned short* v2b  = p; p += NSD;
  unsigned short* k3b  = p; p += NSD;
  unsigned short* v3b  = p; p += NSD;
  unsigned short* ctx1b= p; p += NSD;
  unsigned short* ctx2b= p; p += NSD;
  unsigned short* ctx3b= p; p += NSD;
  unsigned short* xqb  = p; p += NSD;
  unsigned short* xab  = p; p += NSD;
  unsigned short* hqb  = p; p += NSD;
  unsigned short* hab  = p; p += NSD;
  unsigned short* hfb  = p; p += NSD;
  unsigned short* vt1  = p; p += NSD;   // [32][64][1024]
  unsigned short* vt2  = p; p += NSD;
  unsigned short* vt3  = p; p += NSD;
  unsigned short* wb   = p; p += (size_t)9 * D * D;
  unsigned short* wlvb = p; p += (size_t)D * DKH;
  float* yv0   = (float*)p;
  float* yv1   = yv0 + NSD;
  float* q3    = yv1 + NSD;
  float* keyt  = q3 + 512;
  float* c3    = keyt + 4096;
  float* alpha = c3 + (size_t)BB * H * S;

  unsigned short* Wq1b = wb + 0*(size_t)D*D;
  unsigned short* Wv1b = wb + 1*(size_t)D*D;
  unsigned short* Wo1b = wb + 2*(size_t)D*D;
  unsigned short* Wq2b = wb + 3*(size_t)D*D;
  unsigned short* Wv2b = wb + 4*(size_t)D*D;
  unsigned short* Wo2b = wb + 5*(size_t)D*D;
  unsigned short* Wk3b = wb + 6*(size_t)D*D;
  unsigned short* Wv3b = wb + 7*(size_t)D*D;
  unsigned short* Wo3b = wb + 8*(size_t)D*D;

  // ---- conversions + (independent) know-derived precompute ----
  CvtJobs jb;
  jb.s[0] = q_emb;  jb.d[0] = xqb;  jb.n[0] = (int)NSD;
  jb.s[1] = qa_emb; jb.d[1] = xab;  jb.n[1] = (int)NSD;
  jb.s[2] = Wq1; jb.d[2] = Wq1b; jb.n[2] = D*D;
  jb.s[3] = Wv1; jb.d[3] = Wv1b; jb.n[3] = D*D;
  jb.s[4] = Wo1; jb.d[4] = Wo1b; jb.n[4] = D*D;
  jb.s[5] = Wq2; jb.d[5] = Wq2b; jb.n[5] = D*D;
  jb.s[6] = Wv2; jb.d[6] = Wv2b; jb.n[6] = D*D;
  jb.s[7] = Wo2; jb.d[7] = Wo2b; jb.n[7] = D*D;
  jb.s[8] = Wk3; jb.d[8] = Wk3b; jb.n[8] = D*D;
  jb.s[9] = Wv3; jb.d[9] = Wv3b; jb.n[9] = D*D;
  jb.s[10] = Wo3; jb.d[10] = Wo3b; jb.n[10] = D*D;
  jb.s[11] = Wlv; jb.d[11] = wlvb; jb.n[11] = D*DKH;
  cvt_all<<<dim3(256, 12), 256, 0, stream>>>(jb);
  know_kernel<<<144, 256, 0, stream>>>(know, Wq3, bq3, q3, Wlk, b_lk, keyt);

  // ---- blocks 1&2: projections (z=4) ----
  {
    GemmJobs g;
    g.A[0]=xqb; g.W[0]=Wq1b; g.bias[0]=bq1; g.C[0]=qk1b;
    g.A[1]=xqb; g.W[1]=Wv1b; g.bias[1]=bv1; g.C[1]=v1b;
    g.A[2]=xab; g.W[2]=Wq2b; g.bias[2]=bq2; g.C[2]=qk2b;
    g.A[3]=xab; g.W[3]=Wv2b; g.bias[3]=bv2; g.C[3]=v2b;
    mfma_gemm_b<1><<<dim3(4, 32, 4), 256, 0, stream>>>(g);
  }
  { VTArgs a; a.v[0]=v1b; a.v[1]=v2b; a.vt[0]=vt1; a.vt[1]=vt2; a.nz=2;
    a.vtblocks=1024; a.keyt=keyt; a.q_emb=q_emb; a.alpha=alpha;
    vt_kernel<<<dim3(2048), 256, 0, stream>>>(a); }
  { FAArgs a;
    a.qk[0]=qk1b; a.qk[1]=qk2b; a.vt[0]=vt1; a.vt[1]=vt2;
    a.ctx[0]=ctx1b; a.ctx[1]=ctx2b; a.g[0]=g1; a.g[1]=g2;
    a.c3=nullptr; a.diag=0; a.zero_pad=0; a.nz=2;
    fused_attn<0><<<dim3(4096), 256, 0, stream>>>(a); }
  {
    GemmJobs g;
    g.A[0]=ctx1b; g.W[0]=Wo1b; g.bias[0]=bo1; g.C[0]=yv0;
    g.A[1]=ctx2b; g.W[1]=Wo2b; g.bias[1]=bo2; g.C[1]=yv1;
    g.A[2]=ctx1b; g.W[2]=Wo1b; g.bias[2]=bo1; g.C[2]=yv0;
    g.A[3]=ctx1b; g.W[3]=Wo1b; g.bias[3]=bo1; g.C[3]=yv0;
    mfma_gemm_b<0><<<dim3(4, 32, 2), 256, 0, stream>>>(g);
  }
  {
    LNJobs lj;
    lj.resid[0]=q_emb;  lj.y[0]=yv0; lj.ls[0]=ls1; lj.lb[0]=lb1; lj.out[0]=hqb; lj.bcast[0]=0;
    lj.resid[1]=qa_emb; lj.y[1]=yv1; lj.ls[1]=ls2; lj.lb[1]=lb2; lj.out[1]=hab; lj.bcast[1]=0;
    ln_residual_b<<<dim3(BB*S, 2), 256, 0, stream>>>(lj);
  }

  // ---- block 3 ----
  {
    GemmJobs g;
    g.A[0]=hqb; g.W[0]=Wk3b; g.bias[0]=bk3; g.C[0]=k3b;
    g.A[1]=hab; g.W[1]=Wv3b; g.bias[1]=bv3; g.C[1]=v3b;
    g.A[2]=hqb; g.W[2]=Wk3b; g.bias[2]=bk3; g.C[2]=k3b;
    g.A[3]=hqb; g.W[3]=Wk3b; g.bias[3]=bk3; g.C[3]=k3b;
    mfma_gemm_b<1><<<dim3(4, 32, 2), 256, 0, stream>>>(g);
  }
  { VTArgs a; a.v[0]=v3b; a.v[1]=v3b; a.vt[0]=vt3; a.vt[1]=vt3; a.nz=1;
    a.vtblocks=512; a.keyt=keyt; a.q_emb=q_emb; a.alpha=alpha;
    vt_kernel<<<dim3(512), 256, 0, stream>>>(a); }
  scores3_kernel<<<512, 256, 0, stream>>>(q3, k3b, c3);
  { FAArgs a;
    a.qk[0]=k3b; a.qk[1]=k3b; a.vt[0]=vt3; a.vt[1]=vt3;
    a.ctx[0]=ctx3b; a.ctx[1]=ctx3b; a.g[0]=g3; a.g[1]=g3;
    a.c3=c3; a.diag=-1; a.zero_pad=1; a.nz=1;
    fused_attn<1><<<dim3(2048), 256, 0, stream>>>(a); }
  {
    GemmJobs g;
    g.A[0]=ctx3b; g.W[0]=Wo3b; g.bias[0]=bo3; g.C[0]=yv0;
    g.A[1]=ctx3b; g.W[1]=Wo3b; g.bias[1]=bo3; g.C[1]=yv0;
    g.A[2]=ctx3b; g.W[2]=Wo3b; g.bias[2]=bo3; g.C[2]=yv0;
    g.A[3]=ctx3b; g.W[3]=Wo3b; g.bias[3]=bo3; g.C[3]=yv0;
    mfma_gemm_b<0><<<dim3(4, 32, 1), 256, 0, stream>>>(g);
  }
  {
    LNJobs lj;
    lj.resid[0]=know; lj.y[0]=yv0; lj.ls[0]=ls3; lj.lb[0]=lb3; lj.out[0]=hfb; lj.bcast[0]=1;
    lj.resid[1]=know; lj.y[1]=yv0; lj.ls[1]=ls3; lj.lb[1]=lb3; lj.out[1]=hfb; lj.bcast[1]=1;
    ln_residual_b<<<dim3(BB*S, 1), 256, 0, stream>>>(lj);
  }

  // ---- final combine (alphas already computed in vt_kernel merge) ----
  val_fused<<<dim3(4, 256), 256, 0, stream>>>(hfb, wlvb, b_lv, alpha, outp);
}

// Round 10
// 417.902 us; speedup vs baseline: 1.0474x; 1.0133x over previous
//
#include <hip/hip_runtime.h>
#include <math.h>

#define BB 4
#define S 1024
#define D 512
#define H 8
#define DKH 64

#define ATT_LD 1032   // att row stride (shorts): 516 dwords == 4 mod 32 (2-way = free)
#define LOG2E 1.4426950408889634f

typedef __attribute__((ext_vector_type(8))) short bf16x8;
typedef __attribute__((ext_vector_type(4))) float f32x4;

#if __has_builtin(__builtin_amdgcn_exp2f)
#define EXP2(x) __builtin_amdgcn_exp2f(x)
#else
#define EXP2(x) exp2f(x)
#endif
#if __has_builtin(__builtin_amdgcn_sqrtf)
#define SQRTF(x) __builtin_amdgcn_sqrtf(x)
#else
#define SQRTF(x) sqrtf(x)
#endif
#if __has_builtin(__builtin_amdgcn_rcpf)
#define RCPF(x) __builtin_amdgcn_rcpf(x)
#else
#define RCPF(x) (1.0f / (x))
#endif

__device__ __forceinline__ unsigned short f2bf(float f){
  unsigned int u = __float_as_uint(f);
  u += 0x7FFFu + ((u >> 16) & 1u);
  return (unsigned short)(u >> 16);
}
__device__ __forceinline__ unsigned short f2bf_rhu(float f){
  return (unsigned short)((__float_as_uint(f) + 0x8000u) >> 16);
}
__device__ __forceinline__ unsigned int pk_rhu(float lo, float hi){
  unsigned int a = __float_as_uint(lo) + 0x8000u;
  unsigned int b = __float_as_uint(hi) + 0x8000u;
#if __has_builtin(__builtin_amdgcn_perm)
  return __builtin_amdgcn_perm(b, a, 0x07060302u);
#else
  return (a >> 16) | (b & 0xffff0000u);
#endif
}
__device__ __forceinline__ float bf2f(unsigned int v){
  return __uint_as_float(v << 16);
}
__device__ __forceinline__ f32x4 MFMA(bf16x8 a, bf16x8 b, f32x4 c){
  return __builtin_amdgcn_mfma_f32_16x16x32_bf16(a, b, c, 0, 0, 0);
}
__device__ __forceinline__ void gl_lds16(const void* g, void* l){
  __builtin_amdgcn_global_load_lds(
      (const __attribute__((address_space(1))) void*)g,
      (__attribute__((address_space(3))) void*)l, 16, 0, 0);
}

// ---- DPP cross-lane (pure VALU pipe, no ds_bpermute latency) ----
template<int CTRL>
__device__ __forceinline__ float dppadd(float v){
  int s = __builtin_amdgcn_update_dpp(0, __float_as_int(v), CTRL, 0xf, 0xf, true);
  return v + __int_as_float(s);
}
__device__ __forceinline__ float rdl(float v, int l){
  return __int_as_float(__builtin_amdgcn_readlane(__float_as_int(v), l));
}
// inclusive 64-lane prefix (order-exact) + total, via 16-lane row scans + row offsets
__device__ __forceinline__ void wave_scan64(float v, int lane, float& incl, float& total){
  float r = dppadd<0x111>(v);   // row_shr:1
  r = dppadd<0x112>(r);         // row_shr:2
  r = dppadd<0x114>(r);         // row_shr:4
  r = dppadd<0x118>(r);         // row_shr:8
  float t0 = rdl(r, 15), t1 = rdl(r, 31), t2 = rdl(r, 47), t3 = rdl(r, 63);
  const int row = lane >> 4;
  float off = (row > 0 ? t0 : 0.f) + (row > 1 ? t1 : 0.f) + (row > 2 ? t2 : 0.f);
  incl = r + off;
  total = (t0 + t1) + (t2 + t3);
}
__device__ __forceinline__ float wave_sum64(float v){
  float r = dppadd<0x111>(v);
  r = dppadd<0x112>(r);
  r = dppadd<0x114>(r);
  r = dppadd<0x118>(r);
  return (rdl(r, 15) + rdl(r, 31)) + (rdl(r, 47) + rdl(r, 63));
}

// ================= batched projection GEMM (M=4096,N=512,K=512) =================
struct GemmJobs {
  const unsigned short* A[4];
  const unsigned short* W[4];
  const float* bias[4];
  void* C[4];
};
template<int OUTBF>
__global__ __launch_bounds__(256) void mfma_gemm_b(GemmJobs jb)
{
  __shared__ __align__(16) short As[128][32];
  __shared__ __align__(16) short Ws[128][32];
  const int t = threadIdx.x;
  const int z = blockIdx.z;
  const int n0 = blockIdx.x * 128, m0 = blockIdx.y * 128;
  const unsigned short* A = jb.A[z];
  const unsigned short* W = jb.W[z];
  const float* bias = jb.bias[z];
  const int w = t >> 6, lane = t & 63;
  const int wm = (w >> 1) << 6, wn = (w & 1) << 6;
  const int lm = lane & 15, q = lane >> 4;
  const int r = t >> 2, cc = (t & 3) << 3;
  char* ldsA = ((char*)&As[0][0]) + w * 1024;
  char* ldsW = ((char*)&Ws[0][0]) + w * 1024;
  f32x4 acc[4][4];
  #pragma unroll
  for (int a_ = 0; a_ < 4; a_++)
    #pragma unroll
    for (int b_ = 0; b_ < 4; b_++)
      acc[a_][b_] = (f32x4){0.f, 0.f, 0.f, 0.f};
  for (int k0 = 0; k0 < D; k0 += 32){
    gl_lds16(&A[(size_t)(m0 + r)      * D + k0 + cc], ldsA);
    gl_lds16(&A[(size_t)(m0 + r + 64) * D + k0 + cc], ldsA + 4096);
    gl_lds16(&W[(size_t)(n0 + r)      * D + k0 + cc], ldsW);
    gl_lds16(&W[(size_t)(n0 + r + 64) * D + k0 + cc], ldsW + 4096);
    __syncthreads();
    bf16x8 af[4], bf[4];
    #pragma unroll
    for (int mt = 0; mt < 4; mt++) af[mt] = *(const bf16x8*)&As[wm + mt*16 + lm][q*8];
    #pragma unroll
    for (int nt = 0; nt < 4; nt++) bf[nt] = *(const bf16x8*)&Ws[wn + nt*16 + lm][q*8];
    #pragma unroll
    for (int mt = 0; mt < 4; mt++)
      #pragma unroll
      for (int nt = 0; nt < 4; nt++)
        acc[mt][nt] = MFMA(af[mt], bf[nt], acc[mt][nt]);
    __syncthreads();
  }
  #pragma unroll
  for (int nt = 0; nt < 4; nt++){
    const int n = n0 + wn + nt*16 + lm;
    const float bs = bias[n];
    #pragma unroll
    for (int mt = 0; mt < 4; mt++){
      const int mb = m0 + wm + mt*16 + (q << 2);
      f32x4 c = acc[mt][nt];
      #pragma unroll
      for (int rr = 0; rr < 4; rr++){
        float vv = c[rr] + bs;
        if (OUTBF)
          ((unsigned short*)jb.C[z])[(size_t)(mb + rr) * D + n] = f2bf(vv);
        else
          ((float*)jb.C[z])[(size_t)(mb + rr) * D + n] = vv;
      }
    }
  }
}

// ================= V transpose (+ merged alphas / scores3 roles) =================
// XCD-pinned for vt part; blocks >= vtblocks run the extra role:
//   alpha != nullptr -> alphas combine (nz=2 launch; keyt ready: know ran first)
//   alpha == nullptr -> scores3 (nz=1 launch; k3/q3 ready: gemm3+cvt ran first)
#define KS_LD 66
struct VTArgs {
  const unsigned short* v[2]; unsigned short* vt[2]; int nz;
  int vtblocks;
  const float* keyt; const float* q_emb; float* alpha;
  const float* q3; const unsigned short* k3; float* c3;
};
__global__ __launch_bounds__(256) void vt_kernel(VTArgs a)
{
  __shared__ unsigned short tile[64 * KS_LD];
  if ((int)blockIdx.x >= a.vtblocks){
    const int ext = blockIdx.x - a.vtblocks;
    if (a.alpha){
      // ---- alphas role: softmax over heads of keyt . q_emb ----
      const int row = ext * 4 + (threadIdx.x >> 6);
      const int l = threadIdx.x & 63;
      const int h = l >> 3, sub = l & 7;
      const float* qr = a.q_emb + (size_t)row * D;
      const float* kt = a.keyt + h * D;
      float p = 0.f;
      for (int d = sub; d < D; d += 8) p += kt[d] * qr[d];
      p += __shfl_xor(p, 1, 64);
      p += __shfl_xor(p, 2, 64);
      p += __shfl_xor(p, 4, 64);
      float m = p;
      m = fmaxf(m, __shfl_xor(m, 8, 64));
      m = fmaxf(m, __shfl_xor(m, 16, 64));
      m = fmaxf(m, __shfl_xor(m, 32, 64));
      float e = __expf(p - m);
      float ssum = e;
      ssum += __shfl_xor(ssum, 8, 64);
      ssum += __shfl_xor(ssum, 16, 64);
      ssum += __shfl_xor(ssum, 32, 64);
      if (sub == 0) a.alpha[(size_t)row * H + h] = e / ssum;
    } else {
      // ---- scores3 role: c3 = q3 . k3 (4 lanes per output) ----
      int gid = ext * 64 + (threadIdx.x >> 2);
      int sub = threadIdx.x & 3;
      int j  = gid & (S - 1);
      int bh = gid >> 10;
      int h  = bh & 7, b = bh >> 3;
      const unsigned short* kp = a.k3 + ((size_t)b * S + j) * D + h * DKH + sub * 16;
      const float* qp = a.q3 + h * DKH + sub * 16;
      float acc = 0.f;
      #pragma unroll
      for (int d8 = 0; d8 < 16; d8 += 8){
        uint4 u = *(const uint4*)&kp[d8];
        unsigned int uu[4] = {u.x, u.y, u.z, u.w};
        #pragma unroll
        for (int mel = 0; mel < 4; mel++){
          acc += qp[d8 + 2*mel]     * bf2f(uu[mel] & 0xffffu);
          acc += qp[d8 + 2*mel + 1] * bf2f(uu[mel] >> 16);
        }
      }
      acc += __shfl_xor(acc, 1, 64);
      acc += __shfl_xor(acc, 2, 64);
      if (sub == 0) a.c3[gid] = acc * 0.125f;
    }
    return;
  }
  const int lin = blockIdx.x;
  const int xcd = lin & 7, slot = lin >> 3;
  const int j0 = (slot & 15) * 64;
  const int set = slot >> 4;
  const int z   = (a.nz == 2) ? (set & 1)  : 0;
  const int grp = (a.nz == 2) ? (set >> 1) : set;
  const int bh = xcd + 8 * grp, b = bh >> 3, h = bh & 7;
  const int t = threadIdx.x;
  const unsigned short* vp = a.v[z];
  unsigned short* vtp = a.vt[z] + (size_t)bh * 64 * S;
  #pragma unroll
  for (int p = 0; p < 2; p++){
    int lin2 = t + p * 256, row = lin2 >> 3, c8 = (lin2 & 7) << 3;
    *(uint4*)&tile[row * KS_LD + c8] =
      *(const uint4*)&vp[((size_t)b * S + j0 + row) * D + h * DKH + c8];
  }
  __syncthreads();
  #pragma unroll
  for (int p = 0; p < 2; p++){
    int lin2 = t + p * 256, d = lin2 >> 3, c8 = (lin2 & 7) << 3;
    unsigned short tmp[8];
    #pragma unroll
    for (int jx = 0; jx < 8; jx++) tmp[jx] = tile[(c8 + jx) * KS_LD + d];
    *(uint4*)&vtp[(size_t)d * S + j0 + c8] = *(const uint4*)tmp;
  }
}

// ================= fused attention: scores -> decay -> AV =================
// (r5/r9 structure exactly: straight-line phase 2, 32-float live set,
// XCD-pinned, 2-deep prefetch — best-measured configuration.)
struct FAArgs {
  const unsigned short* qk[2];   // q==k source (bf16, [b][S][D])
  const unsigned short* vt[2];   // VT (bf16, [bh][64][S])
  unsigned short* ctx[2];        // out (bf16, [b][S][D])
  const float* g[2];
  const float* c3;               // fp32 [b][h][S] (C3 mode)
  int diag, zero_pad, nz;
};
template<int C3>
__global__ __launch_bounds__(256, 4) void fused_attn(FAArgs a)
{
  __shared__ __align__(16) unsigned short att[16 * ATT_LD];   // 33,024 B
  __shared__ float ls2s[16];                                   // per-row inv2
  const int t = threadIdx.x;
  const int lin = blockIdx.x;
  const int xcd = lin & 7;
  const int slot = lin >> 3;
  const int i0 = (slot & 63) * 16;
  const int set = slot >> 6;
  const int z   = (a.nz == 2) ? (set & 1)  : 0;
  const int grp = (a.nz == 2) ? (set >> 1) : set;
  const int bh = xcd + 8 * grp, b = bh >> 3, h = bh & 7;
  const int w = t >> 6, lane = t & 63, lm = lane & 15, q = lane >> 4;
  const unsigned short* qkp = a.qk[z];
  const unsigned short* vtp = a.vt[z] + (size_t)bh * 64 * S;
  unsigned short* ctxp = a.ctx[z];
  float gm2;
  { float gv = a.g[z][h];
    gm2 = -((gv > 20.f) ? gv : log1pf(expf(gv))) * LOG2E; }   // log2-space gamma

  // ---------- phase 1: scores tile [16 x 1024] -> att (bf16), K prefetched ----------
  if (!C3){
    const size_t rowbase = (size_t)b * S;
    bf16x8 af0 = *(const bf16x8*)&qkp[(rowbase + i0 + lm) * D + h * DKH + q*8];
    bf16x8 af1 = *(const bf16x8*)&qkp[(rowbase + i0 + lm) * D + h * DKH + 32 + q*8];
    size_t kb = (rowbase + w*16 + lm) * D + h * DKH;
    bf16x8 bv0 = *(const bf16x8*)&qkp[kb + q*8];
    bf16x8 bv1 = *(const bf16x8*)&qkp[kb + 32 + q*8];
    for (int jc = 0; jc < S; jc += 64){
      bf16x8 nb0, nb1;
      if (jc + 64 < S){
        size_t kb2 = (rowbase + jc + 64 + w*16 + lm) * D + h * DKH;
        nb0 = *(const bf16x8*)&qkp[kb2 + q*8];
        nb1 = *(const bf16x8*)&qkp[kb2 + 32 + q*8];
      }
      f32x4 acc = (f32x4){0.f, 0.f, 0.f, 0.f};
      acc = MFMA(af0, bv0, acc);
      acc = MFMA(af1, bv1, acc);
      #pragma unroll
      for (int rr = 0; rr < 4; rr++)
        att[(q*4 + rr) * ATT_LD + jc + w*16 + lm] = f2bf_rhu(acc[rr] * 0.125f);
      bv0 = nb0; bv1 = nb1;
    }
  }
  __syncthreads();

  // ---------- phase 2: decay + double softmax, wave-per-row (4 rows/wave) ----------
  const int jA0 = lane * 8, jB0 = 512 + lane * 8;

  // C3: scores are row-invariant per (b,h) — hoist unpack + raw exp across rows
  float cHA[8], cHB[8], erHA[8], erHB[8];
  if (C3){
    const float* c3p = a.c3 + ((size_t)b * H + h) * S;
    float4 x0 = *(const float4*)&c3p[lane*8];
    float4 x1 = *(const float4*)&c3p[lane*8 + 4];
    float4 y0 = *(const float4*)&c3p[512 + lane*8];
    float4 y1 = *(const float4*)&c3p[512 + lane*8 + 4];
    cHA[0]=x0.x*LOG2E; cHA[1]=x0.y*LOG2E; cHA[2]=x0.z*LOG2E; cHA[3]=x0.w*LOG2E;
    cHA[4]=x1.x*LOG2E; cHA[5]=x1.y*LOG2E; cHA[6]=x1.z*LOG2E; cHA[7]=x1.w*LOG2E;
    cHB[0]=y0.x*LOG2E; cHB[1]=y0.y*LOG2E; cHB[2]=y0.z*LOG2E; cHB[3]=y0.w*LOG2E;
    cHB[4]=y1.x*LOG2E; cHB[5]=y1.y*LOG2E; cHB[6]=y1.z*LOG2E; cHB[7]=y1.w*LOG2E;
    #pragma unroll
    for (int k = 0; k < 8; k++){ erHA[k] = EXP2(cHA[k]); erHB[k] = EXP2(cHB[k]); }
  }

  for (int rloc = 0; rloc < 4; rloc++){
    const int rl = w*4 + rloc;
    const int i = i0 + rl;
    unsigned short* rowp = &att[rl * ATT_LD];
    if (C3 && a.zero_pad && i == 0){
      uint4 zz = make_uint4(0u,0u,0u,0u);
      *(uint4*)&rowp[jA0] = zz;
      *(uint4*)&rowp[jB0] = zz;
      if (lane == 0) ls2s[0] = 1.f;
      continue;
    }

    const int jmax = i + a.diag;
    const bool skipB = (jmax < 512);     // wave-uniform

    float cA[8], cB[8], plA[8], plB[8];
    if (!C3){
      uint4 uA = *(const uint4*)&rowp[jA0];
      uint4 uB = *(const uint4*)&rowp[jB0];
      unsigned int ua[4] = {uA.x, uA.y, uA.z, uA.w};
      unsigned int ub[4] = {uB.x, uB.y, uB.z, uB.w};
      #pragma unroll
      for (int mel = 0; mel < 4; mel++){
        cA[mel*2]     = bf2f(ua[mel] & 0xffffu) * LOG2E;
        cA[mel*2 + 1] = bf2f(ua[mel] >> 16) * LOG2E;
        cB[mel*2]     = bf2f(ub[mel] & 0xffffu) * LOG2E;
        cB[mel*2 + 1] = bf2f(ub[mel] >> 16) * LOG2E;
      }
    }

    // cumsum A (er computed inline; 8 exp2)
    float runA = 0.f;
    #pragma unroll
    for (int k = 0; k < 8; k++){
      float e;
      if (C3) e = (jA0 + k <= jmax) ? erHA[k] : 0.f;
      else    e = (jA0 + k <= jmax) ? EXP2(cA[k]) : 0.f;
      runA += e; plA[k] = runA;
    }
    float sA, TA;
    wave_scan64(runA, lane, sA, TA);
    float T = TA, sB = 0.f, runB = 0.f;
    if (!skipB){
      #pragma unroll
      for (int k = 0; k < 8; k++){
        float e;
        if (C3) e = (jB0 + k <= jmax) ? erHB[k] : 0.f;
        else    e = (jB0 + k <= jmax) ? EXP2(cB[k]) : 0.f;
        runB += e; plB[k] = runB;
      }
      float TB;
      wave_scan64(runB, lane, sB, TB);
      T = TA + TB;
    }

    const float inv1 = RCPF(T);
    const float cbaseA = (T - (sA - runA)) * inv1;
    const float fiA = (float)(i - jA0);
    float ls2 = 0.f;
    #pragma unroll
    for (int k = 0; k < 8; k++){
      float remn = fmaf(-plA[k], inv1, cbaseA);
      float pos  = fabsf(fiA - (float)k);
      float dist = SQRTF(fmaxf(remn * pos, 0.f));
      float eff  = fmaxf(EXP2(gm2 * dist), 1e-5f);
      float cv   = C3 ? cHA[k] : cA[k];
      float pp   = EXP2(cv * eff);
      ls2 += pp; plA[k] = pp;
    }
    if (!skipB){
      const float cbaseB = (T - (TA + sB - runB)) * inv1;
      const float fiB = (float)(i - jB0);
      #pragma unroll
      for (int k = 0; k < 8; k++){
        float remn = fmaf(-plB[k], inv1, cbaseB);
        float pos  = fabsf(fiB - (float)k);
        float dist = SQRTF(fmaxf(remn * pos, 0.f));
        float eff  = fmaxf(EXP2(gm2 * dist), 1e-5f);
        float cv   = C3 ? cHB[k] : cB[k];
        float pp   = EXP2(cv * eff);
        ls2 += pp; plB[k] = pp;
      }
    } else {
      #pragma unroll
      for (int k = 0; k < 8; k++){
        float e2 = C3 ? erHB[k] : EXP2(cB[k]);
        plB[k] = e2; ls2 += e2;
      }
    }
    ls2 = wave_sum64(ls2);
    if (lane == 0) ls2s[rl] = RCPF(ls2);

    uint4 oA, oB;
    oA.x = pk_rhu(plA[0], plA[1]);
    oA.y = pk_rhu(plA[2], plA[3]);
    oA.z = pk_rhu(plA[4], plA[5]);
    oA.w = pk_rhu(plA[6], plA[7]);
    oB.x = pk_rhu(plB[0], plB[1]);
    oB.y = pk_rhu(plB[2], plB[3]);
    oB.z = pk_rhu(plB[4], plB[5]);
    oB.w = pk_rhu(plB[6], plB[7]);
    *(uint4*)&rowp[jA0] = oA;
    *(uint4*)&rowp[jB0] = oB;
  }
  __syncthreads();

  // ---------- phase 3: ctx = att @ V (VT prefetched from global), scale by inv2 ----------
  f32x4 acc = (f32x4){0.f,0.f,0.f,0.f};
  const unsigned short* vrow = &vtp[(size_t)(w*16 + lm) * S];
  bf16x8 bv0 = *(const bf16x8*)&vrow[q*8];
  bf16x8 bv1 = *(const bf16x8*)&vrow[32 + q*8];
  for (int kc = 0; kc < S; kc += 64){
    bf16x8 nb0, nb1;
    if (kc + 64 < S){
      nb0 = *(const bf16x8*)&vrow[kc + 64 + q*8];
      nb1 = *(const bf16x8*)&vrow[kc + 96 + q*8];
    }
    bf16x8 a0 = *(const bf16x8*)&att[lm * ATT_LD + kc + q*8];
    bf16x8 a1 = *(const bf16x8*)&att[lm * ATT_LD + kc + 32 + q*8];
    acc = MFMA(a0, bv0, acc);
    acc = MFMA(a1, bv1, acc);
    bv0 = nb0; bv1 = nb1;
  }
  #pragma unroll
  for (int rr = 0; rr < 4; rr++){
    const int rl = q*4 + rr;
    const float sc = ls2s[rl];
    const int row = i0 + rl;
    ctxp[((size_t)b * S + row) * D + h * DKH + w*16 + lm] = f2bf(acc[rr] * sc);
  }
}

// ================= residual + LayerNorm -> bf16 (batched, DPP + float2) =================
// DPP wave reductions (2 barriers) + float2 loads / packed uint store.
struct LNJobs {
  const float* resid[2];
  const float* y[2];
  const float* ls[2];
  const float* lb[2];
  unsigned short* out[2];
  int bcast[2];
};
__global__ __launch_bounds__(256) void ln_residual_b(LNJobs j)
{
  const int z = blockIdx.y;
  const int r = blockIdx.x, t = threadIdx.x;
  const int w = t >> 6, lane = t & 63;
  __shared__ float p1[4], p2[4];
  const size_t base = (size_t)r * D;
  const float* resid = j.resid[z];
  const float* y = j.y[z];
  const int bcast = j.bcast[z];
  float2 rv = bcast ? *(const float2*)&resid[2*t] : *(const float2*)&resid[base + 2*t];
  float2 yv = *(const float2*)&y[base + 2*t];
  float x0 = rv.x + yv.x;
  float x1 = rv.y + yv.y;
  float s = wave_sum64(x0 + x1);
  if (lane == 0) p1[w] = s;
  __syncthreads();
  float mean = ((p1[0] + p1[1]) + (p1[2] + p1[3])) * (1.0f / 512.0f);
  float d0 = x0 - mean, d1 = x1 - mean;
  float v = wave_sum64(d0*d0 + d1*d1);
  if (lane == 0) p2[w] = v;
  __syncthreads();
  float var = ((p2[0] + p2[1]) + (p2[2] + p2[3])) * (1.0f / 512.0f);
  float inv = rsqrtf(var + 1e-5f);
  float2 lsv = *(const float2*)&j.ls[z][2*t];
  float2 lbv = *(const float2*)&j.lb[z][2*t];
  unsigned int o = (unsigned int)f2bf(d0 * inv * lsv.x + lbv.x)
                 | ((unsigned int)f2bf(d1 * inv * lsv.y + lbv.y) << 16);
  *(unsigned int*)&j.out[z][base + 2*t] = o;
}

// ================= fp32 -> bf16 conversions (float4 vectorized) + know role =================
struct CvtJobs {
  const float* s[12];
  unsigned short* d[12];
  int n[12];                       // all multiples of 4
  const float* know; const float* Wq3; const float* bq3; float* q3;
  const float* Wlk; const float* blk_; float* keyt;
};
__global__ __launch_bounds__(256) void cvt_all(CvtJobs jb){
  const int z = blockIdx.y;
  if (z == 12){
    // ---- know-derived role (reads raw inputs only) ----
    if (blockIdx.x >= 144) return;
    if (blockIdx.x < 128){
      const int wv = (blockIdx.x * 256 + threadIdx.x) >> 6;
      const int lane = threadIdx.x & 63;
      const float* wr = jb.Wq3 + (size_t)wv * 512 + lane * 8;
      const float* kr = jb.know + lane * 8;
      float4 w0 = *(const float4*)&wr[0], w1 = *(const float4*)&wr[4];
      float4 k0 = *(const float4*)&kr[0], k1 = *(const float4*)&kr[4];
      float p = w0.x*k0.x + w0.y*k0.y + w0.z*k0.z + w0.w*k0.w
              + w1.x*k1.x + w1.y*k1.y + w1.z*k1.z + w1.w*k1.w;
      p = wave_sum64(p);
      if (lane == 0) jb.q3[wv] = p + jb.bq3[wv];
    } else {
      int idx = (blockIdx.x - 128) * 256 + threadIdx.x;
      int h = idx >> 9, n = idx & 511;
      float acc = 0.f;
      for (int i = 0; i < 64; i++) acc += jb.know[h * 64 + i] * jb.Wlk[(size_t)n * 64 + i];
      jb.keyt[idx] = 1.f / (1.f + __expf(-(acc + jb.blk_[n])));
    }
    return;
  }
  const int n4 = jb.n[z] >> 2;
  const float4* s = (const float4*)jb.s[z];
  uint2* d = (uint2*)jb.d[z];
  for (int idx = blockIdx.x * 256 + threadIdx.x; idx < n4; idx += gridDim.x * 256){
    float4 v = s[idx];
    uint2 o;
    o.x = (unsigned int)f2bf(v.x) | ((unsigned int)f2bf(v.y) << 16);
    o.y = (unsigned int)f2bf(v.z) | ((unsigned int)f2bf(v.w) << 16);
    d[idx] = o;
  }
}

// ================= fused val GEMM + sigmoid + alpha-combine =================
__global__ __launch_bounds__(256) void val_fused(
    const unsigned short* __restrict__ Ah,
    const unsigned short* __restrict__ Wv,
    const float* __restrict__ blv,
    const float* __restrict__ alpha,
    float* __restrict__ out)
{
  __shared__ __align__(16) short As[128][32];
  __shared__ __align__(16) short Ws[128][32];
  __shared__ float als[128];
  const int t = threadIdx.x;
  const int n0 = blockIdx.x * 128, m0 = blockIdx.y * 128;
  if (t < 128) als[t] = alpha[m0 + t];
  const int w = t >> 6, lane = t & 63;
  const int wm = (w >> 1) << 6, wn = (w & 1) << 6;
  const int lm = lane & 15, q = lane >> 4;
  const int r = t >> 2, cc = (t & 3) << 3;
  f32x4 acc[4][4];
  #pragma unroll
  for (int a_ = 0; a_ < 4; a_++)
    #pragma unroll
    for (int b_ = 0; b_ < 4; b_++)
      acc[a_][b_] = (f32x4){0.f, 0.f, 0.f, 0.f};
  for (int k0 = 0; k0 < 64; k0 += 32){
    *(uint4*)&As[r][cc]      = *(const uint4*)&Ah[(size_t)(m0 + r) * 64 + k0 + cc];
    *(uint4*)&As[r + 64][cc] = *(const uint4*)&Ah[(size_t)(m0 + r + 64) * 64 + k0 + cc];
    *(uint4*)&Ws[r][cc]      = *(const uint4*)&Wv[(size_t)(n0 + r) * 64 + k0 + cc];
    *(uint4*)&Ws[r + 64][cc] = *(const uint4*)&Wv[(size_t)(n0 + r + 64) * 64 + k0 + cc];
    __syncthreads();
    bf16x8 af[4], bf[4];
    #pragma unroll
    for (int mt = 0; mt < 4; mt++) af[mt] = *(const bf16x8*)&As[wm + mt*16 + lm][q*8];
    #pragma unroll
    for (int nt = 0; nt < 4; nt++) bf[nt] = *(const bf16x8*)&Ws[wn + nt*16 + lm][q*8];
    #pragma unroll
    for (int mt = 0; mt < 4; mt++)
      #pragma unroll
      for (int nt = 0; nt < 4; nt++)
        acc[mt][nt] = MFMA(af[mt], bf[nt], acc[mt][nt]);
    __syncthreads();
  }
  #pragma unroll
  for (int nt = 0; nt < 4; nt++){
    const int n = n0 + wn + nt*16 + lm;
    const float bs = blv[n];
    #pragma unroll
    for (int mt = 0; mt < 4; mt++){
      const int mb = m0 + wm + mt*16;
      f32x4 c = acc[mt][nt];
      float part = 0.f;
      #pragma unroll
      for (int rr = 0; rr < 4; rr++){
        const int ml = (mb - m0) + (q << 2) + rr;
        float sg = 1.f / (1.f + __expf(-(c[rr] + bs)));
        part += als[ml] * sg;
      }
      part += __shfl_xor(part, 16, 64);
      if ((q & 1) == 0){
        const int srow = (mb >> 3) + (q >> 1);
        out[(size_t)srow * D + n] = part;
      }
    }
  }
}

// ================= orchestration =================
extern "C" void kernel_launch(void* const* d_in, const int* in_sizes, int n_in,
                              void* d_out, int out_size, void* d_ws, size_t ws_size,
                              hipStream_t stream) {
  const float* q_emb  = (const float*)d_in[0];
  const float* qa_emb = (const float*)d_in[1];
  const float* Wq1 = (const float*)d_in[2],  *bq1 = (const float*)d_in[3];
  const float* Wv1 = (const float*)d_in[4],  *bv1 = (const float*)d_in[5];
  const float* Wo1 = (const float*)d_in[6],  *bo1 = (const float*)d_in[7];
  const float* g1  = (const float*)d_in[8],  *ls1 = (const float*)d_in[9],  *lb1 = (const float*)d_in[10];
  const float* Wq2 = (const float*)d_in[11], *bq2 = (const float*)d_in[12];
  const float* Wv2 = (const float*)d_in[13], *bv2 = (const float*)d_in[14];
  const float* Wo2 = (const float*)d_in[15], *bo2 = (const float*)d_in[16];
  const float* g2  = (const float*)d_in[17], *ls2 = (const float*)d_in[18], *lb2 = (const float*)d_in[19];
  const float* Wq3 = (const float*)d_in[20], *bq3 = (const float*)d_in[21];
  const float* Wk3 = (const float*)d_in[22], *bk3 = (const float*)d_in[23];
  const float* Wv3 = (const float*)d_in[24], *bv3 = (const float*)d_in[25];
  const float* Wo3 = (const float*)d_in[26], *bo3 = (const float*)d_in[27];
  const float* g3  = (const float*)d_in[28], *ls3 = (const float*)d_in[29], *lb3 = (const float*)d_in[30];
  const float* know = (const float*)d_in[31];
  const float* Wlk  = (const float*)d_in[32], *b_lk = (const float*)d_in[33];
  const float* Wlv  = (const float*)d_in[34], *b_lv = (const float*)d_in[35];
  float* outp = (float*)d_out;

  const size_t NSD = (size_t)BB * S * D;   // 2,097,152
  unsigned short* p = (unsigned short*)d_ws;
  unsigned short* qk1b = p; p += NSD;
  unsigned short* v1b  = p; p += NSD;
  unsigned short* qk2b = p; p += NSD;
  unsigned short* v2b  = p; p += NSD;
  unsigned short* k3b  = p; p += NSD;
  unsigned short* v3b  = p; p += NSD;
  unsigned short* ctx1b= p; p += NSD;
  unsigned short* ctx2b= p; p += NSD;
  unsigned short* ctx3b= p; p += NSD;
  unsigned short* xqb  = p; p += NSD;
  unsigned short* xab  = p; p += NSD;
  unsigned short* hqb  = p; p += NSD;
  unsigned short* hab  = p; p += NSD;
  unsigned short* hfb  = p; p += NSD;
  unsigned short* vt1  = p; p += NSD;   // [32][64][1024]
  unsigned short* vt2  = p; p += NSD;
  unsigned short* vt3  = p; p += NSD;
  unsigned short* wb   = p; p += (size_t)9 * D * D;
  unsigned short* wlvb = p; p += (size_t)D * DKH;
  float* yv0   = (float*)p;
  float* yv1   = yv0 + NSD;
  float* q3    = yv1 + NSD;
  float* keyt  = q3 + 512;
  float* c3    = keyt + 4096;
  float* alpha = c3 + (size_t)BB * H * S;

  unsigned short* Wq1b = wb + 0*(size_t)D*D;
  unsigned short* Wv1b = wb + 1*(size_t)D*D;
  unsigned short* Wo1b = wb + 2*(size_t)D*D;
  unsigned short* Wq2b = wb + 3*(size_t)D*D;
  unsigned short* Wv2b = wb + 4*(size_t)D*D;
  unsigned short* Wo2b = wb + 5*(size_t)D*D;
  unsigned short* Wk3b = wb + 6*(size_t)D*D;
  unsigned short* Wv3b = wb + 7*(size_t)D*D;
  unsigned short* Wo3b = wb + 8*(size_t)D*D;

  // ---- conversions (vectorized) + know-derived precompute (merged z=12) ----
  CvtJobs jb;
  jb.s[0] = q_emb;  jb.d[0] = xqb;  jb.n[0] = (int)NSD;
  jb.s[1] = qa_emb; jb.d[1] = xab;  jb.n[1] = (int)NSD;
  jb.s[2] = Wq1; jb.d[2] = Wq1b; jb.n[2] = D*D;
  jb.s[3] = Wv1; jb.d[3] = Wv1b; jb.n[3] = D*D;
  jb.s[4] = Wo1; jb.d[4] = Wo1b; jb.n[4] = D*D;
  jb.s[5] = Wq2; jb.d[5] = Wq2b; jb.n[5] = D*D;
  jb.s[6] = Wv2; jb.d[6] = Wv2b; jb.n[6] = D*D;
  jb.s[7] = Wo2; jb.d[7] = Wo2b; jb.n[7] = D*D;
  jb.s[8] = Wk3; jb.d[8] = Wk3b; jb.n[8] = D*D;
  jb.s[9] = Wv3; jb.d[9] = Wv3b; jb.n[9] = D*D;
  jb.s[10] = Wo3; jb.d[10] = Wo3b; jb.n[10] = D*D;
  jb.s[11] = Wlv; jb.d[11] = wlvb; jb.n[11] = D*DKH;
  jb.know = know; jb.Wq3 = Wq3; jb.bq3 = bq3; jb.q3 = q3;
  jb.Wlk = Wlk; jb.blk_ = b_lk; jb.keyt = keyt;
  cvt_all<<<dim3(256, 13), 256, 0, stream>>>(jb);

  // ---- blocks 1&2: projections (z=4) ----
  {
    GemmJobs g;
    g.A[0]=xqb; g.W[0]=Wq1b; g.bias[0]=bq1; g.C[0]=qk1b;
    g.A[1]=xqb; g.W[1]=Wv1b; g.bias[1]=bv1; g.C[1]=v1b;
    g.A[2]=xab; g.W[2]=Wq2b; g.bias[2]=bq2; g.C[2]=qk2b;
    g.A[3]=xab; g.W[3]=Wv2b; g.bias[3]=bv2; g.C[3]=v2b;
    mfma_gemm_b<1><<<dim3(4, 32, 4), 256, 0, stream>>>(g);
  }
  { VTArgs a; a.v[0]=v1b; a.v[1]=v2b; a.vt[0]=vt1; a.vt[1]=vt2; a.nz=2;
    a.vtblocks=1024; a.keyt=keyt; a.q_emb=q_emb; a.alpha=alpha;
    a.q3=nullptr; a.k3=nullptr; a.c3=nullptr;
    vt_kernel<<<dim3(2048), 256, 0, stream>>>(a); }
  { FAArgs a;
    a.qk[0]=qk1b; a.qk[1]=qk2b; a.vt[0]=vt1; a.vt[1]=vt2;
    a.ctx[0]=ctx1b; a.ctx[1]=ctx2b; a.g[0]=g1; a.g[1]=g2;
    a.c3=nullptr; a.diag=0; a.zero_pad=0; a.nz=2;
    fused_attn<0><<<dim3(4096), 256, 0, stream>>>(a); }
  {
    GemmJobs g;
    g.A[0]=ctx1b; g.W[0]=Wo1b; g.bias[0]=bo1; g.C[0]=yv0;
    g.A[1]=ctx2b; g.W[1]=Wo2b; g.bias[1]=bo2; g.C[1]=yv1;
    g.A[2]=ctx1b; g.W[2]=Wo1b; g.bias[2]=bo1; g.C[2]=yv0;
    g.A[3]=ctx1b; g.W[3]=Wo1b; g.bias[3]=bo1; g.C[3]=yv0;
    mfma_gemm_b<0><<<dim3(4, 32, 2), 256, 0, stream>>>(g);
  }
  {
    LNJobs lj;
    lj.resid[0]=q_emb;  lj.y[0]=yv0; lj.ls[0]=ls1; lj.lb[0]=lb1; lj.out[0]=hqb; lj.bcast[0]=0;
    lj.resid[1]=qa_emb; lj.y[1]=yv1; lj.ls[1]=ls2; lj.lb[1]=lb2; lj.out[1]=hab; lj.bcast[1]=0;
    ln_residual_b<<<dim3(BB*S, 2), 256, 0, stream>>>(lj);
  }

  // ---- block 3 ----
  {
    GemmJobs g;
    g.A[0]=hqb; g.W[0]=Wk3b; g.bias[0]=bk3; g.C[0]=k3b;
    g.A[1]=hab; g.W[1]=Wv3b; g.bias[1]=bv3; g.C[1]=v3b;
    g.A[2]=hqb; g.W[2]=Wk3b; g.bias[2]=bk3; g.C[2]=k3b;
    g.A[3]=hqb; g.W[3]=Wk3b; g.bias[3]=bk3; g.C[3]=k3b;
    mfma_gemm_b<1><<<dim3(4, 32, 2), 256, 0, stream>>>(g);
  }
  { VTArgs a; a.v[0]=v3b; a.v[1]=v3b; a.vt[0]=vt3; a.vt[1]=vt3; a.nz=1;
    a.vtblocks=512; a.keyt=nullptr; a.q_emb=nullptr; a.alpha=nullptr;
    a.q3=q3; a.k3=k3b; a.c3=c3;
    vt_kernel<<<dim3(1024), 256, 0, stream>>>(a); }
  { FAArgs a;
    a.qk[0]=k3b; a.qk[1]=k3b; a.vt[0]=vt3; a.vt[1]=vt3;
    a.ctx[0]=ctx3b; a.ctx[1]=ctx3b; a.g[0]=g3; a.g[1]=g3;
    a.c3=c3; a.diag=-1; a.zero_pad=1; a.nz=1;
    fused_attn<1><<<dim3(2048), 256, 0, stream>>>(a); }
  {
    GemmJobs g;
    g.A[0]=ctx3b; g.W[0]=Wo3b; g.bias[0]=bo3; g.C[0]=yv0;
    g.A[1]=ctx3b; g.W[1]=Wo3b; g.bias[1]=bo3; g.C[1]=yv0;
    g.A[2]=ctx3b; g.W[2]=Wo3b; g.bias[2]=bo3; g.C[2]=yv0;
    g.A[3]=ctx3b; g.W[3]=Wo3b; g.bias[3]=bo3; g.C[3]=yv0;
    mfma_gemm_b<0><<<dim3(4, 32, 1), 256, 0, stream>>>(g);
  }
  {
    LNJobs lj;
    lj.resid[0]=know; lj.y[0]=yv0; lj.ls[0]=ls3; lj.lb[0]=lb3; lj.out[0]=hfb; lj.bcast[0]=1;
    lj.resid[1]=know; lj.y[1]=yv0; lj.ls[1]=ls3; lj.lb[1]=lb3; lj.out[1]=hfb; lj.bcast[1]=1;
    ln_residual_b<<<dim3(BB*S, 1), 256, 0, stream>>>(lj);
  }

  // ---- final combine (alphas computed in vt12 launch) ----
  val_fused<<<dim3(4, 256), 256, 0, stream>>>(hfb, wlvb, b_lv, alpha, outp);
}

// Round 11
// 416.603 us; speedup vs baseline: 1.0507x; 1.0031x over previous
//
#include <hip/hip_runtime.h>
#include <math.h>

#define BB 4
#define S 1024
#define D 512
#define H 8
#define DKH 64

#define ATT_LD 1032   // att row stride (shorts): 516 dwords == 4 mod 32 (2-way = free)
#define LOG2E 1.4426950408889634f

typedef __attribute__((ext_vector_type(8))) short bf16x8;
typedef __attribute__((ext_vector_type(4))) float f32x4;

#if __has_builtin(__builtin_amdgcn_exp2f)
#define EXP2(x) __builtin_amdgcn_exp2f(x)
#else
#define EXP2(x) exp2f(x)
#endif
#if __has_builtin(__builtin_amdgcn_sqrtf)
#define SQRTF(x) __builtin_amdgcn_sqrtf(x)
#else
#define SQRTF(x) sqrtf(x)
#endif
#if __has_builtin(__builtin_amdgcn_rcpf)
#define RCPF(x) __builtin_amdgcn_rcpf(x)
#else
#define RCPF(x) (1.0f / (x))
#endif

__device__ __forceinline__ unsigned short f2bf(float f){
  unsigned int u = __float_as_uint(f);
  u += 0x7FFFu + ((u >> 16) & 1u);
  return (unsigned short)(u >> 16);
}
__device__ __forceinline__ unsigned short f2bf_rhu(float f){
  return (unsigned short)((__float_as_uint(f) + 0x8000u) >> 16);
}
__device__ __forceinline__ unsigned int pk_rhu(float lo, float hi){
  unsigned int a = __float_as_uint(lo) + 0x8000u;
  unsigned int b = __float_as_uint(hi) + 0x8000u;
#if __has_builtin(__builtin_amdgcn_perm)
  return __builtin_amdgcn_perm(b, a, 0x07060302u);
#else
  return (a >> 16) | (b & 0xffff0000u);
#endif
}
__device__ __forceinline__ float bf2f(unsigned int v){
  return __uint_as_float(v << 16);
}
__device__ __forceinline__ f32x4 MFMA(bf16x8 a, bf16x8 b, f32x4 c){
  return __builtin_amdgcn_mfma_f32_16x16x32_bf16(a, b, c, 0, 0, 0);
}
__device__ __forceinline__ void gl_lds16(const void* g, void* l){
  __builtin_amdgcn_global_load_lds(
      (const __attribute__((address_space(1))) void*)g,
      (__attribute__((address_space(3))) void*)l, 16, 0, 0);
}

// ---- DPP cross-lane (pure VALU pipe, no ds_bpermute latency) ----
template<int CTRL>
__device__ __forceinline__ float dppadd(float v){
  int s = __builtin_amdgcn_update_dpp(0, __float_as_int(v), CTRL, 0xf, 0xf, true);
  return v + __int_as_float(s);
}
__device__ __forceinline__ float rdl(float v, int l){
  return __int_as_float(__builtin_amdgcn_readlane(__float_as_int(v), l));
}
// inclusive 64-lane prefix (order-exact) + total, via 16-lane row scans + row offsets
__device__ __forceinline__ void wave_scan64(float v, int lane, float& incl, float& total){
  float r = dppadd<0x111>(v);   // row_shr:1
  r = dppadd<0x112>(r);         // row_shr:2
  r = dppadd<0x114>(r);         // row_shr:4
  r = dppadd<0x118>(r);         // row_shr:8
  float t0 = rdl(r, 15), t1 = rdl(r, 31), t2 = rdl(r, 47), t3 = rdl(r, 63);
  const int row = lane >> 4;
  float off = (row > 0 ? t0 : 0.f) + (row > 1 ? t1 : 0.f) + (row > 2 ? t2 : 0.f);
  incl = r + off;
  total = (t0 + t1) + (t2 + t3);
}
__device__ __forceinline__ float wave_sum64(float v){
  float r = dppadd<0x111>(v);
  r = dppadd<0x112>(r);
  r = dppadd<0x114>(r);
  r = dppadd<0x118>(r);
  return (rdl(r, 15) + rdl(r, 31)) + (rdl(r, 47) + rdl(r, 63));
}

// ================= batched projection GEMM (M=4096,N=512,K=512) =================
// Epilogue stages the C-tile through LDS (reusing the staging buffers) so
// global writes are coalesced uint4 instead of 64 scalar b16/b32 per lane.
struct GemmJobs {
  const unsigned short* A[4];
  const unsigned short* W[4];
  const float* bias[4];
  void* C[4];
};
template<int OUTBF>
__global__ __launch_bounds__(256) void mfma_gemm_b(GemmJobs jb)
{
  __shared__ __align__(16) char SB[17408];
  short (*As)[32] = (short(*)[32])SB;
  short (*Ws)[32] = (short(*)[32])(SB + 8192);
  const int t = threadIdx.x;
  const int z = blockIdx.z;
  const int n0 = blockIdx.x * 128, m0 = blockIdx.y * 128;
  const unsigned short* A = jb.A[z];
  const unsigned short* W = jb.W[z];
  const float* bias = jb.bias[z];
  const int w = t >> 6, lane = t & 63;
  const int wm = (w >> 1) << 6, wn = (w & 1) << 6;
  const int lm = lane & 15, q = lane >> 4;
  const int r = t >> 2, cc = (t & 3) << 3;
  char* ldsA = ((char*)&As[0][0]) + w * 1024;
  char* ldsW = ((char*)&Ws[0][0]) + w * 1024;
  f32x4 acc[4][4];
  #pragma unroll
  for (int a_ = 0; a_ < 4; a_++)
    #pragma unroll
    for (int b_ = 0; b_ < 4; b_++)
      acc[a_][b_] = (f32x4){0.f, 0.f, 0.f, 0.f};
  for (int k0 = 0; k0 < D; k0 += 32){
    gl_lds16(&A[(size_t)(m0 + r)      * D + k0 + cc], ldsA);
    gl_lds16(&A[(size_t)(m0 + r + 64) * D + k0 + cc], ldsA + 4096);
    gl_lds16(&W[(size_t)(n0 + r)      * D + k0 + cc], ldsW);
    gl_lds16(&W[(size_t)(n0 + r + 64) * D + k0 + cc], ldsW + 4096);
    __syncthreads();
    bf16x8 af[4], bf[4];
    #pragma unroll
    for (int mt = 0; mt < 4; mt++) af[mt] = *(const bf16x8*)&As[wm + mt*16 + lm][q*8];
    #pragma unroll
    for (int nt = 0; nt < 4; nt++) bf[nt] = *(const bf16x8*)&Ws[wn + nt*16 + lm][q*8];
    #pragma unroll
    for (int mt = 0; mt < 4; mt++)
      #pragma unroll
      for (int nt = 0; nt < 4; nt++)
        acc[mt][nt] = MFMA(af[mt], bf[nt], acc[mt][nt]);
    __syncthreads();
  }
  if (OUTBF){
    // 2 chunks of 64 rows; LDS tile [64][136] bf16 (stride 136: 16B-aligned rows,
    // q-groups 2-way on banks = free)
    unsigned short* EP = (unsigned short*)SB;
    #pragma unroll
    for (int ch = 0; ch < 2; ch++){
      __syncthreads();
      if ((w >> 1) == ch){
        #pragma unroll
        for (int nt = 0; nt < 4; nt++){
          const int col = wn + nt*16 + lm;
          const float bs = bias[n0 + col];
          #pragma unroll
          for (int mt = 0; mt < 4; mt++)
            #pragma unroll
            for (int rr = 0; rr < 4; rr++)
              EP[(mt*16 + q*4 + rr) * 136 + col] = f2bf(acc[mt][nt][rr] + bs);
        }
      }
      __syncthreads();
      #pragma unroll
      for (int pp = 0; pp < 4; pp++){
        int linid = t + pp*256;
        int row = linid >> 4, c8 = (linid & 15) << 3;
        uint4 v = *(const uint4*)&EP[row*136 + c8];
        *(uint4*)&((unsigned short*)jb.C[z])[(size_t)(m0 + ch*64 + row)*D + n0 + c8] = v;
      }
    }
  } else {
    // 4 chunks of 32 rows; LDS tile [32][132] fp32 (stride 132: aligned, 2-way banks)
    float* EP = (float*)SB;
    #pragma unroll
    for (int ch = 0; ch < 4; ch++){
      __syncthreads();
      if ((w >> 1) == (ch >> 1)){
        #pragma unroll
        for (int mi = 0; mi < 2; mi++){
          const int mt = (ch & 1)*2 + mi;
          #pragma unroll
          for (int nt = 0; nt < 4; nt++){
            const int col = wn + nt*16 + lm;
            const float bs = bias[n0 + col];
            #pragma unroll
            for (int rr = 0; rr < 4; rr++)
              EP[(mi*16 + q*4 + rr)*132 + col] = acc[mt][nt][rr] + bs;
          }
        }
      }
      __syncthreads();
      #pragma unroll
      for (int pp = 0; pp < 4; pp++){
        int linid = t + pp*256;
        int row = linid >> 5, c4 = (linid & 31) << 2;
        uint4 v = *(const uint4*)&EP[row*132 + c4];
        *(uint4*)&((float*)jb.C[z])[(size_t)(m0 + ch*32 + row)*D + n0 + c4] = v;
      }
    }
  }
}

// ================= V transpose (+ merged alphas / scores3 roles) =================
#define KS_LD 66
struct VTArgs {
  const unsigned short* v[2]; unsigned short* vt[2]; int nz;
  int vtblocks;
  const float* keyt; const float* q_emb; float* alpha;
  const float* q3; const unsigned short* k3; float* c3;
};
__global__ __launch_bounds__(256) void vt_kernel(VTArgs a)
{
  __shared__ unsigned short tile[64 * KS_LD];
  if ((int)blockIdx.x >= a.vtblocks){
    const int ext = blockIdx.x - a.vtblocks;
    if (a.alpha){
      const int row = ext * 4 + (threadIdx.x >> 6);
      const int l = threadIdx.x & 63;
      const int h = l >> 3, sub = l & 7;
      const float* qr = a.q_emb + (size_t)row * D;
      const float* kt = a.keyt + h * D;
      float p = 0.f;
      for (int d = sub; d < D; d += 8) p += kt[d] * qr[d];
      p += __shfl_xor(p, 1, 64);
      p += __shfl_xor(p, 2, 64);
      p += __shfl_xor(p, 4, 64);
      float m = p;
      m = fmaxf(m, __shfl_xor(m, 8, 64));
      m = fmaxf(m, __shfl_xor(m, 16, 64));
      m = fmaxf(m, __shfl_xor(m, 32, 64));
      float e = __expf(p - m);
      float ssum = e;
      ssum += __shfl_xor(ssum, 8, 64);
      ssum += __shfl_xor(ssum, 16, 64);
      ssum += __shfl_xor(ssum, 32, 64);
      if (sub == 0) a.alpha[(size_t)row * H + h] = e / ssum;
    } else {
      int gid = ext * 64 + (threadIdx.x >> 2);
      int sub = threadIdx.x & 3;
      int j  = gid & (S - 1);
      int bh = gid >> 10;
      int h  = bh & 7, b = bh >> 3;
      const unsigned short* kp = a.k3 + ((size_t)b * S + j) * D + h * DKH + sub * 16;
      const float* qp = a.q3 + h * DKH + sub * 16;
      float acc = 0.f;
      #pragma unroll
      for (int d8 = 0; d8 < 16; d8 += 8){
        uint4 u = *(const uint4*)&kp[d8];
        unsigned int uu[4] = {u.x, u.y, u.z, u.w};
        #pragma unroll
        for (int mel = 0; mel < 4; mel++){
          acc += qp[d8 + 2*mel]     * bf2f(uu[mel] & 0xffffu);
          acc += qp[d8 + 2*mel + 1] * bf2f(uu[mel] >> 16);
        }
      }
      acc += __shfl_xor(acc, 1, 64);
      acc += __shfl_xor(acc, 2, 64);
      if (sub == 0) a.c3[gid] = acc * 0.125f;
    }
    return;
  }
  const int lin = blockIdx.x;
  const int xcd = lin & 7, slot = lin >> 3;
  const int j0 = (slot & 15) * 64;
  const int set = slot >> 4;
  const int z   = (a.nz == 2) ? (set & 1)  : 0;
  const int grp = (a.nz == 2) ? (set >> 1) : set;
  const int bh = xcd + 8 * grp, b = bh >> 3, h = bh & 7;
  const int t = threadIdx.x;
  const unsigned short* vp = a.v[z];
  unsigned short* vtp = a.vt[z] + (size_t)bh * 64 * S;
  #pragma unroll
  for (int p = 0; p < 2; p++){
    int lin2 = t + p * 256, row = lin2 >> 3, c8 = (lin2 & 7) << 3;
    *(uint4*)&tile[row * KS_LD + c8] =
      *(const uint4*)&vp[((size_t)b * S + j0 + row) * D + h * DKH + c8];
  }
  __syncthreads();
  #pragma unroll
  for (int p = 0; p < 2; p++){
    int lin2 = t + p * 256, d = lin2 >> 3, c8 = (lin2 & 7) << 3;
    unsigned short tmp[8];
    #pragma unroll
    for (int jx = 0; jx < 8; jx++) tmp[jx] = tile[(c8 + jx) * KS_LD + d];
    *(uint4*)&vtp[(size_t)d * S + j0 + c8] = *(const uint4*)tmp;
  }
}

// ================= fused attention: scores -> decay -> AV =================
// (r5/r9 structure exactly — best-measured configuration; frozen.)
struct FAArgs {
  const unsigned short* qk[2];   // q==k source (bf16, [b][S][D])
  const unsigned short* vt[2];   // VT (bf16, [bh][64][S])
  unsigned short* ctx[2];        // out (bf16, [b][S][D])
  const float* g[2];
  const float* c3;               // fp32 [b][h][S] (C3 mode)
  int diag, zero_pad, nz;
};
template<int C3>
__global__ __launch_bounds__(256, 4) void fused_attn(FAArgs a)
{
  __shared__ __align__(16) unsigned short att[16 * ATT_LD];   // 33,024 B
  __shared__ float ls2s[16];                                   // per-row inv2
  const int t = threadIdx.x;
  const int lin = blockIdx.x;
  const int xcd = lin & 7;
  const int slot = lin >> 3;
  const int i0 = (slot & 63) * 16;
  const int set = slot >> 6;
  const int z   = (a.nz == 2) ? (set & 1)  : 0;
  const int grp = (a.nz == 2) ? (set >> 1) : set;
  const int bh = xcd + 8 * grp, b = bh >> 3, h = bh & 7;
  const int w = t >> 6, lane = t & 63, lm = lane & 15, q = lane >> 4;
  const unsigned short* qkp = a.qk[z];
  const unsigned short* vtp = a.vt[z] + (size_t)bh * 64 * S;
  unsigned short* ctxp = a.ctx[z];
  float gm2;
  { float gv = a.g[z][h];
    gm2 = -((gv > 20.f) ? gv : log1pf(expf(gv))) * LOG2E; }   // log2-space gamma

  // ---------- phase 1: scores tile [16 x 1024] -> att (bf16), K prefetched ----------
  if (!C3){
    const size_t rowbase = (size_t)b * S;
    bf16x8 af0 = *(const bf16x8*)&qkp[(rowbase + i0 + lm) * D + h * DKH + q*8];
    bf16x8 af1 = *(const bf16x8*)&qkp[(rowbase + i0 + lm) * D + h * DKH + 32 + q*8];
    size_t kb = (rowbase + w*16 + lm) * D + h * DKH;
    bf16x8 bv0 = *(const bf16x8*)&qkp[kb + q*8];
    bf16x8 bv1 = *(const bf16x8*)&qkp[kb + 32 + q*8];
    for (int jc = 0; jc < S; jc += 64){
      bf16x8 nb0, nb1;
      if (jc + 64 < S){
        size_t kb2 = (rowbase + jc + 64 + w*16 + lm) * D + h * DKH;
        nb0 = *(const bf16x8*)&qkp[kb2 + q*8];
        nb1 = *(const bf16x8*)&qkp[kb2 + 32 + q*8];
      }
      f32x4 acc = (f32x4){0.f, 0.f, 0.f, 0.f};
      acc = MFMA(af0, bv0, acc);
      acc = MFMA(af1, bv1, acc);
      #pragma unroll
      for (int rr = 0; rr < 4; rr++)
        att[(q*4 + rr) * ATT_LD + jc + w*16 + lm] = f2bf_rhu(acc[rr] * 0.125f);
      bv0 = nb0; bv1 = nb1;
    }
  }
  __syncthreads();

  // ---------- phase 2: decay + double softmax, wave-per-row (4 rows/wave) ----------
  const int jA0 = lane * 8, jB0 = 512 + lane * 8;

  float cHA[8], cHB[8], erHA[8], erHB[8];
  if (C3){
    const float* c3p = a.c3 + ((size_t)b * H + h) * S;
    float4 x0 = *(const float4*)&c3p[lane*8];
    float4 x1 = *(const float4*)&c3p[lane*8 + 4];
    float4 y0 = *(const float4*)&c3p[512 + lane*8];
    float4 y1 = *(const float4*)&c3p[512 + lane*8 + 4];
    cHA[0]=x0.x*LOG2E; cHA[1]=x0.y*LOG2E; cHA[2]=x0.z*LOG2E; cHA[3]=x0.w*LOG2E;
    cHA[4]=x1.x*LOG2E; cHA[5]=x1.y*LOG2E; cHA[6]=x1.z*LOG2E; cHA[7]=x1.w*LOG2E;
    cHB[0]=y0.x*LOG2E; cHB[1]=y0.y*LOG2E; cHB[2]=y0.z*LOG2E; cHB[3]=y0.w*LOG2E;
    cHB[4]=y1.x*LOG2E; cHB[5]=y1.y*LOG2E; cHB[6]=y1.z*LOG2E; cHB[7]=y1.w*LOG2E;
    #pragma unroll
    for (int k = 0; k < 8; k++){ erHA[k] = EXP2(cHA[k]); erHB[k] = EXP2(cHB[k]); }
  }

  for (int rloc = 0; rloc < 4; rloc++){
    const int rl = w*4 + rloc;
    const int i = i0 + rl;
    unsigned short* rowp = &att[rl * ATT_LD];
    if (C3 && a.zero_pad && i == 0){
      uint4 zz = make_uint4(0u,0u,0u,0u);
      *(uint4*)&rowp[jA0] = zz;
      *(uint4*)&rowp[jB0] = zz;
      if (lane == 0) ls2s[0] = 1.f;
      continue;
    }

    const int jmax = i + a.diag;
    const bool skipB = (jmax < 512);     // wave-uniform

    float cA[8], cB[8], plA[8], plB[8];
    if (!C3){
      uint4 uA = *(const uint4*)&rowp[jA0];
      uint4 uB = *(const uint4*)&rowp[jB0];
      unsigned int ua[4] = {uA.x, uA.y, uA.z, uA.w};
      unsigned int ub[4] = {uB.x, uB.y, uB.z, uB.w};
      #pragma unroll
      for (int mel = 0; mel < 4; mel++){
        cA[mel*2]     = bf2f(ua[mel] & 0xffffu) * LOG2E;
        cA[mel*2 + 1] = bf2f(ua[mel] >> 16) * LOG2E;
        cB[mel*2]     = bf2f(ub[mel] & 0xffffu) * LOG2E;
        cB[mel*2 + 1] = bf2f(ub[mel] >> 16) * LOG2E;
      }
    }

    float runA = 0.f;
    #pragma unroll
    for (int k = 0; k < 8; k++){
      float e;
      if (C3) e = (jA0 + k <= jmax) ? erHA[k] : 0.f;
      else    e = (jA0 + k <= jmax) ? EXP2(cA[k]) : 0.f;
      runA += e; plA[k] = runA;
    }
    float sA, TA;
    wave_scan64(runA, lane, sA, TA);
    float T = TA, sB = 0.f, runB = 0.f;
    if (!skipB){
      #pragma unroll
      for (int k = 0; k < 8; k++){
        float e;
        if (C3) e = (jB0 + k <= jmax) ? erHB[k] : 0.f;
        else    e = (jB0 + k <= jmax) ? EXP2(cB[k]) : 0.f;
        runB += e; plB[k] = runB;
      }
      float TB;
      wave_scan64(runB, lane, sB, TB);
      T = TA + TB;
    }

    const float inv1 = RCPF(T);
    const float cbaseA = (T - (sA - runA)) * inv1;
    const float fiA = (float)(i - jA0);
    float ls2 = 0.f;
    #pragma unroll
    for (int k = 0; k < 8; k++){
      float remn = fmaf(-plA[k], inv1, cbaseA);
      float pos  = fabsf(fiA - (float)k);
      float dist = SQRTF(fmaxf(remn * pos, 0.f));
      float eff  = fmaxf(EXP2(gm2 * dist), 1e-5f);
      float cv   = C3 ? cHA[k] : cA[k];
      float pp   = EXP2(cv * eff);
      ls2 += pp; plA[k] = pp;
    }
    if (!skipB){
      const float cbaseB = (T - (TA + sB - runB)) * inv1;
      const float fiB = (float)(i - jB0);
      #pragma unroll
      for (int k = 0; k < 8; k++){
        float remn = fmaf(-plB[k], inv1, cbaseB);
        float pos  = fabsf(fiB - (float)k);
        float dist = SQRTF(fmaxf(remn * pos, 0.f));
        float eff  = fmaxf(EXP2(gm2 * dist), 1e-5f);
        float cv   = C3 ? cHB[k] : cB[k];
        float pp   = EXP2(cv * eff);
        ls2 += pp; plB[k] = pp;
      }
    } else {
      #pragma unroll
      for (int k = 0; k < 8; k++){
        float e2 = C3 ? erHB[k] : EXP2(cB[k]);
        plB[k] = e2; ls2 += e2;
      }
    }
    ls2 = wave_sum64(ls2);
    if (lane == 0) ls2s[rl] = RCPF(ls2);

    uint4 oA, oB;
    oA.x = pk_rhu(plA[0], plA[1]);
    oA.y = pk_rhu(plA[2], plA[3]);
    oA.z = pk_rhu(plA[4], plA[5]);
    oA.w = pk_rhu(plA[6], plA[7]);
    oB.x = pk_rhu(plB[0], plB[1]);
    oB.y = pk_rhu(plB[2], plB[3]);
    oB.z = pk_rhu(plB[4], plB[5]);
    oB.w = pk_rhu(plB[6], plB[7]);
    *(uint4*)&rowp[jA0] = oA;
    *(uint4*)&rowp[jB0] = oB;
  }
  __syncthreads();

  // ---------- phase 3: ctx = att @ V (VT prefetched from global), scale by inv2 ----------
  f32x4 acc = (f32x4){0.f,0.f,0.f,0.f};
  const unsigned short* vrow = &vtp[(size_t)(w*16 + lm) * S];
  bf16x8 bv0 = *(const bf16x8*)&vrow[q*8];
  bf16x8 bv1 = *(const bf16x8*)&vrow[32 + q*8];
  for (int kc = 0; kc < S; kc += 64){
    bf16x8 nb0, nb1;
    if (kc + 64 < S){
      nb0 = *(const bf16x8*)&vrow[kc + 64 + q*8];
      nb1 = *(const bf16x8*)&vrow[kc + 96 + q*8];
    }
    bf16x8 a0 = *(const bf16x8*)&att[lm * ATT_LD + kc + q*8];
    bf16x8 a1 = *(const bf16x8*)&att[lm * ATT_LD + kc + 32 + q*8];
    acc = MFMA(a0, bv0, acc);
    acc = MFMA(a1, bv1, acc);
    bv0 = nb0; bv1 = nb1;
  }
  #pragma unroll
  for (int rr = 0; rr < 4; rr++){
    const int rl = q*4 + rr;
    const float sc = ls2s[rl];
    const int row = i0 + rl;
    ctxp[((size_t)b * S + row) * D + h * DKH + w*16 + lm] = f2bf(acc[rr] * sc);
  }
}

// ================= residual + LayerNorm -> bf16 (2 rows/block, float4) =================
struct LNJobs {
  const float* resid[2];
  const float* y[2];
  const float* ls[2];
  const float* lb[2];
  unsigned short* out[2];
  int bcast[2];
};
__global__ __launch_bounds__(256) void ln_residual_b(LNJobs j)
{
  const int z = blockIdx.y;
  const int t = threadIdx.x;
  const int w = t >> 6, lane = t & 63;
  const int row = blockIdx.x * 2 + (t >> 7);   // waves 0,1 -> row even; 2,3 -> odd
  const int tl = t & 127;
  __shared__ float p1[4], p2[4];
  const size_t base = (size_t)row * D;
  const float* resid = j.resid[z];
  const float* y = j.y[z];
  const int bcast = j.bcast[z];
  float4 rv = bcast ? *(const float4*)&resid[4*tl] : *(const float4*)&resid[base + 4*tl];
  float4 yv = *(const float4*)&y[base + 4*tl];
  float x0 = rv.x + yv.x, x1 = rv.y + yv.y, x2 = rv.z + yv.z, x3 = rv.w + yv.w;
  float s = wave_sum64((x0 + x1) + (x2 + x3));
  if (lane == 0) p1[w] = s;
  __syncthreads();
  const int rw = (w >> 1) * 2;
  float mean = (p1[rw] + p1[rw+1]) * (1.0f / 512.0f);
  float d0 = x0 - mean, d1 = x1 - mean, d2 = x2 - mean, d3 = x3 - mean;
  float v = wave_sum64((d0*d0 + d1*d1) + (d2*d2 + d3*d3));
  if (lane == 0) p2[w] = v;
  __syncthreads();
  float var = (p2[rw] + p2[rw+1]) * (1.0f / 512.0f);
  float inv = rsqrtf(var + 1e-5f);
  float4 lsv = *(const float4*)&j.ls[z][4*tl];
  float4 lbv = *(const float4*)&j.lb[z][4*tl];
  uint2 o;
  o.x = (unsigned int)f2bf(d0 * inv * lsv.x + lbv.x)
      | ((unsigned int)f2bf(d1 * inv * lsv.y + lbv.y) << 16);
  o.y = (unsigned int)f2bf(d2 * inv * lsv.z + lbv.z)
      | ((unsigned int)f2bf(d3 * inv * lsv.w + lbv.w) << 16);
  *(uint2*)&j.out[z][base + 4*tl] = o;
}

// ================= fp32 -> bf16 conversions (float4 vectorized) + know role =================
struct CvtJobs {
  const float* s[12];
  unsigned short* d[12];
  int n[12];                       // all multiples of 4
  const float* know; const float* Wq3; const float* bq3; float* q3;
  const float* Wlk; const float* blk_; float* keyt;
};
__global__ __launch_bounds__(256) void cvt_all(CvtJobs jb){
  const int z = blockIdx.y;
  if (z == 12){
    if (blockIdx.x >= 144) return;
    if (blockIdx.x < 128){
      const int wv = (blockIdx.x * 256 + threadIdx.x) >> 6;
      const int lane = threadIdx.x & 63;
      const float* wr = jb.Wq3 + (size_t)wv * 512 + lane * 8;
      const float* kr = jb.know + lane * 8;
      float4 w0 = *(const float4*)&wr[0], w1 = *(const float4*)&wr[4];
      float4 k0 = *(const float4*)&kr[0], k1 = *(const float4*)&kr[4];
      float p = w0.x*k0.x + w0.y*k0.y + w0.z*k0.z + w0.w*k0.w
              + w1.x*k1.x + w1.y*k1.y + w1.z*k1.z + w1.w*k1.w;
      p = wave_sum64(p);
      if (lane == 0) jb.q3[wv] = p + jb.bq3[wv];
    } else {
      int idx = (blockIdx.x - 128) * 256 + threadIdx.x;
      int h = idx >> 9, n = idx & 511;
      float acc = 0.f;
      for (int i = 0; i < 64; i++) acc += jb.know[h * 64 + i] * jb.Wlk[(size_t)n * 64 + i];
      jb.keyt[idx] = 1.f / (1.f + __expf(-(acc + jb.blk_[n])));
    }
    return;
  }
  const int n4 = jb.n[z] >> 2;
  const float4* s = (const float4*)jb.s[z];
  uint2* d = (uint2*)jb.d[z];
  for (int idx = blockIdx.x * 256 + threadIdx.x; idx < n4; idx += gridDim.x * 256){
    float4 v = s[idx];
    uint2 o;
    o.x = (unsigned int)f2bf(v.x) | ((unsigned int)f2bf(v.y) << 16);
    o.y = (unsigned int)f2bf(v.z) | ((unsigned int)f2bf(v.w) << 16);
    d[idx] = o;
  }
}

// ================= fused val GEMM + sigmoid + alpha-combine =================
__global__ __launch_bounds__(256) void val_fused(
    const unsigned short* __restrict__ Ah,
    const unsigned short* __restrict__ Wv,
    const float* __restrict__ blv,
    const float* __restrict__ alpha,
    float* __restrict__ out)
{
  __shared__ __align__(16) short As[128][32];
  __shared__ __align__(16) short Ws[128][32];
  __shared__ float als[128];
  const int t = threadIdx.x;
  const int n0 = blockIdx.x * 128, m0 = blockIdx.y * 128;
  if (t < 128) als[t] = alpha[m0 + t];
  const int w = t >> 6, lane = t & 63;
  const int wm = (w >> 1) << 6, wn = (w & 1) << 6;
  const int lm = lane & 15, q = lane >> 4;
  const int r = t >> 2, cc = (t & 3) << 3;
  f32x4 acc[4][4];
  #pragma unroll
  for (int a_ = 0; a_ < 4; a_++)
    #pragma unroll
    for (int b_ = 0; b_ < 4; b_++)
      acc[a_][b_] = (f32x4){0.f, 0.f, 0.f, 0.f};
  for (int k0 = 0; k0 < 64; k0 += 32){
    *(uint4*)&As[r][cc]      = *(const uint4*)&Ah[(size_t)(m0 + r) * 64 + k0 + cc];
    *(uint4*)&As[r + 64][cc] = *(const uint4*)&Ah[(size_t)(m0 + r + 64) * 64 + k0 + cc];
    *(uint4*)&Ws[r][cc]      = *(const uint4*)&Wv[(size_t)(n0 + r) * 64 + k0 + cc];
    *(uint4*)&Ws[r + 64][cc] = *(const uint4*)&Wv[(size_t)(n0 + r + 64) * 64 + k0 + cc];
    __syncthreads();
    bf16x8 af[4], bf[4];
    #pragma unroll
    for (int mt = 0; mt < 4; mt++) af[mt] = *(const bf16x8*)&As[wm + mt*16 + lm][q*8];
    #pragma unroll
    for (int nt = 0; nt < 4; nt++) bf[nt] = *(const bf16x8*)&Ws[wn + nt*16 + lm][q*8];
    #pragma unroll
    for (int mt = 0; mt < 4; mt++)
      #pragma unroll
      for (int nt = 0; nt < 4; nt++)
        acc[mt][nt] = MFMA(af[mt], bf[nt], acc[mt][nt]);
    __syncthreads();
  }
  #pragma unroll
  for (int nt = 0; nt < 4; nt++){
    const int n = n0 + wn + nt*16 + lm;
    const float bs = blv[n];
    #pragma unroll
    for (int mt = 0; mt < 4; mt++){
      const int mb = m0 + wm + mt*16;
      f32x4 c = acc[mt][nt];
      float part = 0.f;
      #pragma unroll
      for (int rr = 0; rr < 4; rr++){
        const int ml = (mb - m0) + (q << 2) + rr;
        float sg = 1.f / (1.f + __expf(-(c[rr] + bs)));
        part += als[ml] * sg;
      }
      part += __shfl_xor(part, 16, 64);
      if ((q & 1) == 0){
        const int srow = (mb >> 3) + (q >> 1);
        out[(size_t)srow * D + n] = part;
      }
    }
  }
}

// ================= orchestration =================
extern "C" void kernel_launch(void* const* d_in, const int* in_sizes, int n_in,
                              void* d_out, int out_size, void* d_ws, size_t ws_size,
                              hipStream_t stream) {
  const float* q_emb  = (const float*)d_in[0];
  const float* qa_emb = (const float*)d_in[1];
  const float* Wq1 = (const float*)d_in[2],  *bq1 = (const float*)d_in[3];
  const float* Wv1 = (const float*)d_in[4],  *bv1 = (const float*)d_in[5];
  const float* Wo1 = (const float*)d_in[6],  *bo1 = (const float*)d_in[7];
  const float* g1  = (const float*)d_in[8],  *ls1 = (const float*)d_in[9],  *lb1 = (const float*)d_in[10];
  const float* Wq2 = (const float*)d_in[11], *bq2 = (const float*)d_in[12];
  const float* Wv2 = (const float*)d_in[13], *bv2 = (const float*)d_in[14];
  const float* Wo2 = (const float*)d_in[15], *bo2 = (const float*)d_in[16];
  const float* g2  = (const float*)d_in[17], *ls2 = (const float*)d_in[18], *lb2 = (const float*)d_in[19];
  const float* Wq3 = (const float*)d_in[20], *bq3 = (const float*)d_in[21];
  const float* Wk3 = (const float*)d_in[22], *bk3 = (const float*)d_in[23];
  const float* Wv3 = (const float*)d_in[24], *bv3 = (const float*)d_in[25];
  const float* Wo3 = (const float*)d_in[26], *bo3 = (const float*)d_in[27];
  const float* g3  = (const float*)d_in[28], *ls3 = (const float*)d_in[29], *lb3 = (const float*)d_in[30];
  const float* know = (const float*)d_in[31];
  const float* Wlk  = (const float*)d_in[32], *b_lk = (const float*)d_in[33];
  const float* Wlv  = (const float*)d_in[34], *b_lv = (const float*)d_in[35];
  float* outp = (float*)d_out;

  const size_t NSD = (size_t)BB * S * D;   // 2,097,152
  unsigned short* p = (unsigned short*)d_ws;
  unsigned short* qk1b = p; p += NSD;
  unsigned short* v1b  = p; p += NSD;
  unsigned short* qk2b = p; p += NSD;
  unsigned short* v2b  = p; p += NSD;
  unsigned short* k3b  = p; p += NSD;
  unsigned short* v3b  = p; p += NSD;
  unsigned short* ctx1b= p; p += NSD;
  unsigned short* ctx2b= p; p += NSD;
  unsigned short* ctx3b= p; p += NSD;
  unsigned short* xqb  = p; p += NSD;
  unsigned short* xab  = p; p += NSD;
  unsigned short* hqb  = p; p += NSD;
  unsigned short* hab  = p; p += NSD;
  unsigned short* hfb  = p; p += NSD;
  unsigned short* vt1  = p; p += NSD;   // [32][64][1024]
  unsigned short* vt2  = p; p += NSD;
  unsigned short* vt3  = p; p += NSD;
  unsigned short* wb   = p; p += (size_t)9 * D * D;
  unsigned short* wlvb = p; p += (size_t)D * DKH;
  float* yv0   = (float*)p;
  float* yv1   = yv0 + NSD;
  float* q3    = yv1 + NSD;
  float* keyt  = q3 + 512;
  float* c3    = keyt + 4096;
  float* alpha = c3 + (size_t)BB * H * S;

  unsigned short* Wq1b = wb + 0*(size_t)D*D;
  unsigned short* Wv1b = wb + 1*(size_t)D*D;
  unsigned short* Wo1b = wb + 2*(size_t)D*D;
  unsigned short* Wq2b = wb + 3*(size_t)D*D;
  unsigned short* Wv2b = wb + 4*(size_t)D*D;
  unsigned short* Wo2b = wb + 5*(size_t)D*D;
  unsigned short* Wk3b = wb + 6*(size_t)D*D;
  unsigned short* Wv3b = wb + 7*(size_t)D*D;
  unsigned short* Wo3b = wb + 8*(size_t)D*D;

  // ---- conversions (vectorized) + know-derived precompute (merged z=12) ----
  CvtJobs jb;
  jb.s[0] = q_emb;  jb.d[0] = xqb;  jb.n[0] = (int)NSD;
  jb.s[1] = qa_emb; jb.d[1] = xab;  jb.n[1] = (int)NSD;
  jb.s[2] = Wq1; jb.d[2] = Wq1b; jb.n[2] = D*D;
  jb.s[3] = Wv1; jb.d[3] = Wv1b; jb.n[3] = D*D;
  jb.s[4] = Wo1; jb.d[4] = Wo1b; jb.n[4] = D*D;
  jb.s[5] = Wq2; jb.d[5] = Wq2b; jb.n[5] = D*D;
  jb.s[6] = Wv2; jb.d[6] = Wv2b; jb.n[6] = D*D;
  jb.s[7] = Wo2; jb.d[7] = Wo2b; jb.n[7] = D*D;
  jb.s[8] = Wk3; jb.d[8] = Wk3b; jb.n[8] = D*D;
  jb.s[9] = Wv3; jb.d[9] = Wv3b; jb.n[9] = D*D;
  jb.s[10] = Wo3; jb.d[10] = Wo3b; jb.n[10] = D*D;
  jb.s[11] = Wlv; jb.d[11] = wlvb; jb.n[11] = D*DKH;
  jb.know = know; jb.Wq3 = Wq3; jb.bq3 = bq3; jb.q3 = q3;
  jb.Wlk = Wlk; jb.blk_ = b_lk; jb.keyt = keyt;
  cvt_all<<<dim3(256, 13), 256, 0, stream>>>(jb);

  // ---- blocks 1&2: projections (z=4) ----
  {
    GemmJobs g;
    g.A[0]=xqb; g.W[0]=Wq1b; g.bias[0]=bq1; g.C[0]=qk1b;
    g.A[1]=xqb; g.W[1]=Wv1b; g.bias[1]=bv1; g.C[1]=v1b;
    g.A[2]=xab; g.W[2]=Wq2b; g.bias[2]=bq2; g.C[2]=qk2b;
    g.A[3]=xab; g.W[3]=Wv2b; g.bias[3]=bv2; g.C[3]=v2b;
    mfma_gemm_b<1><<<dim3(4, 32, 4), 256, 0, stream>>>(g);
  }
  { VTArgs a; a.v[0]=v1b; a.v[1]=v2b; a.vt[0]=vt1; a.vt[1]=vt2; a.nz=2;
    a.vtblocks=1024; a.keyt=keyt; a.q_emb=q_emb; a.alpha=alpha;
    a.q3=nullptr; a.k3=nullptr; a.c3=nullptr;
    vt_kernel<<<dim3(2048), 256, 0, stream>>>(a); }
  { FAArgs a;
    a.qk[0]=qk1b; a.qk[1]=qk2b; a.vt[0]=vt1; a.vt[1]=vt2;
    a.ctx[0]=ctx1b; a.ctx[1]=ctx2b; a.g[0]=g1; a.g[1]=g2;
    a.c3=nullptr; a.diag=0; a.zero_pad=0; a.nz=2;
    fused_attn<0><<<dim3(4096), 256, 0, stream>>>(a); }
  {
    GemmJobs g;
    g.A[0]=ctx1b; g.W[0]=Wo1b; g.bias[0]=bo1; g.C[0]=yv0;
    g.A[1]=ctx2b; g.W[1]=Wo2b; g.bias[1]=bo2; g.C[1]=yv1;
    g.A[2]=ctx1b; g.W[2]=Wo1b; g.bias[2]=bo1; g.C[2]=yv0;
    g.A[3]=ctx1b; g.W[3]=Wo1b; g.bias[3]=bo1; g.C[3]=yv0;
    mfma_gemm_b<0><<<dim3(4, 32, 2), 256, 0, stream>>>(g);
  }
  {
    LNJobs lj;
    lj.resid[0]=q_emb;  lj.y[0]=yv0; lj.ls[0]=ls1; lj.lb[0]=lb1; lj.out[0]=hqb; lj.bcast[0]=0;
    lj.resid[1]=qa_emb; lj.y[1]=yv1; lj.ls[1]=ls2; lj.lb[1]=lb2; lj.out[1]=hab; lj.bcast[1]=0;
    ln_residual_b<<<dim3(BB*S/2, 2), 256, 0, stream>>>(lj);
  }

  // ---- block 3 ----
  {
    GemmJobs g;
    g.A[0]=hqb; g.W[0]=Wk3b; g.bias[0]=bk3; g.C[0]=k3b;
    g.A[1]=hab; g.W[1]=Wv3b; g.bias[1]=bv3; g.C[1]=v3b;
    g.A[2]=hqb; g.W[2]=Wk3b; g.bias[2]=bk3; g.C[2]=k3b;
    g.A[3]=hqb; g.W[3]=Wk3b; g.bias[3]=bk3; g.C[3]=k3b;
    mfma_gemm_b<1><<<dim3(4, 32, 2), 256, 0, stream>>>(g);
  }
  { VTArgs a; a.v[0]=v3b; a.v[1]=v3b; a.vt[0]=vt3; a.vt[1]=vt3; a.nz=1;
    a.vtblocks=512; a.keyt=nullptr; a.q_emb=nullptr; a.alpha=nullptr;
    a.q3=q3; a.k3=k3b; a.c3=c3;
    vt_kernel<<<dim3(1024), 256, 0, stream>>>(a); }
  { FAArgs a;
    a.qk[0]=k3b; a.qk[1]=k3b; a.vt[0]=vt3; a.vt[1]=vt3;
    a.ctx[0]=ctx3b; a.ctx[1]=ctx3b; a.g[0]=g3; a.g[1]=g3;
    a.c3=c3; a.diag=-1; a.zero_pad=1; a.nz=1;
    fused_attn<1><<<dim3(2048), 256, 0, stream>>>(a); }
  {
    GemmJobs g;
    g.A[0]=ctx3b; g.W[0]=Wo3b; g.bias[0]=bo3; g.C[0]=yv0;
    g.A[1]=ctx3b; g.W[1]=Wo3b; g.bias[1]=bo3; g.C[1]=yv0;
    g.A[2]=ctx3b; g.W[2]=Wo3b; g.bias[2]=bo3; g.C[2]=yv0;
    g.A[3]=ctx3b; g.W[3]=Wo3b; g.bias[3]=bo3; g.C[3]=yv0;
    mfma_gemm_b<0><<<dim3(4, 32, 1), 256, 0, stream>>>(g);
  }
  {
    LNJobs lj;
    lj.resid[0]=know; lj.y[0]=yv0; lj.ls[0]=ls3; lj.lb[0]=lb3; lj.out[0]=hfb; lj.bcast[0]=1;
    lj.resid[1]=know; lj.y[1]=yv0; lj.ls[1]=ls3; lj.lb[1]=lb3; lj.out[1]=hfb; lj.bcast[1]=1;
    ln_residual_b<<<dim3(BB*S/2, 1), 256, 0, stream>>>(lj);
  }

  // ---- final combine (alphas computed in vt12 launch) ----
  val_fused<<<dim3(4, 256), 256, 0, stream>>>(hfb, wlvb, b_lv, alpha, outp);
}